// Round 14
// baseline (6133.958 us; speedup 1.0000x reference)
//
#include <hip/hip_runtime.h>
#include <math.h>

constexpr int BATCH = 256;
constexpr int EQ_   = 192;
constexpr int EC_   = 240;
constexpr int EPG   = 432;   // edges per pair
constexpr int NPG   = 216;   // nodes per pair
constexpr int NN    = BATCH * NPG;   // 55296
constexpr int NE    = BATCH * EPG;   // 110592

typedef __attribute__((ext_vector_type(8))) short short8;
typedef __attribute__((ext_vector_type(4))) float floatx4;
typedef unsigned short u16;

__device__ __forceinline__ u16 f2bf(float x) {
  union { float f; unsigned u; } c; c.f = x;
  const unsigned r = (c.u + 0x7FFFu + ((c.u >> 16) & 1u)) >> 16;
  return (u16)r;
}
__device__ __forceinline__ float bf2f(u16 x) {
  union { unsigned u; float f; } c; c.u = ((unsigned)x) << 16;
  return c.f;
}
__device__ __forceinline__ unsigned pack2(float a, float b) {
  return (unsigned)f2bf(a) | ((unsigned)f2bf(b) << 16);
}
__device__ __forceinline__ short8 cvt8(const float* __restrict__ p) {
  const float4 a = *(const float4*)p;
  const float4 b = *(const float4*)(p + 4);
  short8 o;
  o[0]=(short)f2bf(a.x); o[1]=(short)f2bf(a.y); o[2]=(short)f2bf(a.z); o[3]=(short)f2bf(a.w);
  o[4]=(short)f2bf(b.x); o[5]=(short)f2bf(b.y); o[6]=(short)f2bf(b.z); o[7]=(short)f2bf(b.w);
  return o;
}

__device__ __forceinline__ void lse_online(float& m, float& s, float tt) {
  if (tt > m) { s = s * __expf(m - tt) + 1.f; m = tt; }
  else        { s += __expf(tt - m); }
}

// ---------------------------------------------------------------------------
// weight transpose + f32->bf16:  out[n*K+k] = bf16(W[k*N+n])
// ---------------------------------------------------------------------------
__global__ __launch_bounds__(256)
void wconv(const float* __restrict__ W, u16* __restrict__ out, int K, int N)
{
  const int i = blockIdx.x * 256 + threadIdx.x;
  if (i < K * N) {
    const int n = i / K, k = i - n * K;
    out[i] = f2bf(W[(size_t)k * N + n]);
  }
}

// ---------------------------------------------------------------------------
// MFMA fused 2-layer MLP. Generalized wave->tile decomposition:
//   MT = RT/16 m-tiles; CW = WAVES/MT waves per m-tile.
//   Wave w owns m-tile (w/CW) and column group (w%CW):
//   layer1 covers NC1=(HID/16)/CW col-tiles, layer2 NC2=(NOUT/16)/CW.
// RT=64/WAVES=16 for edge MLPs: halves per-dispatch weight refetch (blocks
// halve), doubles per-block MFMA work, acc regs ~40 (<64-VGPR cap that this
// toolchain imposes on 1024-thread kernels - rounds 7-9). Numerics unchanged.
// IN_MODE: 1 [hb[IA],hb[IB],comb]  3 [hb,aggFb,aggBb]  4 [e(f32), inter(f32|0)]
// OUT_MODE: 0 f32 write (sum)  1 bf16 write (sum)  2 bf16 per-dir -> Yb0/Yb1
// ---------------------------------------------------------------------------
template<int K1, int HID, int NOUT, int IN_MODE, int DUAL, int OUT_MODE,
         int WAVES, int RT>
__global__ __launch_bounds__(WAVES * 64)
void mlp_mfma(const void* __restrict__ X, const void* __restrict__ P2,
              const void* __restrict__ P3, const u16* __restrict__ CB,
              const int* __restrict__ IA, const int* __restrict__ IB,
              const u16* __restrict__ W1t, const float* __restrict__ B1,
              const u16* __restrict__ W2t, const float* __restrict__ B2,
              float* __restrict__ Yf, u16* __restrict__ Yb0, u16* __restrict__ Yb1)
{
  constexpr int THREADS = WAVES * 64;
  constexpr int MT  = RT / 16;
  constexpr int CW  = WAVES / MT;
  constexpr int NC1 = (HID / 16) / CW;
  constexpr int NC2 = (NOUT / 16) / CW;
  constexpr int KCH = K1 / 8;
  constexpr int SAB = RT * K1 * 2;
  constexpr int SHB = RT * (HID + 8) * 2;
  __shared__ __align__(16) char smem[(SAB > SHB ? SAB : SHB)];
  u16* sA = (u16*)smem;
  u16* sH = (u16*)smem;

  const int tid = threadIdx.x;
  const int rowBase = blockIdx.x * RT;

  // ---- stage A panel, XOR-swizzled rows ----
  for (int ch = tid; ch < RT * KCH; ch += THREADS) {
    const int r = ch / KCH, kc = ch - r * KCH;
    const int gr = rowBase + r, k0 = kc * 8;
    short8 pk;
    if constexpr (IN_MODE == 4) {
      const float* Xf  = (const float*)X;
      const float* P2f = (const float*)P2;
      if (k0 < 128)      pk = cvt8(&Xf[(size_t)gr * 128 + k0]);
      else if (P2f)      pk = cvt8(&P2f[(size_t)gr * 128 + (k0 - 128)]);
      else { pk = short8{0,0,0,0,0,0,0,0}; }
    } else if constexpr (IN_MODE == 1) {
      const u16* Hb = (const u16*)X;
      if (k0 < 64)       pk = *(const short8*)&Hb[(size_t)IA[gr] * 64 + k0];
      else if (k0 < 128) pk = *(const short8*)&Hb[(size_t)IB[gr] * 64 + (k0 - 64)];
      else               pk = *(const short8*)&CB[(size_t)gr * 128 + (k0 - 128)];
    } else { // 3
      const u16* Hb = (const u16*)X;
      const u16* A0 = (const u16*)P2;
      const u16* A1 = (const u16*)P3;
      if (k0 < 64)       pk = *(const short8*)&Hb[(size_t)gr * 64 + k0];
      else if (k0 < 192) pk = *(const short8*)&A0[(size_t)gr * 128 + (k0 - 64)];
      else               pk = *(const short8*)&A1[(size_t)gr * 128 + (k0 - 192)];
    }
    const int byte = ((r * K1 + k0) * 2) ^ ((r & 7) << 4);
    *(short8*)((char*)sA + byte) = pk;
  }
  __syncthreads();

  const int wid = tid >> 6, lane = tid & 63;
  const int l15 = lane & 15, lg = lane >> 4;
  const int mt = wid / CW;          // this wave's m-tile (row block)
  const int cg = wid % CW;          // this wave's column group
  const int arow = mt * 16 + l15;   // A-operand row for this wave

  // ---- layer 1, all dirs (sA stays live only here) ----
  floatx4 acc1[1 + DUAL][NC1];
  #pragma unroll
  for (int d = 0; d <= DUAL; ++d)
    #pragma unroll
    for (int n = 0; n < NC1; ++n) acc1[d][n] = floatx4{0.f,0.f,0.f,0.f};

  #pragma unroll 2
  for (int kk = 0; kk < K1 / 32; ++kk) {
    short8 bw[NC1];
    #pragma unroll
    for (int n = 0; n < NC1; ++n) {
      const int col = (cg * NC1 + n) * 16 + l15;
      bw[n] = *(const short8*)&W1t[(size_t)col * K1 + kk * 32 + lg * 8];
    }
    #pragma unroll
    for (int d = 0; d <= DUAL; ++d) {
      int k0 = kk * 32 + lg * 8;
      if (DUAL && d && k0 < 128) k0 ^= 64;
      const int byte = ((arow * K1 + k0) * 2) ^ ((arow & 7) << 4);
      const short8 af = *(const short8*)((char*)sA + byte);
      #pragma unroll
      for (int n = 0; n < NC1; ++n)
        acc1[d][n] = __builtin_amdgcn_mfma_f32_16x16x32_bf16(af, bw[n], acc1[d][n], 0, 0, 0);
    }
  }
  __syncthreads();   // sA dead from here; smem becomes sH

  floatx4 accO[NC2];
  #pragma unroll
  for (int n = 0; n < NC2; ++n) accO[n] = floatx4{0.f,0.f,0.f,0.f};

  #pragma unroll
  for (int d = 0; d <= DUAL; ++d) {
    // hidden: bias + relu -> bf16 LDS (rows mt*16+lg*4+r, cols this group's)
    #pragma unroll
    for (int n = 0; n < NC1; ++n) {
      const int col = (cg * NC1 + n) * 16 + l15;
      const float b1 = B1[col];
      #pragma unroll
      for (int r = 0; r < 4; ++r) {
        const int row = mt * 16 + lg * 4 + r;
        const float y = acc1[d][n][r] + b1;
        sH[row * (HID + 8) + col] = f2bf(y > 0.f ? y : 0.f);
      }
    }
    __syncthreads();
    if (OUT_MODE == 2 && d == 1) {
      #pragma unroll
      for (int n = 0; n < NC2; ++n) accO[n] = floatx4{0.f,0.f,0.f,0.f};
    }
    #pragma unroll 2
    for (int kk = 0; kk < HID / 32; ++kk) {
      short8 bw2[NC2];
      #pragma unroll
      for (int n = 0; n < NC2; ++n) {
        const int col = (cg * NC2 + n) * 16 + l15;
        bw2[n] = *(const short8*)&W2t[(size_t)col * HID + kk * 32 + lg * 8];
      }
      const short8 af = *(const short8*)&sH[arow * (HID + 8) + kk * 32 + lg * 8];
      #pragma unroll
      for (int n = 0; n < NC2; ++n)
        accO[n] = __builtin_amdgcn_mfma_f32_16x16x32_bf16(af, bw2[n], accO[n], 0, 0, 0);
    }
    if constexpr (OUT_MODE == 2) {
      u16* Y = d ? Yb1 : Yb0;
      #pragma unroll
      for (int n = 0; n < NC2; ++n) {
        const int col = (cg * NC2 + n) * 16 + l15;
        const float b2 = B2[col];
        #pragma unroll
        for (int r = 0; r < 4; ++r) {
          const int gr = rowBase + mt * 16 + lg * 4 + r;
          Y[(size_t)gr * NOUT + col] = f2bf(accO[n][r] + b2);
        }
      }
    }
    if (DUAL && d == 0) __syncthreads();   // before overwriting sH
  }

  if constexpr (OUT_MODE != 2) {
    #pragma unroll
    for (int n = 0; n < NC2; ++n) {
      const int col = (cg * NC2 + n) * 16 + l15;
      const float b2 = B2[col] * (float)(1 + DUAL);
      #pragma unroll
      for (int r = 0; r < 4; ++r) {
        const int gr = rowBase + mt * 16 + lg * 4 + r;
        const float y = accO[n][r] + b2;
        if constexpr (OUT_MODE == 1) Yb0[(size_t)gr * NOUT + col] = f2bf(y);
        else                         Yf[(size_t)gr * NOUT + col] = y;
      }
    }
  }
}

// ---------------------------------------------------------------------------
// Pair-local segment-sum scatter: block = pair*2 + dir, 512 threads.
// ---------------------------------------------------------------------------
__global__ __launch_bounds__(512)
void scatter_agg(const u16* __restrict__ MF, const u16* __restrict__ MB,
                 const int* __restrict__ FI, const int* __restrict__ TI,
                 u16* __restrict__ AggF, u16* __restrict__ AggB)
{
  const int pair = blockIdx.x >> 1, dir = blockIdx.x & 1;
  const u16* M  = dir ? MB : MF;
  const int* SI = dir ? FI : TI;
  u16* Agg      = dir ? AggB : AggF;
  const int tid = threadIdx.x;
  __shared__ float sAgg[NPG * 128];

  for (int i = tid; i < NPG * 128; i += 512) sAgg[i] = 0.f;
  __syncthreads();

  for (int i = tid; i < EPG * 32; i += 512) {
    const int edge = i >> 5, cb = i & 31;
    const int er = pair * EPG + edge;
    const int node = SI[er] - pair * NPG;
    const size_t base = (size_t)er * 128 + cb;
    #pragma unroll
    for (int k = 0; k < 4; ++k)
      atomicAdd(&sAgg[node * 128 + cb + 32 * k], bf2f(M[base + 32 * k]));
  }
  __syncthreads();
  unsigned* dst = (unsigned*)(Agg + (size_t)pair * NPG * 128);
  for (int i = tid; i < NPG * 64; i += 512)
    dst[i] = pack2(sAgg[2 * i], sAgg[2 * i + 1]);
}

// ---------------------------------------------------------------------------
// f32 fused MLP (encoders + sinkhorn feature MLPs)
// IN_MODE: 0 plain X  5 q-side rows of e (zero-padded)  6 c-side rows
// OUTBF (SINGLE only): write bf16 to Yb
// ---------------------------------------------------------------------------
template<int K1, int HID, int NOUT, int IN_MODE, int SINGLE, int OUTBF>
__global__ __launch_bounds__(256)
void fused_mlp(const float* __restrict__ X, const float* __restrict__ P1,
               const float* __restrict__ W1, const float* __restrict__ B1,
               const float* __restrict__ W2, const float* __restrict__ B2,
               float* __restrict__ Y, u16* __restrict__ Yb, int maskLen)
{
  constexpr int RT = 32, BK = 32;
  constexpr int J1 = HID / 32;
  constexpr int J2 = NOUT / 32;
  constexpr int BMAX = (HID > NOUT ? HID : NOUT);
  __shared__ float sA[RT * 33];
  __shared__ float sB[BK * BMAX];
  __shared__ float sH[SINGLE ? 1 : RT * (HID + 1)];

  const int t  = threadIdx.x;
  const int tx = t & 31, ty = t >> 5;
  const int rowBase = blockIdx.x * RT;

  float acc[4][J1];
  #pragma unroll
  for (int i = 0; i < 4; ++i)
    #pragma unroll
    for (int j = 0; j < J1; ++j) acc[i][j] = 0.f;

  for (int kb = 0; kb < K1; kb += BK) {
    for (int l = t; l < RT * BK; l += 256) {
      const int r = l >> 5, k = l & 31;
      const int gr = rowBase + r, gk = kb + k;
      float v;
      if constexpr (IN_MODE == 0) {
        v = X[(size_t)gr * K1 + gk];
      } else {
        const int bb = gr >> 8, m = gr & 255;
        constexpr int off = (IN_MODE == 5) ? 0 : EQ_;
        constexpr int len = (IN_MODE == 5) ? EQ_ : EC_;
        v = (m < len) ? P1[((size_t)bb * EPG + off + m) * 128 + gk] : 0.f;
      }
      sA[r * 33 + k] = v;
    }
    for (int l = t * 4; l < BK * HID; l += 1024) {
      *(float4*)&sB[l] = *(const float4*)&W1[(size_t)(kb + l / HID) * HID + (l % HID)];
    }
    __syncthreads();
    #pragma unroll
    for (int k = 0; k < BK; ++k) {
      const float a0 = sA[(ty*4+0)*33+k], a1 = sA[(ty*4+1)*33+k],
                  a2 = sA[(ty*4+2)*33+k], a3 = sA[(ty*4+3)*33+k];
      #pragma unroll
      for (int j = 0; j < J1; ++j) {
        const float bb = sB[k * HID + tx + 32*j];
        acc[0][j] += a0 * bb; acc[1][j] += a1 * bb;
        acc[2][j] += a2 * bb; acc[3][j] += a3 * bb;
      }
    }
    __syncthreads();
  }

  if constexpr (SINGLE) {
    #pragma unroll
    for (int j = 0; j < J1; ++j) {
      const int col = tx + 32*j;
      const float bias = B1[col];
      #pragma unroll
      for (int i = 0; i < 4; ++i) {
        const int gr = rowBase + ty*4 + i;
        if constexpr (OUTBF) Yb[(size_t)gr * HID + col] = f2bf(acc[i][j] + bias);
        else                 Y[(size_t)gr * HID + col] = acc[i][j] + bias;
      }
    }
  } else {
    #pragma unroll
    for (int j = 0; j < J1; ++j) {
      const int col = tx + 32*j;
      const float bias = B1[col];
      #pragma unroll
      for (int i = 0; i < 4; ++i) {
        float y = acc[i][j] + bias;
        sH[(ty*4+i) * (HID+1) + col] = y > 0.f ? y : 0.f;
      }
    }
    __syncthreads();

    float acc2[4][J2];
    #pragma unroll
    for (int i = 0; i < 4; ++i)
      #pragma unroll
      for (int j = 0; j < J2; ++j) acc2[i][j] = 0.f;

    for (int kb = 0; kb < HID; kb += BK) {
      for (int l = t * 4; l < BK * NOUT; l += 1024) {
        *(float4*)&sB[l] = *(const float4*)&W2[(size_t)(kb + l / NOUT) * NOUT + (l % NOUT)];
      }
      __syncthreads();
      #pragma unroll
      for (int k = 0; k < BK; ++k) {
        const float a0 = sH[(ty*4+0)*(HID+1) + kb + k],
                    a1 = sH[(ty*4+1)*(HID+1) + kb + k],
                    a2 = sH[(ty*4+2)*(HID+1) + kb + k],
                    a3 = sH[(ty*4+3)*(HID+1) + kb + k];
        #pragma unroll
        for (int j = 0; j < J2; ++j) {
          const float bb = sB[k * NOUT + tx + 32*j];
          acc2[0][j] += a0 * bb; acc2[1][j] += a1 * bb;
          acc2[2][j] += a2 * bb; acc2[3][j] += a3 * bb;
        }
      }
      __syncthreads();
    }
    #pragma unroll
    for (int j = 0; j < J2; ++j) {
      const int col = tx + 32*j;
      const float bias = B2[col];
      #pragma unroll
      for (int i = 0; i < 4; ++i) {
        const int gr = rowBase + ty*4 + i;
        float y = acc2[i][j] + bias;
        if (maskLen >= 0 && (gr & 255) >= maskLen) y = 0.f;
        Y[(size_t)gr * NOUT + col] = y;
      }
    }
  }
}

// ---------------------------------------------------------------------------
// S[b] = scale * fq[b] @ fc[b]^T
// ---------------------------------------------------------------------------
__global__ __launch_bounds__(256)
void gemm_nt_scale(const float* __restrict__ A, const float* __restrict__ Bm,
                   float* __restrict__ C, float scale)
{
  const int b = blockIdx.z, qt = blockIdx.x, ct = blockIdx.y;
  __shared__ float sA[64 * 68];
  __shared__ float sB[64 * 68];
  const int t = threadIdx.x;
  const int tx = t & 15, ty = t >> 4;
  const float* Ab = A  + (size_t)b * 16384 + (size_t)qt * 4096;
  const float* Bb = Bm + (size_t)b * 16384 + (size_t)ct * 4096;
  for (int l = t * 4; l < 64 * 64; l += 1024) {
    const int r = l >> 6, d = l & 63;
    *(float4*)&sA[r*68 + d] = *(const float4*)&Ab[r*64 + d];
    *(float4*)&sB[r*68 + d] = *(const float4*)&Bb[r*64 + d];
  }
  __syncthreads();
  float acc[4][4] = {};
  #pragma unroll
  for (int d = 0; d < 64; ++d) {
    float a[4], bb[4];
    #pragma unroll
    for (int i = 0; i < 4; ++i) a[i]  = sA[(ty*4+i)*68 + d];
    #pragma unroll
    for (int j = 0; j < 4; ++j) bb[j] = sB[(tx+16*j)*68 + d];
    #pragma unroll
    for (int i = 0; i < 4; ++i)
      #pragma unroll
      for (int j = 0; j < 4; ++j) acc[i][j] += a[i] * bb[j];
  }
  float* Cb = C + (size_t)b * 65536 + (size_t)(qt*64) * 256 + ct*64;
  #pragma unroll
  for (int i = 0; i < 4; ++i)
    #pragma unroll
    for (int j = 0; j < 4; ++j)
      Cb[(ty*4+i)*256 + tx + 16*j] = acc[i][j] * scale;
}

// ---------------------------------------------------------------------------
// Y rows r<maskRows at ((b*RPB + YOFF + r)*128) = op(P[b]) @ V (gathered from e)
// ---------------------------------------------------------------------------
template<int TRANSA>
__global__ __launch_bounds__(256)
void gemm_plan(const float* __restrict__ P, const float* __restrict__ E,
               float* __restrict__ Y, int RPB, int YOFF, int VOFF, int VLEN,
               int maskRows)
{
  const int b = blockIdx.y, rt = blockIdx.x;
  __shared__ float sA[64 * 33];
  __shared__ float sB[32 * 128];
  const int t = threadIdx.x;
  const int tx = t & 15, ty = t >> 4;
  const float* Pb = P + (size_t)b * 65536;
  float acc[4][8] = {};
  for (int kb = 0; kb < 256; kb += 32) {
    if constexpr (TRANSA == 0) {
      for (int l = t; l < 64 * 32; l += 256) {
        const int r = l >> 5, k = l & 31;
        sA[r*33 + k] = Pb[(size_t)(rt*64 + r) * 256 + kb + k];
      }
    } else {
      for (int l = t; l < 64 * 32; l += 256) {
        const int r = l & 63, k = l >> 6;
        sA[r*33 + k] = Pb[(size_t)(kb + k) * 256 + rt*64 + r];
      }
    }
    for (int l = t * 4; l < 32 * 128; l += 1024) {
      const int vr = kb + (l >> 7), d = l & 127;
      float4 val = {0.f, 0.f, 0.f, 0.f};
      if (vr < VLEN) val = *(const float4*)&E[((size_t)b * EPG + VOFF + vr) * 128 + d];
      *(float4*)&sB[l] = val;
    }
    __syncthreads();
    #pragma unroll
    for (int k = 0; k < 32; ++k) {
      float a[4], bb[8];
      #pragma unroll
      for (int i = 0; i < 4; ++i) a[i]  = sA[(ty*4+i)*33 + k];
      #pragma unroll
      for (int j = 0; j < 8; ++j) bb[j] = sB[k*128 + tx + 16*j];
      #pragma unroll
      for (int i = 0; i < 4; ++i)
        #pragma unroll
        for (int j = 0; j < 8; ++j) acc[i][j] += a[i] * bb[j];
    }
    __syncthreads();
  }
  #pragma unroll
  for (int i = 0; i < 4; ++i) {
    const int r = rt*64 + ty*4 + i;
    if (r >= maskRows) continue;
    float* yr = Y + ((size_t)b * RPB + YOFF + r) * 128;
    #pragma unroll
    for (int j = 0; j < 8; ++j) yr[tx + 16*j] = acc[i][j];
  }
}

// ---------------------------------------------------------------------------
// Single-pass fused sinkhorn with exp-free butterflies (round-11 proven).
// ---------------------------------------------------------------------------
__global__ __launch_bounds__(1024)
void sinkhorn_fused(float* __restrict__ S)
{
  const int b = blockIdx.x, t = threadIdx.x;
  float* Sb = S + (size_t)b * 65536;
  const int w = t >> 6, lane = t & 63;
  const int cbase = lane * 4;
  __shared__ float pm[16 * 256], ps[16 * 256];
  __shared__ float su[256], sv[256];
  if (t < 256) sv[t] = 0.f;
  __syncthreads();

  for (int it = 0; it < 10; ++it) {
    const float4 v4 = *(const float4*)&sv[cbase];
    float4 cm = {-1e30f, -1e30f, -1e30f, -1e30f};
    float4 cs = {0.f, 0.f, 0.f, 0.f};
    #pragma unroll 2
    for (int i = 0; i < 16; ++i) {
      const int r = w * 16 + i;
      const float4 s4 = *(const float4*)&Sb[(size_t)r * 256 + cbase];
      const float ax = s4.x + v4.x, ay = s4.y + v4.y;
      const float az = s4.z + v4.z, aw = s4.w + v4.w;
      float m = fmaxf(fmaxf(ax, ay), fmaxf(az, aw));
      #pragma unroll
      for (int off = 32; off; off >>= 1) m = fmaxf(m, __shfl_xor(m, off));
      float s = __expf(ax - m) + __expf(ay - m) + __expf(az - m) + __expf(aw - m);
      #pragma unroll
      for (int off = 32; off; off >>= 1) s += __shfl_xor(s, off);
      const float u = -(m + __logf(s));
      if (lane == 0) su[r] = u;
      lse_online(cm.x, cs.x, s4.x + u);
      lse_online(cm.y, cs.y, s4.y + u);
      lse_online(cm.z, cs.z, s4.z + u);
      lse_online(cm.w, cs.w, s4.w + u);
    }
    *(float4*)&pm[w * 256 + cbase] = cm;
    *(float4*)&ps[w * 256 + cbase] = cs;
    __syncthreads();
    if (t < 256) {
      float m = pm[t];
      #pragma unroll
      for (int k = 1; k < 16; ++k) m = fmaxf(m, pm[k * 256 + t]);
      float s = 0.f;
      #pragma unroll
      for (int k = 0; k < 16; ++k) s += ps[k * 256 + t] * __expf(pm[k * 256 + t] - m);
      sv[t] = -(m + __logf(s));
    }
    __syncthreads();
  }
  for (int i = t; i < 16384; i += 1024) {
    const int row = i >> 6, c4 = (i & 63) * 4;
    float4 s4 = *(float4*)&Sb[(size_t)row * 256 + c4];
    const float uu = su[row];
    const float4 v4 = *(const float4*)&sv[c4];
    s4.x = __expf(s4.x + uu + v4.x);
    s4.y = __expf(s4.y + uu + v4.y);
    s4.z = __expf(s4.z + uu + v4.z);
    s4.w = __expf(s4.w + uu + v4.w);
    *(float4*)&Sb[(size_t)row * 256 + c4] = s4;
  }
}

// ---------------------------------------------------------------------------
// score[b] = -sum_{m<256,d} | (m<EQ ? e_q[m,d] : 0) - pc[m,d] |
// ---------------------------------------------------------------------------
__global__ __launch_bounds__(256)
void escore_kernel(const float* __restrict__ e, const float* __restrict__ pc,
                   float* __restrict__ out)
{
  const int b = blockIdx.x, t = threadIdx.x;
  float acc = 0.f;
  for (int i4 = t; i4 < 8192; i4 += 256) {
    const int flat = i4 * 4;
    const int m = flat >> 7, d = flat & 127;
    float4 p = *(const float4*)&pc[((size_t)b * 256 + m) * 128 + d];
    float4 q = {0.f, 0.f, 0.f, 0.f};
    if (m < EQ_) q = *(const float4*)&e[((size_t)b * EPG + m) * 128 + d];
    acc += fabsf(q.x - p.x) + fabsf(q.y - p.y) + fabsf(q.z - p.z) + fabsf(q.w - p.w);
  }
  __shared__ float red[256];
  red[t] = acc; __syncthreads();
  for (int s2 = 128; s2 > 0; s2 >>= 1) { if (t < s2) red[t] += red[t + s2]; __syncthreads(); }
  if (t == 0) out[b] = -red[0];
}

// ---------------------------------------------------------------------------
extern "C" void kernel_launch(void* const* d_in, const int* in_sizes, int n_in,
                              void* d_out, int out_size, void* d_ws, size_t ws_size,
                              hipStream_t stream)
{
  const float* node_features = (const float*)d_in[0];
  const float* edge_features = (const float*)d_in[1];
  const int*   from_idx      = (const int*)d_in[2];
  const int*   to_idx        = (const int*)d_in[3];
  const float* enc_node_W = (const float*)d_in[4];
  const float* enc_node_b = (const float*)d_in[5];
  const float* enc_edge_W = (const float*)d_in[6];
  const float* enc_edge_b = (const float*)d_in[7];
  const float* msg_W1 = (const float*)d_in[8];
  const float* msg_b1 = (const float*)d_in[9];
  const float* msg_W2 = (const float*)d_in[10];
  const float* msg_b2 = (const float*)d_in[11];
  const float* upd_W1 = (const float*)d_in[12];
  const float* upd_b1 = (const float*)d_in[13];
  const float* upd_W2 = (const float*)d_in[14];
  const float* upd_b2 = (const float*)d_in[15];
  const float* int_W1 = (const float*)d_in[16];
  const float* int_b1 = (const float*)d_in[17];
  const float* int_W2 = (const float*)d_in[18];
  const float* int_b2 = (const float*)d_in[19];
  const float* sink_W1 = (const float*)d_in[20];
  const float* sink_b1 = (const float*)d_in[21];
  const float* sink_W2 = (const float*)d_in[22];
  const float* sink_b2 = (const float*)d_in[23];
  float* out = (float*)d_out;

  // ~224 MB layout (proven). h bf16; aggF/aggB bf16; mf/mb alias e's dead window.
  float* wsf = (float*)d_ws;
  float* hreg = wsf;                              // region: NN*64 f32-sized
  float* e   = hreg + (size_t)NN * 64;            // NE*128 f32
  float* shr = e + (size_t)NE * 128;              // NE*128 f32 (inter | agg bf16 | fq+fc | pc)
  float* S   = shr + (size_t)NE * 128;            // BATCH*65536 f32
  u16* comb  = (u16*)(S + (size_t)BATCH * 65536); // NE*128 bf16
  u16* wi1 = comb + (size_t)NE * 128;             // 256x256
  u16* wi2 = wi1 + 65536;                         // 128x256
  u16* wm1 = wi2 + 32768;                         // 256x256
  u16* wm2 = wm1 + 65536;                         // 128x256
  u16* wu1 = wm2 + 32768;                         // 128x320
  u16* wu2 = wu1 + 40960;                         // 64x128

  u16* hb  = (u16*)hreg;                          // NN*64 bf16 node states
  u16* mfb = (u16*)e;                             // aliases e (dead window)
  u16* mbb = mfb + (size_t)NE * 128;

  u16* aggFb = (u16*)shr;                         // NN*128 bf16
  u16* aggBb = aggFb + (size_t)NN * 128;
  float* inter = shr;                             // EPG-row layout (f32)
  float* fq    = shr;
  float* fc    = shr + (size_t)BATCH * 16384;

  // weights -> bf16, transposed [N][K]
  wconv<<<256, 256, 0, stream>>>(int_W1, wi1, 256, 256);
  wconv<<<128, 256, 0, stream>>>(int_W2, wi2, 256, 128);
  wconv<<<256, 256, 0, stream>>>(msg_W1, wm1, 256, 256);
  wconv<<<128, 256, 0, stream>>>(msg_W2, wm2, 256, 128);
  wconv<<<160, 256, 0, stream>>>(upd_W1, wu1, 320, 128);
  wconv<<< 32, 256, 0, stream>>>(upd_W2, wu2, 128, 64);

  for (int ts = 0; ts < 2; ++ts) {
    // encoders (reset hb, e)
    fused_mlp<32,64,64,0,1,1><<<NN/32, 256, 0, stream>>>(
        node_features, nullptr, enc_node_W, enc_node_b, nullptr, nullptr,
        nullptr, hb, -1);
    fused_mlp<32,128,128,0,1,0><<<NE/32, 256, 0, stream>>>(
        edge_features, nullptr, enc_edge_W, enc_edge_b, nullptr, nullptr,
        e, nullptr, -1);

    for (int p = 0; p < 3; ++p) {
      // comb = intMLP([e, inter]) -> bf16   (inter==0 for ts0 and ts1/p0)
      const float* interArg = (ts == 1 && p > 0) ? inter : nullptr;
      mlp_mfma<256,256,128,4,0,1,16,64><<<NE/64, 1024, 0, stream>>>(
          e, interArg, nullptr, nullptr, nullptr, nullptr,
          wi1, int_b1, wi2, int_b2, nullptr, comb, nullptr);
      // messages on old h -> mf, mb (bf16, in e's dead storage), both dirs
      mlp_mfma<256,256,128,1,1,2,16,64><<<NE/64, 1024, 0, stream>>>(
          hb, nullptr, nullptr, comb, from_idx, to_idx,
          wm1, msg_b1, wm2, msg_b2, nullptr, mfb, mbb);
      // pair-local segment sums (LDS), both dirs as blocks -> bf16 agg
      scatter_agg<<<BATCH*2, 512, 0, stream>>>(mfb, mbb, from_idx, to_idx, aggFb, aggBb);
      // node update (in place, bf16)
      mlp_mfma<320,128,64,3,0,1,4,32><<<NN/32, 256, 0, stream>>>(
          hb, aggFb, aggBb, nullptr, nullptr, nullptr,
          wu1, upd_b1, wu2, upd_b2, nullptr, hb, nullptr);
      // e = mf2 + mb2 with updated h (dual-direction sum; overwrites mf/mb)
      mlp_mfma<256,256,128,1,1,0,16,64><<<NE/64, 1024, 0, stream>>>(
          hb, nullptr, nullptr, comb, from_idx, to_idx,
          wm1, msg_b1, wm2, msg_b2, e, nullptr, nullptr);
      // interaction features from last time step's transport plan
      if (ts == 1 && p < 2) {
        gemm_plan<0><<<dim3(4, BATCH), 256, 0, stream>>>(
            S, e, inter, EPG, 0,   EQ_, EC_, EQ_);
        gemm_plan<1><<<dim3(4, BATCH), 256, 0, stream>>>(
            S, e, inter, EPG, EQ_, 0,   EQ_, EC_);
      }
    }
    // sinkhorn features + plan
    fused_mlp<128,64,64,5,0,0><<<BATCH*8, 256, 0, stream>>>(
        nullptr, e, sink_W1, sink_b1, sink_W2, sink_b2, fq, nullptr, EQ_);
    fused_mlp<128,64,64,6,0,0><<<BATCH*8, 256, 0, stream>>>(
        nullptr, e, sink_W1, sink_b1, sink_W2, sink_b2, fc, nullptr, EC_);
    gemm_nt_scale<<<dim3(4,4,BATCH), 256, 0, stream>>>(fq, fc, S, 10.0f);
    sinkhorn_fused<<<BATCH, 1024, 0, stream>>>(S);   // S := plan
  }

  // final score
  gemm_plan<0><<<dim3(4, BATCH), 256, 0, stream>>>(S, e, shr, 256, 0, EQ_, EC_, 256);
  escore_kernel<<<BATCH, 256, 0, stream>>>(e, shr, out);
}

// Round 15
// 5795.572 us; speedup vs baseline: 1.0584x; 1.0584x over previous
//
#include <hip/hip_runtime.h>
#include <math.h>

constexpr int BATCH = 256;
constexpr int EQ_   = 192;
constexpr int EC_   = 240;
constexpr int EPG   = 432;   // edges per pair
constexpr int NPG   = 216;   // nodes per pair
constexpr int NN    = BATCH * NPG;   // 55296
constexpr int NE    = BATCH * EPG;   // 110592

typedef __attribute__((ext_vector_type(8))) short short8;
typedef __attribute__((ext_vector_type(4))) float floatx4;
typedef unsigned short u16;

__device__ __forceinline__ u16 f2bf(float x) {
  union { float f; unsigned u; } c; c.f = x;
  const unsigned r = (c.u + 0x7FFFu + ((c.u >> 16) & 1u)) >> 16;
  return (u16)r;
}
__device__ __forceinline__ float bf2f(u16 x) {
  union { unsigned u; float f; } c; c.u = ((unsigned)x) << 16;
  return c.f;
}
__device__ __forceinline__ unsigned pack2(float a, float b) {
  return (unsigned)f2bf(a) | ((unsigned)f2bf(b) << 16);
}
__device__ __forceinline__ short8 cvt8(const float* __restrict__ p) {
  const float4 a = *(const float4*)p;
  const float4 b = *(const float4*)(p + 4);
  short8 o;
  o[0]=(short)f2bf(a.x); o[1]=(short)f2bf(a.y); o[2]=(short)f2bf(a.z); o[3]=(short)f2bf(a.w);
  o[4]=(short)f2bf(b.x); o[5]=(short)f2bf(b.y); o[6]=(short)f2bf(b.z); o[7]=(short)f2bf(b.w);
  return o;
}

__device__ __forceinline__ void lse_online(float& m, float& s, float tt) {
  if (tt > m) { s = s * __expf(m - tt) + 1.f; m = tt; }
  else        { s += __expf(tt - m); }
}

// ---------------------------------------------------------------------------
// weight transpose + f32->bf16:  out[n*K+k] = bf16(W[k*N+n])
// ---------------------------------------------------------------------------
__global__ __launch_bounds__(256)
void wconv(const float* __restrict__ W, u16* __restrict__ out, int K, int N)
{
  const int i = blockIdx.x * 256 + threadIdx.x;
  if (i < K * N) {
    const int n = i / K, k = i - n * K;
    out[i] = f2bf(W[(size_t)k * N + n]);
  }
}

// ---------------------------------------------------------------------------
// MFMA fused 2-layer MLP (round-13 operating point: WAVES=8/RT=32 edge,
// WAVES=4/RT=32 node; round-14's RT=64/W=16 regressed 47% -> reverted).
// Wave w owns m-tile (w/CW) and column group (w%CW).
// IN_MODE: 1 [hb[IA],hb[IB],comb]  3 [hb,aggFb,aggBb]  4 [e(f32), inter(f32|0)]
// OUT_MODE: 0 f32 write (sum)  1 bf16 write (sum)  2 bf16 per-dir -> Yb0/Yb1
// ---------------------------------------------------------------------------
template<int K1, int HID, int NOUT, int IN_MODE, int DUAL, int OUT_MODE,
         int WAVES, int RT>
__global__ __launch_bounds__(WAVES * 64)
void mlp_mfma(const void* __restrict__ X, const void* __restrict__ P2,
              const void* __restrict__ P3, const u16* __restrict__ CB,
              const int* __restrict__ IA, const int* __restrict__ IB,
              const u16* __restrict__ W1t, const float* __restrict__ B1,
              const u16* __restrict__ W2t, const float* __restrict__ B2,
              float* __restrict__ Yf, u16* __restrict__ Yb0, u16* __restrict__ Yb1)
{
  constexpr int THREADS = WAVES * 64;
  constexpr int MT  = RT / 16;
  constexpr int CW  = WAVES / MT;
  constexpr int NC1 = (HID / 16) / CW;
  constexpr int NC2 = (NOUT / 16) / CW;
  constexpr int KCH = K1 / 8;
  constexpr int SAB = RT * K1 * 2;
  constexpr int SHB = RT * (HID + 8) * 2;
  __shared__ __align__(16) char smem[(SAB > SHB ? SAB : SHB)];
  u16* sA = (u16*)smem;
  u16* sH = (u16*)smem;

  const int tid = threadIdx.x;
  const int rowBase = blockIdx.x * RT;

  // ---- stage A panel, XOR-swizzled rows ----
  for (int ch = tid; ch < RT * KCH; ch += THREADS) {
    const int r = ch / KCH, kc = ch - r * KCH;
    const int gr = rowBase + r, k0 = kc * 8;
    short8 pk;
    if constexpr (IN_MODE == 4) {
      const float* Xf  = (const float*)X;
      const float* P2f = (const float*)P2;
      if (k0 < 128)      pk = cvt8(&Xf[(size_t)gr * 128 + k0]);
      else if (P2f)      pk = cvt8(&P2f[(size_t)gr * 128 + (k0 - 128)]);
      else { pk = short8{0,0,0,0,0,0,0,0}; }
    } else if constexpr (IN_MODE == 1) {
      const u16* Hb = (const u16*)X;
      if (k0 < 64)       pk = *(const short8*)&Hb[(size_t)IA[gr] * 64 + k0];
      else if (k0 < 128) pk = *(const short8*)&Hb[(size_t)IB[gr] * 64 + (k0 - 64)];
      else               pk = *(const short8*)&CB[(size_t)gr * 128 + (k0 - 128)];
    } else { // 3
      const u16* Hb = (const u16*)X;
      const u16* A0 = (const u16*)P2;
      const u16* A1 = (const u16*)P3;
      if (k0 < 64)       pk = *(const short8*)&Hb[(size_t)gr * 64 + k0];
      else if (k0 < 192) pk = *(const short8*)&A0[(size_t)gr * 128 + (k0 - 64)];
      else               pk = *(const short8*)&A1[(size_t)gr * 128 + (k0 - 192)];
    }
    const int byte = ((r * K1 + k0) * 2) ^ ((r & 7) << 4);
    *(short8*)((char*)sA + byte) = pk;
  }
  __syncthreads();

  const int wid = tid >> 6, lane = tid & 63;
  const int l15 = lane & 15, lg = lane >> 4;
  const int mt = wid / CW;          // this wave's m-tile (row block)
  const int cg = wid % CW;          // this wave's column group
  const int arow = mt * 16 + l15;   // A-operand row for this wave

  // ---- layer 1, all dirs (sA stays live only here) ----
  floatx4 acc1[1 + DUAL][NC1];
  #pragma unroll
  for (int d = 0; d <= DUAL; ++d)
    #pragma unroll
    for (int n = 0; n < NC1; ++n) acc1[d][n] = floatx4{0.f,0.f,0.f,0.f};

  #pragma unroll 2
  for (int kk = 0; kk < K1 / 32; ++kk) {
    short8 bw[NC1];
    #pragma unroll
    for (int n = 0; n < NC1; ++n) {
      const int col = (cg * NC1 + n) * 16 + l15;
      bw[n] = *(const short8*)&W1t[(size_t)col * K1 + kk * 32 + lg * 8];
    }
    #pragma unroll
    for (int d = 0; d <= DUAL; ++d) {
      int k0 = kk * 32 + lg * 8;
      if (DUAL && d && k0 < 128) k0 ^= 64;
      const int byte = ((arow * K1 + k0) * 2) ^ ((arow & 7) << 4);
      const short8 af = *(const short8*)((char*)sA + byte);
      #pragma unroll
      for (int n = 0; n < NC1; ++n)
        acc1[d][n] = __builtin_amdgcn_mfma_f32_16x16x32_bf16(af, bw[n], acc1[d][n], 0, 0, 0);
    }
  }
  __syncthreads();   // sA dead from here; smem becomes sH

  floatx4 accO[NC2];
  #pragma unroll
  for (int n = 0; n < NC2; ++n) accO[n] = floatx4{0.f,0.f,0.f,0.f};

  #pragma unroll
  for (int d = 0; d <= DUAL; ++d) {
    // hidden: bias + relu -> bf16 LDS
    #pragma unroll
    for (int n = 0; n < NC1; ++n) {
      const int col = (cg * NC1 + n) * 16 + l15;
      const float b1 = B1[col];
      #pragma unroll
      for (int r = 0; r < 4; ++r) {
        const int row = mt * 16 + lg * 4 + r;
        const float y = acc1[d][n][r] + b1;
        sH[row * (HID + 8) + col] = f2bf(y > 0.f ? y : 0.f);
      }
    }
    __syncthreads();
    if (OUT_MODE == 2 && d == 1) {
      #pragma unroll
      for (int n = 0; n < NC2; ++n) accO[n] = floatx4{0.f,0.f,0.f,0.f};
    }
    #pragma unroll 2
    for (int kk = 0; kk < HID / 32; ++kk) {
      short8 bw2[NC2];
      #pragma unroll
      for (int n = 0; n < NC2; ++n) {
        const int col = (cg * NC2 + n) * 16 + l15;
        bw2[n] = *(const short8*)&W2t[(size_t)col * HID + kk * 32 + lg * 8];
      }
      const short8 af = *(const short8*)&sH[arow * (HID + 8) + kk * 32 + lg * 8];
      #pragma unroll
      for (int n = 0; n < NC2; ++n)
        accO[n] = __builtin_amdgcn_mfma_f32_16x16x32_bf16(af, bw2[n], accO[n], 0, 0, 0);
    }
    if constexpr (OUT_MODE == 2) {
      u16* Y = d ? Yb1 : Yb0;
      #pragma unroll
      for (int n = 0; n < NC2; ++n) {
        const int col = (cg * NC2 + n) * 16 + l15;
        const float b2 = B2[col];
        #pragma unroll
        for (int r = 0; r < 4; ++r) {
          const int gr = rowBase + mt * 16 + lg * 4 + r;
          Y[(size_t)gr * NOUT + col] = f2bf(accO[n][r] + b2);
        }
      }
    }
    if (DUAL && d == 0) __syncthreads();   // before overwriting sH
  }

  if constexpr (OUT_MODE != 2) {
    #pragma unroll
    for (int n = 0; n < NC2; ++n) {
      const int col = (cg * NC2 + n) * 16 + l15;
      const float b2 = B2[col] * (float)(1 + DUAL);
      #pragma unroll
      for (int r = 0; r < 4; ++r) {
        const int gr = rowBase + mt * 16 + lg * 4 + r;
        const float y = accO[n][r] + b2;
        if constexpr (OUT_MODE == 1) Yb0[(size_t)gr * NOUT + col] = f2bf(y);
        else                         Yf[(size_t)gr * NOUT + col] = y;
      }
    }
  }
}

// ---------------------------------------------------------------------------
// Pair-local segment-sum scatter: block = pair*2 + dir, 512 threads.
// ---------------------------------------------------------------------------
__global__ __launch_bounds__(512)
void scatter_agg(const u16* __restrict__ MF, const u16* __restrict__ MB,
                 const int* __restrict__ FI, const int* __restrict__ TI,
                 u16* __restrict__ AggF, u16* __restrict__ AggB)
{
  const int pair = blockIdx.x >> 1, dir = blockIdx.x & 1;
  const u16* M  = dir ? MB : MF;
  const int* SI = dir ? FI : TI;
  u16* Agg      = dir ? AggB : AggF;
  const int tid = threadIdx.x;
  __shared__ float sAgg[NPG * 128];

  for (int i = tid; i < NPG * 128; i += 512) sAgg[i] = 0.f;
  __syncthreads();

  for (int i = tid; i < EPG * 32; i += 512) {
    const int edge = i >> 5, cb = i & 31;
    const int er = pair * EPG + edge;
    const int node = SI[er] - pair * NPG;
    const size_t base = (size_t)er * 128 + cb;
    #pragma unroll
    for (int k = 0; k < 4; ++k)
      atomicAdd(&sAgg[node * 128 + cb + 32 * k], bf2f(M[base + 32 * k]));
  }
  __syncthreads();
  unsigned* dst = (unsigned*)(Agg + (size_t)pair * NPG * 128);
  for (int i = tid; i < NPG * 64; i += 512)
    dst[i] = pack2(sAgg[2 * i], sAgg[2 * i + 1]);
}

// ---------------------------------------------------------------------------
// f32 fused MLP (encoders + sinkhorn feature MLPs)
// IN_MODE: 0 plain X  5 q-side rows of e (zero-padded)  6 c-side rows
// OUTBF (SINGLE only): write bf16 to Yb
// ---------------------------------------------------------------------------
template<int K1, int HID, int NOUT, int IN_MODE, int SINGLE, int OUTBF>
__global__ __launch_bounds__(256)
void fused_mlp(const float* __restrict__ X, const float* __restrict__ P1,
               const float* __restrict__ W1, const float* __restrict__ B1,
               const float* __restrict__ W2, const float* __restrict__ B2,
               float* __restrict__ Y, u16* __restrict__ Yb, int maskLen)
{
  constexpr int RT = 32, BK = 32;
  constexpr int J1 = HID / 32;
  constexpr int J2 = NOUT / 32;
  constexpr int BMAX = (HID > NOUT ? HID : NOUT);
  __shared__ float sA[RT * 33];
  __shared__ float sB[BK * BMAX];
  __shared__ float sH[SINGLE ? 1 : RT * (HID + 1)];

  const int t  = threadIdx.x;
  const int tx = t & 31, ty = t >> 5;
  const int rowBase = blockIdx.x * RT;

  float acc[4][J1];
  #pragma unroll
  for (int i = 0; i < 4; ++i)
    #pragma unroll
    for (int j = 0; j < J1; ++j) acc[i][j] = 0.f;

  for (int kb = 0; kb < K1; kb += BK) {
    for (int l = t; l < RT * BK; l += 256) {
      const int r = l >> 5, k = l & 31;
      const int gr = rowBase + r, gk = kb + k;
      float v;
      if constexpr (IN_MODE == 0) {
        v = X[(size_t)gr * K1 + gk];
      } else {
        const int bb = gr >> 8, m = gr & 255;
        constexpr int off = (IN_MODE == 5) ? 0 : EQ_;
        constexpr int len = (IN_MODE == 5) ? EQ_ : EC_;
        v = (m < len) ? P1[((size_t)bb * EPG + off + m) * 128 + gk] : 0.f;
      }
      sA[r * 33 + k] = v;
    }
    for (int l = t * 4; l < BK * HID; l += 1024) {
      *(float4*)&sB[l] = *(const float4*)&W1[(size_t)(kb + l / HID) * HID + (l % HID)];
    }
    __syncthreads();
    #pragma unroll
    for (int k = 0; k < BK; ++k) {
      const float a0 = sA[(ty*4+0)*33+k], a1 = sA[(ty*4+1)*33+k],
                  a2 = sA[(ty*4+2)*33+k], a3 = sA[(ty*4+3)*33+k];
      #pragma unroll
      for (int j = 0; j < J1; ++j) {
        const float bb = sB[k * HID + tx + 32*j];
        acc[0][j] += a0 * bb; acc[1][j] += a1 * bb;
        acc[2][j] += a2 * bb; acc[3][j] += a3 * bb;
      }
    }
    __syncthreads();
  }

  if constexpr (SINGLE) {
    #pragma unroll
    for (int j = 0; j < J1; ++j) {
      const int col = tx + 32*j;
      const float bias = B1[col];
      #pragma unroll
      for (int i = 0; i < 4; ++i) {
        const int gr = rowBase + ty*4 + i;
        if constexpr (OUTBF) Yb[(size_t)gr * HID + col] = f2bf(acc[i][j] + bias);
        else                 Y[(size_t)gr * HID + col] = acc[i][j] + bias;
      }
    }
  } else {
    #pragma unroll
    for (int j = 0; j < J1; ++j) {
      const int col = tx + 32*j;
      const float bias = B1[col];
      #pragma unroll
      for (int i = 0; i < 4; ++i) {
        float y = acc[i][j] + bias;
        sH[(ty*4+i) * (HID+1) + col] = y > 0.f ? y : 0.f;
      }
    }
    __syncthreads();

    float acc2[4][J2];
    #pragma unroll
    for (int i = 0; i < 4; ++i)
      #pragma unroll
      for (int j = 0; j < J2; ++j) acc2[i][j] = 0.f;

    for (int kb = 0; kb < HID; kb += BK) {
      for (int l = t * 4; l < BK * NOUT; l += 1024) {
        *(float4*)&sB[l] = *(const float4*)&W2[(size_t)(kb + l / NOUT) * NOUT + (l % NOUT)];
      }
      __syncthreads();
      #pragma unroll
      for (int k = 0; k < BK; ++k) {
        const float a0 = sH[(ty*4+0)*(HID+1) + kb + k],
                    a1 = sH[(ty*4+1)*(HID+1) + kb + k],
                    a2 = sH[(ty*4+2)*(HID+1) + kb + k],
                    a3 = sH[(ty*4+3)*(HID+1) + kb + k];
        #pragma unroll
        for (int j = 0; j < J2; ++j) {
          const float bb = sB[k * NOUT + tx + 32*j];
          acc2[0][j] += a0 * bb; acc2[1][j] += a1 * bb;
          acc2[2][j] += a2 * bb; acc2[3][j] += a3 * bb;
        }
      }
      __syncthreads();
    }
    #pragma unroll
    for (int j = 0; j < J2; ++j) {
      const int col = tx + 32*j;
      const float bias = B2[col];
      #pragma unroll
      for (int i = 0; i < 4; ++i) {
        const int gr = rowBase + ty*4 + i;
        float y = acc2[i][j] + bias;
        if (maskLen >= 0 && (gr & 255) >= maskLen) y = 0.f;
        Y[(size_t)gr * NOUT + col] = y;
      }
    }
  }
}

// ---------------------------------------------------------------------------
// S[b] = scale * fq[b] @ fc[b]^T  (kept f32: S feeds exp(10*S), error-sensitive)
// ---------------------------------------------------------------------------
__global__ __launch_bounds__(256)
void gemm_nt_scale(const float* __restrict__ A, const float* __restrict__ Bm,
                   float* __restrict__ C, float scale)
{
  const int b = blockIdx.z, qt = blockIdx.x, ct = blockIdx.y;
  __shared__ float sA[64 * 68];
  __shared__ float sB[64 * 68];
  const int t = threadIdx.x;
  const int tx = t & 15, ty = t >> 4;
  const float* Ab = A  + (size_t)b * 16384 + (size_t)qt * 4096;
  const float* Bb = Bm + (size_t)b * 16384 + (size_t)ct * 4096;
  for (int l = t * 4; l < 64 * 64; l += 1024) {
    const int r = l >> 6, d = l & 63;
    *(float4*)&sA[r*68 + d] = *(const float4*)&Ab[r*64 + d];
    *(float4*)&sB[r*68 + d] = *(const float4*)&Bb[r*64 + d];
  }
  __syncthreads();
  float acc[4][4] = {};
  #pragma unroll
  for (int d = 0; d < 64; ++d) {
    float a[4], bb[4];
    #pragma unroll
    for (int i = 0; i < 4; ++i) a[i]  = sA[(ty*4+i)*68 + d];
    #pragma unroll
    for (int j = 0; j < 4; ++j) bb[j] = sB[(tx+16*j)*68 + d];
    #pragma unroll
    for (int i = 0; i < 4; ++i)
      #pragma unroll
      for (int j = 0; j < 4; ++j) acc[i][j] += a[i] * bb[j];
  }
  float* Cb = C + (size_t)b * 65536 + (size_t)(qt*64) * 256 + ct*64;
  #pragma unroll
  for (int i = 0; i < 4; ++i)
    #pragma unroll
    for (int j = 0; j < 4; ++j)
      Cb[(ty*4+i)*256 + tx + 16*j] = acc[i][j] * scale;
}

// ---------------------------------------------------------------------------
// MFMA plan GEMM: Y rows r<maskRows at ((b*RPB+YOFF+r)*128) = op(P[b]) @ V,
// V gathered from e rows (zero-padded past VLEN). P,V converted to bf16 at
// stage; f32 accumulate; f32 output. Block = (rowtile of 64, pair), 256 thr,
// 4 waves; wave = one 16-row m-tile, all 8 col-tiles (acc 32 VGPR).
// TRANSA=0: C[q,d]=sum_c P[q,c]V[c,d];  TRANSA=1: C[c,d]=sum_q P[q,c]V[q,d].
// ---------------------------------------------------------------------------
template<int TRANSA>
__global__ __launch_bounds__(256)
void gemm_plan_mfma(const float* __restrict__ P, const float* __restrict__ E,
                    float* __restrict__ Y, int RPB, int YOFF, int VOFF,
                    int VLEN, int maskRows)
{
  __shared__ u16 sP[64 * 40];    // A chunk [row 64][k 32], stride 40 (16B-aligned rows)
  __shared__ u16 sVT[128 * 40];  // B chunk [d 128][k 32]
  const int b = blockIdx.y, rt = blockIdx.x;
  const int t = threadIdx.x;
  const int wid = t >> 6, lane = t & 63;
  const int l15 = lane & 15, lg = lane >> 4;
  const float* Pb = P + (size_t)b * 65536;

  floatx4 acc[8];
  #pragma unroll
  for (int n = 0; n < 8; ++n) acc[n] = floatx4{0.f,0.f,0.f,0.f};

  for (int kb = 0; kb < 256; kb += 32) {
    // stage A chunk
    if constexpr (TRANSA == 0) {
      for (int l = t; l < 64 * 32; l += 256) {
        const int r = l >> 5, k = l & 31;
        sP[r * 40 + k] = f2bf(Pb[(size_t)(rt * 64 + r) * 256 + kb + k]);
      }
    } else {
      for (int l = t; l < 64 * 32; l += 256) {
        const int q = l >> 6, c = l & 63;   // read 32 q-rows x 64 c, transpose
        sP[c * 40 + q] = f2bf(Pb[(size_t)(kb + q) * 256 + rt * 64 + c]);
      }
    }
    // stage V^T chunk: sVT[d][k] = V[kb+k][d] (zero past VLEN)
    for (int l = t; l < 32 * 128; l += 256) {
      const int k = l >> 7, d = l & 127;
      const int vr = kb + k;
      float v = 0.f;
      if (vr < VLEN) v = E[((size_t)b * EPG + VOFF + vr) * 128 + d];
      sVT[d * 40 + k] = f2bf(v);
    }
    __syncthreads();
    const short8 af = *(const short8*)&sP[(wid * 16 + l15) * 40 + lg * 8];
    #pragma unroll
    for (int n = 0; n < 8; ++n) {
      const short8 bw = *(const short8*)&sVT[(n * 16 + l15) * 40 + lg * 8];
      acc[n] = __builtin_amdgcn_mfma_f32_16x16x32_bf16(af, bw, acc[n], 0, 0, 0);
    }
    __syncthreads();
  }
  #pragma unroll
  for (int n = 0; n < 8; ++n) {
    const int col = n * 16 + l15;
    #pragma unroll
    for (int r = 0; r < 4; ++r) {
      const int row = rt * 64 + wid * 16 + lg * 4 + r;
      if (row < maskRows)
        Y[((size_t)b * RPB + YOFF + row) * 128 + col] = acc[n][r];
    }
  }
}

// ---------------------------------------------------------------------------
// Single-pass fused sinkhorn with exp-free butterflies (round-11 proven).
// ---------------------------------------------------------------------------
__global__ __launch_bounds__(1024)
void sinkhorn_fused(float* __restrict__ S)
{
  const int b = blockIdx.x, t = threadIdx.x;
  float* Sb = S + (size_t)b * 65536;
  const int w = t >> 6, lane = t & 63;
  const int cbase = lane * 4;
  __shared__ float pm[16 * 256], ps[16 * 256];
  __shared__ float su[256], sv[256];
  if (t < 256) sv[t] = 0.f;
  __syncthreads();

  for (int it = 0; it < 10; ++it) {
    const float4 v4 = *(const float4*)&sv[cbase];
    float4 cm = {-1e30f, -1e30f, -1e30f, -1e30f};
    float4 cs = {0.f, 0.f, 0.f, 0.f};
    #pragma unroll 2
    for (int i = 0; i < 16; ++i) {
      const int r = w * 16 + i;
      const float4 s4 = *(const float4*)&Sb[(size_t)r * 256 + cbase];
      const float ax = s4.x + v4.x, ay = s4.y + v4.y;
      const float az = s4.z + v4.z, aw = s4.w + v4.w;
      float m = fmaxf(fmaxf(ax, ay), fmaxf(az, aw));
      #pragma unroll
      for (int off = 32; off; off >>= 1) m = fmaxf(m, __shfl_xor(m, off));
      float s = __expf(ax - m) + __expf(ay - m) + __expf(az - m) + __expf(aw - m);
      #pragma unroll
      for (int off = 32; off; off >>= 1) s += __shfl_xor(s, off);
      const float u = -(m + __logf(s));
      if (lane == 0) su[r] = u;
      lse_online(cm.x, cs.x, s4.x + u);
      lse_online(cm.y, cs.y, s4.y + u);
      lse_online(cm.z, cs.z, s4.z + u);
      lse_online(cm.w, cs.w, s4.w + u);
    }
    *(float4*)&pm[w * 256 + cbase] = cm;
    *(float4*)&ps[w * 256 + cbase] = cs;
    __syncthreads();
    if (t < 256) {
      float m = pm[t];
      #pragma unroll
      for (int k = 1; k < 16; ++k) m = fmaxf(m, pm[k * 256 + t]);
      float s = 0.f;
      #pragma unroll
      for (int k = 0; k < 16; ++k) s += ps[k * 256 + t] * __expf(pm[k * 256 + t] - m);
      sv[t] = -(m + __logf(s));
    }
    __syncthreads();
  }
  for (int i = t; i < 16384; i += 1024) {
    const int row = i >> 6, c4 = (i & 63) * 4;
    float4 s4 = *(float4*)&Sb[(size_t)row * 256 + c4];
    const float uu = su[row];
    const float4 v4 = *(const float4*)&sv[c4];
    s4.x = __expf(s4.x + uu + v4.x);
    s4.y = __expf(s4.y + uu + v4.y);
    s4.z = __expf(s4.z + uu + v4.z);
    s4.w = __expf(s4.w + uu + v4.w);
    *(float4*)&Sb[(size_t)row * 256 + c4] = s4;
  }
}

// ---------------------------------------------------------------------------
// score[b] = -sum_{m<256,d} | (m<EQ ? e_q[m,d] : 0) - pc[m,d] |
// ---------------------------------------------------------------------------
__global__ __launch_bounds__(256)
void escore_kernel(const float* __restrict__ e, const float* __restrict__ pc,
                   float* __restrict__ out)
{
  const int b = blockIdx.x, t = threadIdx.x;
  float acc = 0.f;
  for (int i4 = t; i4 < 8192; i4 += 256) {
    const int flat = i4 * 4;
    const int m = flat >> 7, d = flat & 127;
    float4 p = *(const float4*)&pc[((size_t)b * 256 + m) * 128 + d];
    float4 q = {0.f, 0.f, 0.f, 0.f};
    if (m < EQ_) q = *(const float4*)&e[((size_t)b * EPG + m) * 128 + d];
    acc += fabsf(q.x - p.x) + fabsf(q.y - p.y) + fabsf(q.z - p.z) + fabsf(q.w - p.w);
  }
  __shared__ float red[256];
  red[t] = acc; __syncthreads();
  for (int s2 = 128; s2 > 0; s2 >>= 1) { if (t < s2) red[t] += red[t + s2]; __syncthreads(); }
  if (t == 0) out[b] = -red[0];
}

// ---------------------------------------------------------------------------
extern "C" void kernel_launch(void* const* d_in, const int* in_sizes, int n_in,
                              void* d_out, int out_size, void* d_ws, size_t ws_size,
                              hipStream_t stream)
{
  const float* node_features = (const float*)d_in[0];
  const float* edge_features = (const float*)d_in[1];
  const int*   from_idx      = (const int*)d_in[2];
  const int*   to_idx        = (const int*)d_in[3];
  const float* enc_node_W = (const float*)d_in[4];
  const float* enc_node_b = (const float*)d_in[5];
  const float* enc_edge_W = (const float*)d_in[6];
  const float* enc_edge_b = (const float*)d_in[7];
  const float* msg_W1 = (const float*)d_in[8];
  const float* msg_b1 = (const float*)d_in[9];
  const float* msg_W2 = (const float*)d_in[10];
  const float* msg_b2 = (const float*)d_in[11];
  const float* upd_W1 = (const float*)d_in[12];
  const float* upd_b1 = (const float*)d_in[13];
  const float* upd_W2 = (const float*)d_in[14];
  const float* upd_b2 = (const float*)d_in[15];
  const float* int_W1 = (const float*)d_in[16];
  const float* int_b1 = (const float*)d_in[17];
  const float* int_W2 = (const float*)d_in[18];
  const float* int_b2 = (const float*)d_in[19];
  const float* sink_W1 = (const float*)d_in[20];
  const float* sink_b1 = (const float*)d_in[21];
  const float* sink_W2 = (const float*)d_in[22];
  const float* sink_b2 = (const float*)d_in[23];
  float* out = (float*)d_out;

  // ~224 MB layout (proven). h bf16; aggF/aggB bf16; mf/mb alias e's dead window.
  float* wsf = (float*)d_ws;
  float* hreg = wsf;                              // region: NN*64 f32-sized
  float* e   = hreg + (size_t)NN * 64;            // NE*128 f32
  float* shr = e + (size_t)NE * 128;              // NE*128 f32 (inter | agg bf16 | fq+fc | pc)
  float* S   = shr + (size_t)NE * 128;            // BATCH*65536 f32
  u16* comb  = (u16*)(S + (size_t)BATCH * 65536); // NE*128 bf16
  u16* wi1 = comb + (size_t)NE * 128;             // 256x256
  u16* wi2 = wi1 + 65536;                         // 128x256
  u16* wm1 = wi2 + 32768;                         // 256x256
  u16* wm2 = wm1 + 65536;                         // 128x256
  u16* wu1 = wm2 + 32768;                         // 128x320
  u16* wu2 = wu1 + 40960;                         // 64x128

  u16* hb  = (u16*)hreg;                          // NN*64 bf16 node states
  u16* mfb = (u16*)e;                             // aliases e (dead window)
  u16* mbb = mfb + (size_t)NE * 128;

  u16* aggFb = (u16*)shr;                         // NN*128 bf16
  u16* aggBb = aggFb + (size_t)NN * 128;
  float* inter = shr;                             // EPG-row layout (f32)
  float* fq    = shr;
  float* fc    = shr + (size_t)BATCH * 16384;

  // weights -> bf16, transposed [N][K]
  wconv<<<256, 256, 0, stream>>>(int_W1, wi1, 256, 256);
  wconv<<<128, 256, 0, stream>>>(int_W2, wi2, 256, 128);
  wconv<<<256, 256, 0, stream>>>(msg_W1, wm1, 256, 256);
  wconv<<<128, 256, 0, stream>>>(msg_W2, wm2, 256, 128);
  wconv<<<160, 256, 0, stream>>>(upd_W1, wu1, 320, 128);
  wconv<<< 32, 256, 0, stream>>>(upd_W2, wu2, 128, 64);

  for (int ts = 0; ts < 2; ++ts) {
    // encoders (reset hb, e)
    fused_mlp<32,64,64,0,1,1><<<NN/32, 256, 0, stream>>>(
        node_features, nullptr, enc_node_W, enc_node_b, nullptr, nullptr,
        nullptr, hb, -1);
    fused_mlp<32,128,128,0,1,0><<<NE/32, 256, 0, stream>>>(
        edge_features, nullptr, enc_edge_W, enc_edge_b, nullptr, nullptr,
        e, nullptr, -1);

    for (int p = 0; p < 3; ++p) {
      // comb = intMLP([e, inter]) -> bf16   (inter==0 for ts0 and ts1/p0)
      const float* interArg = (ts == 1 && p > 0) ? inter : nullptr;
      mlp_mfma<256,256,128,4,0,1,8,32><<<NE/32, 512, 0, stream>>>(
          e, interArg, nullptr, nullptr, nullptr, nullptr,
          wi1, int_b1, wi2, int_b2, nullptr, comb, nullptr);
      // messages on old h -> mf, mb (bf16, in e's dead storage), both dirs
      mlp_mfma<256,256,128,1,1,2,8,32><<<NE/32, 512, 0, stream>>>(
          hb, nullptr, nullptr, comb, from_idx, to_idx,
          wm1, msg_b1, wm2, msg_b2, nullptr, mfb, mbb);
      // pair-local segment sums (LDS), both dirs as blocks -> bf16 agg
      scatter_agg<<<BATCH*2, 512, 0, stream>>>(mfb, mbb, from_idx, to_idx, aggFb, aggBb);
      // node update (in place, bf16)
      mlp_mfma<320,128,64,3,0,1,4,32><<<NN/32, 256, 0, stream>>>(
          hb, aggFb, aggBb, nullptr, nullptr, nullptr,
          wu1, upd_b1, wu2, upd_b2, nullptr, hb, nullptr);
      // e = mf2 + mb2 with updated h (dual-direction sum; overwrites mf/mb)
      mlp_mfma<256,256,128,1,1,0,8,32><<<NE/32, 512, 0, stream>>>(
          hb, nullptr, nullptr, comb, from_idx, to_idx,
          wm1, msg_b1, wm2, msg_b2, e, nullptr, nullptr);
      // interaction features from last time step's transport plan (MFMA)
      if (ts == 1 && p < 2) {
        gemm_plan_mfma<0><<<dim3(4, BATCH), 256, 0, stream>>>(
            S, e, inter, EPG, 0,   EQ_, EC_, EQ_);
        gemm_plan_mfma<1><<<dim3(4, BATCH), 256, 0, stream>>>(
            S, e, inter, EPG, EQ_, 0,   EQ_, EC_);
      }
    }
    // sinkhorn features + plan
    fused_mlp<128,64,64,5,0,0><<<BATCH*8, 256, 0, stream>>>(
        nullptr, e, sink_W1, sink_b1, sink_W2, sink_b2, fq, nullptr, EQ_);
    fused_mlp<128,64,64,6,0,0><<<BATCH*8, 256, 0, stream>>>(
        nullptr, e, sink_W1, sink_b1, sink_W2, sink_b2, fc, nullptr, EC_);
    gemm_nt_scale<<<dim3(4,4,BATCH), 256, 0, stream>>>(fq, fc, S, 10.0f);
    sinkhorn_fused<<<BATCH, 1024, 0, stream>>>(S);   // S := plan
  }

  // final score
  gemm_plan_mfma<0><<<dim3(4, BATCH), 256, 0, stream>>>(S, e, shr, 256, 0, EQ_, EC_, 256);
  escore_kernel<<<BATCH, 256, 0, stream>>>(e, shr, out);
}

// Round 16
// 4036.023 us; speedup vs baseline: 1.5198x; 1.4360x over previous
//
#include <hip/hip_runtime.h>
#include <math.h>

constexpr int BATCH = 256;
constexpr int EQ_   = 192;
constexpr int EC_   = 240;
constexpr int EPG   = 432;   // edges per pair
constexpr int NPG   = 216;   // nodes per pair
constexpr int NN    = BATCH * NPG;   // 55296
constexpr int NE    = BATCH * EPG;   // 110592

typedef __attribute__((ext_vector_type(8))) short short8;
typedef __attribute__((ext_vector_type(4))) float floatx4;
typedef unsigned short u16;

__device__ __forceinline__ u16 f2bf(float x) {
  union { float f; unsigned u; } c; c.f = x;
  const unsigned r = (c.u + 0x7FFFu + ((c.u >> 16) & 1u)) >> 16;
  return (u16)r;
}
__device__ __forceinline__ float bf2f(u16 x) {
  union { unsigned u; float f; } c; c.u = ((unsigned)x) << 16;
  return c.f;
}
__device__ __forceinline__ unsigned pack2(float a, float b) {
  return (unsigned)f2bf(a) | ((unsigned)f2bf(b) << 16);
}
__device__ __forceinline__ short8 cvt8(const float* __restrict__ p) {
  const float4 a = *(const float4*)p;
  const float4 b = *(const float4*)(p + 4);
  short8 o;
  o[0]=(short)f2bf(a.x); o[1]=(short)f2bf(a.y); o[2]=(short)f2bf(a.z); o[3]=(short)f2bf(a.w);
  o[4]=(short)f2bf(b.x); o[5]=(short)f2bf(b.y); o[6]=(short)f2bf(b.z); o[7]=(short)f2bf(b.w);
  return o;
}

__device__ __forceinline__ void lse_online(float& m, float& s, float tt) {
  if (tt > m) { s = s * __expf(m - tt) + 1.f; m = tt; }
  else        { s += __expf(tt - m); }
}

// ---------------------------------------------------------------------------
// weight transpose + f32->bf16:  out[n*K+k] = bf16(W[k*N+n])
// ---------------------------------------------------------------------------
__global__ __launch_bounds__(256)
void wconv(const float* __restrict__ W, u16* __restrict__ out, int K, int N)
{
  const int i = blockIdx.x * 256 + threadIdx.x;
  if (i < K * N) {
    const int n = i / K, k = i - n * K;
    out[i] = f2bf(W[(size_t)k * N + n]);
  }
}

// ---------------------------------------------------------------------------
// MFMA fused 2-layer MLP — EXACT round-12 m-loop variant (measured 4181us).
// Round-14/15 "generalized" rewrites of this kernel regressed 15-47% at
// identical FLOPs: the 2-m-tile loop's dual independent af chains schedule
// better. DO NOT restructure again without isolated A/B.
// IN_MODE: 1 [hb[IA],hb[IB],comb]  3 [hb,aggFb,aggBb]  4 [e(f32), inter(f32|0)]
// OUT_MODE: 0 f32 write (sum)  1 bf16 write (sum)  2 bf16 per-dir -> Yb0/Yb1
// ---------------------------------------------------------------------------
template<int K1, int HID, int NOUT, int IN_MODE, int DUAL, int OUT_MODE, int WAVES>
__global__ __launch_bounds__(WAVES * 64, 4)
void mlp_mfma(const void* __restrict__ X, const void* __restrict__ P2,
              const void* __restrict__ P3, const u16* __restrict__ CB,
              const int* __restrict__ IA, const int* __restrict__ IB,
              const u16* __restrict__ W1t, const float* __restrict__ B1,
              const u16* __restrict__ W2t, const float* __restrict__ B2,
              float* __restrict__ Yf, u16* __restrict__ Yb0, u16* __restrict__ Yb1)
{
  constexpr int RT  = 32;
  constexpr int THREADS = WAVES * 64;
  constexpr int KCH = K1 / 8;
  constexpr int NT1 = HID / (WAVES * 16);
  constexpr int NT2 = (NOUT / (WAVES * 16) > 0) ? NOUT / (WAVES * 16) : 1;
  constexpr int SAB = RT * K1 * 2;
  constexpr int SHB = RT * (HID + 8) * 2;
  __shared__ __align__(16) char smem[(SAB > SHB ? SAB : SHB)];
  u16* sA = (u16*)smem;
  u16* sH = (u16*)smem;

  const int tid = threadIdx.x;
  const int rowBase = blockIdx.x * RT;

  // ---- stage A panel, XOR-swizzled rows ----
  for (int ch = tid; ch < RT * KCH; ch += THREADS) {
    const int r = ch / KCH, kc = ch - r * KCH;
    const int gr = rowBase + r, k0 = kc * 8;
    short8 pk;
    if constexpr (IN_MODE == 4) {
      const float* Xf  = (const float*)X;
      const float* P2f = (const float*)P2;
      if (k0 < 128)      pk = cvt8(&Xf[(size_t)gr * 128 + k0]);
      else if (P2f)      pk = cvt8(&P2f[(size_t)gr * 128 + (k0 - 128)]);
      else { pk = short8{0,0,0,0,0,0,0,0}; }
    } else if constexpr (IN_MODE == 1) {
      const u16* Hb = (const u16*)X;
      if (k0 < 64)       pk = *(const short8*)&Hb[(size_t)IA[gr] * 64 + k0];
      else if (k0 < 128) pk = *(const short8*)&Hb[(size_t)IB[gr] * 64 + (k0 - 64)];
      else               pk = *(const short8*)&CB[(size_t)gr * 128 + (k0 - 128)];
    } else { // 3
      const u16* Hb = (const u16*)X;
      const u16* A0 = (const u16*)P2;
      const u16* A1 = (const u16*)P3;
      if (k0 < 64)       pk = *(const short8*)&Hb[(size_t)gr * 64 + k0];
      else if (k0 < 192) pk = *(const short8*)&A0[(size_t)gr * 128 + (k0 - 64)];
      else               pk = *(const short8*)&A1[(size_t)gr * 128 + (k0 - 192)];
    }
    const int byte = ((r * K1 + k0) * 2) ^ ((r & 7) << 4);
    *(short8*)((char*)sA + byte) = pk;
  }
  __syncthreads();

  const int wid = tid >> 6, lane = tid & 63;
  const int l15 = lane & 15, lg = lane >> 4;

  // ---- layer 1, all dirs (sA stays live only here) ----
  floatx4 acc1[1 + DUAL][2][NT1];
  #pragma unroll
  for (int d = 0; d <= DUAL; ++d)
    #pragma unroll
    for (int m = 0; m < 2; ++m)
      #pragma unroll
      for (int n = 0; n < NT1; ++n) acc1[d][m][n] = floatx4{0.f,0.f,0.f,0.f};

  #pragma unroll 2
  for (int kk = 0; kk < K1 / 32; ++kk) {
    short8 bw[NT1];
    #pragma unroll
    for (int n = 0; n < NT1; ++n) {
      const int col = wid * (HID / WAVES) + n * 16 + l15;
      bw[n] = *(const short8*)&W1t[(size_t)col * K1 + kk * 32 + lg * 8];
    }
    #pragma unroll
    for (int d = 0; d <= DUAL; ++d) {
      int k0 = kk * 32 + lg * 8;
      if (DUAL && d && k0 < 128) k0 ^= 64;
      #pragma unroll
      for (int m = 0; m < 2; ++m) {
        const int r = m * 16 + l15;
        const int byte = ((r * K1 + k0) * 2) ^ ((r & 7) << 4);
        const short8 af = *(const short8*)((char*)sA + byte);
        #pragma unroll
        for (int n = 0; n < NT1; ++n)
          acc1[d][m][n] = __builtin_amdgcn_mfma_f32_16x16x32_bf16(af, bw[n], acc1[d][m][n], 0, 0, 0);
      }
    }
  }
  __syncthreads();   // sA dead from here; smem becomes sH

  floatx4 accO[2][NT2];
  #pragma unroll
  for (int m = 0; m < 2; ++m)
    #pragma unroll
    for (int n = 0; n < NT2; ++n) accO[m][n] = floatx4{0.f,0.f,0.f,0.f};

  #pragma unroll
  for (int d = 0; d <= DUAL; ++d) {
    // hidden: bias + relu -> bf16 LDS
    #pragma unroll
    for (int n = 0; n < NT1; ++n) {
      const int col = wid * (HID / WAVES) + n * 16 + l15;
      const float b1 = B1[col];
      #pragma unroll
      for (int m = 0; m < 2; ++m)
        #pragma unroll
        for (int r = 0; r < 4; ++r) {
          const int row = m * 16 + lg * 4 + r;
          const float y = acc1[d][m][n][r] + b1;
          sH[row * (HID + 8) + col] = f2bf(y > 0.f ? y : 0.f);
        }
    }
    __syncthreads();
    if (OUT_MODE == 2 && d == 1) {
      #pragma unroll
      for (int m = 0; m < 2; ++m)
        #pragma unroll
        for (int n = 0; n < NT2; ++n) accO[m][n] = floatx4{0.f,0.f,0.f,0.f};
    }
    #pragma unroll 2
    for (int kk = 0; kk < HID / 32; ++kk) {
      short8 bw2[NT2];
      #pragma unroll
      for (int n = 0; n < NT2; ++n) {
        const int col = wid * (NOUT / WAVES) + n * 16 + l15;
        bw2[n] = *(const short8*)&W2t[(size_t)col * HID + kk * 32 + lg * 8];
      }
      #pragma unroll
      for (int m = 0; m < 2; ++m) {
        const short8 af = *(const short8*)&sH[(m * 16 + l15) * (HID + 8) + kk * 32 + lg * 8];
        #pragma unroll
        for (int n = 0; n < NT2; ++n)
          accO[m][n] = __builtin_amdgcn_mfma_f32_16x16x32_bf16(af, bw2[n], accO[m][n], 0, 0, 0);
      }
    }
    if constexpr (OUT_MODE == 2) {
      u16* Y = d ? Yb1 : Yb0;
      #pragma unroll
      for (int n = 0; n < NT2; ++n) {
        const int col = wid * (NOUT / WAVES) + n * 16 + l15;
        const float b2 = B2[col];
        #pragma unroll
        for (int m = 0; m < 2; ++m)
          #pragma unroll
          for (int r = 0; r < 4; ++r) {
            const int gr = rowBase + m * 16 + lg * 4 + r;
            Y[(size_t)gr * NOUT + col] = f2bf(accO[m][n][r] + b2);
          }
      }
    }
    if (DUAL && d == 0) __syncthreads();   // before overwriting sH
  }

  if constexpr (OUT_MODE != 2) {
    #pragma unroll
    for (int n = 0; n < NT2; ++n) {
      const int col = wid * (NOUT / WAVES) + n * 16 + l15;
      const float b2 = B2[col] * (float)(1 + DUAL);
      #pragma unroll
      for (int m = 0; m < 2; ++m)
        #pragma unroll
        for (int r = 0; r < 4; ++r) {
          const int gr = rowBase + m * 16 + lg * 4 + r;
          const float y = accO[m][n][r] + b2;
          if constexpr (OUT_MODE == 1) Yb0[(size_t)gr * NOUT + col] = f2bf(y);
          else                         Yf[(size_t)gr * NOUT + col] = y;
        }
    }
  }
}

// ---------------------------------------------------------------------------
// Pair-local segment-sum scatter: block = pair*2 + dir, 512 threads.
// ---------------------------------------------------------------------------
__global__ __launch_bounds__(512)
void scatter_agg(const u16* __restrict__ MF, const u16* __restrict__ MB,
                 const int* __restrict__ FI, const int* __restrict__ TI,
                 u16* __restrict__ AggF, u16* __restrict__ AggB)
{
  const int pair = blockIdx.x >> 1, dir = blockIdx.x & 1;
  const u16* M  = dir ? MB : MF;
  const int* SI = dir ? FI : TI;
  u16* Agg      = dir ? AggB : AggF;
  const int tid = threadIdx.x;
  __shared__ float sAgg[NPG * 128];

  for (int i = tid; i < NPG * 128; i += 512) sAgg[i] = 0.f;
  __syncthreads();

  for (int i = tid; i < EPG * 32; i += 512) {
    const int edge = i >> 5, cb = i & 31;
    const int er = pair * EPG + edge;
    const int node = SI[er] - pair * NPG;
    const size_t base = (size_t)er * 128 + cb;
    #pragma unroll
    for (int k = 0; k < 4; ++k)
      atomicAdd(&sAgg[node * 128 + cb + 32 * k], bf2f(M[base + 32 * k]));
  }
  __syncthreads();
  unsigned* dst = (unsigned*)(Agg + (size_t)pair * NPG * 128);
  for (int i = tid; i < NPG * 64; i += 512)
    dst[i] = pack2(sAgg[2 * i], sAgg[2 * i + 1]);
}

// ---------------------------------------------------------------------------
// f32 fused MLP (encoders + sinkhorn feature MLPs)
// IN_MODE: 0 plain X  5 q-side rows of e (zero-padded)  6 c-side rows
// OUTBF (SINGLE only): write bf16 to Yb
// ---------------------------------------------------------------------------
template<int K1, int HID, int NOUT, int IN_MODE, int SINGLE, int OUTBF>
__global__ __launch_bounds__(256)
void fused_mlp(const float* __restrict__ X, const float* __restrict__ P1,
               const float* __restrict__ W1, const float* __restrict__ B1,
               const float* __restrict__ W2, const float* __restrict__ B2,
               float* __restrict__ Y, u16* __restrict__ Yb, int maskLen)
{
  constexpr int RT = 32, BK = 32;
  constexpr int J1 = HID / 32;
  constexpr int J2 = NOUT / 32;
  constexpr int BMAX = (HID > NOUT ? HID : NOUT);
  __shared__ float sA[RT * 33];
  __shared__ float sB[BK * BMAX];
  __shared__ float sH[SINGLE ? 1 : RT * (HID + 1)];

  const int t  = threadIdx.x;
  const int tx = t & 31, ty = t >> 5;
  const int rowBase = blockIdx.x * RT;

  float acc[4][J1];
  #pragma unroll
  for (int i = 0; i < 4; ++i)
    #pragma unroll
    for (int j = 0; j < J1; ++j) acc[i][j] = 0.f;

  for (int kb = 0; kb < K1; kb += BK) {
    for (int l = t; l < RT * BK; l += 256) {
      const int r = l >> 5, k = l & 31;
      const int gr = rowBase + r, gk = kb + k;
      float v;
      if constexpr (IN_MODE == 0) {
        v = X[(size_t)gr * K1 + gk];
      } else {
        const int bb = gr >> 8, m = gr & 255;
        constexpr int off = (IN_MODE == 5) ? 0 : EQ_;
        constexpr int len = (IN_MODE == 5) ? EQ_ : EC_;
        v = (m < len) ? P1[((size_t)bb * EPG + off + m) * 128 + gk] : 0.f;
      }
      sA[r * 33 + k] = v;
    }
    for (int l = t * 4; l < BK * HID; l += 1024) {
      *(float4*)&sB[l] = *(const float4*)&W1[(size_t)(kb + l / HID) * HID + (l % HID)];
    }
    __syncthreads();
    #pragma unroll
    for (int k = 0; k < BK; ++k) {
      const float a0 = sA[(ty*4+0)*33+k], a1 = sA[(ty*4+1)*33+k],
                  a2 = sA[(ty*4+2)*33+k], a3 = sA[(ty*4+3)*33+k];
      #pragma unroll
      for (int j = 0; j < J1; ++j) {
        const float bb = sB[k * HID + tx + 32*j];
        acc[0][j] += a0 * bb; acc[1][j] += a1 * bb;
        acc[2][j] += a2 * bb; acc[3][j] += a3 * bb;
      }
    }
    __syncthreads();
  }

  if constexpr (SINGLE) {
    #pragma unroll
    for (int j = 0; j < J1; ++j) {
      const int col = tx + 32*j;
      const float bias = B1[col];
      #pragma unroll
      for (int i = 0; i < 4; ++i) {
        const int gr = rowBase + ty*4 + i;
        if constexpr (OUTBF) Yb[(size_t)gr * HID + col] = f2bf(acc[i][j] + bias);
        else                 Y[(size_t)gr * HID + col] = acc[i][j] + bias;
      }
    }
  } else {
    #pragma unroll
    for (int j = 0; j < J1; ++j) {
      const int col = tx + 32*j;
      const float bias = B1[col];
      #pragma unroll
      for (int i = 0; i < 4; ++i) {
        float y = acc[i][j] + bias;
        sH[(ty*4+i) * (HID+1) + col] = y > 0.f ? y : 0.f;
      }
    }
    __syncthreads();

    float acc2[4][J2];
    #pragma unroll
    for (int i = 0; i < 4; ++i)
      #pragma unroll
      for (int j = 0; j < J2; ++j) acc2[i][j] = 0.f;

    for (int kb = 0; kb < HID; kb += BK) {
      for (int l = t * 4; l < BK * NOUT; l += 1024) {
        *(float4*)&sB[l] = *(const float4*)&W2[(size_t)(kb + l / NOUT) * NOUT + (l % NOUT)];
      }
      __syncthreads();
      #pragma unroll
      for (int k = 0; k < BK; ++k) {
        const float a0 = sH[(ty*4+0)*(HID+1) + kb + k],
                    a1 = sH[(ty*4+1)*(HID+1) + kb + k],
                    a2 = sH[(ty*4+2)*(HID+1) + kb + k],
                    a3 = sH[(ty*4+3)*(HID+1) + kb + k];
        #pragma unroll
        for (int j = 0; j < J2; ++j) {
          const float bb = sB[k * NOUT + tx + 32*j];
          acc2[0][j] += a0 * bb; acc2[1][j] += a1 * bb;
          acc2[2][j] += a2 * bb; acc2[3][j] += a3 * bb;
        }
      }
      __syncthreads();
    }
    #pragma unroll
    for (int j = 0; j < J2; ++j) {
      const int col = tx + 32*j;
      const float bias = B2[col];
      #pragma unroll
      for (int i = 0; i < 4; ++i) {
        const int gr = rowBase + ty*4 + i;
        float y = acc2[i][j] + bias;
        if (maskLen >= 0 && (gr & 255) >= maskLen) y = 0.f;
        Y[(size_t)gr * NOUT + col] = y;
      }
    }
  }
}

// ---------------------------------------------------------------------------
// S[b] = scale * fq[b] @ fc[b]^T  (kept f32: S feeds exp(10*S), error-sensitive)
// ---------------------------------------------------------------------------
__global__ __launch_bounds__(256)
void gemm_nt_scale(const float* __restrict__ A, const float* __restrict__ Bm,
                   float* __restrict__ C, float scale)
{
  const int b = blockIdx.z, qt = blockIdx.x, ct = blockIdx.y;
  __shared__ float sA[64 * 68];
  __shared__ float sB[64 * 68];
  const int t = threadIdx.x;
  const int tx = t & 15, ty = t >> 4;
  const float* Ab = A  + (size_t)b * 16384 + (size_t)qt * 4096;
  const float* Bb = Bm + (size_t)b * 16384 + (size_t)ct * 4096;
  for (int l = t * 4; l < 64 * 64; l += 1024) {
    const int r = l >> 6, d = l & 63;
    *(float4*)&sA[r*68 + d] = *(const float4*)&Ab[r*64 + d];
    *(float4*)&sB[r*68 + d] = *(const float4*)&Bb[r*64 + d];
  }
  __syncthreads();
  float acc[4][4] = {};
  #pragma unroll
  for (int d = 0; d < 64; ++d) {
    float a[4], bb[4];
    #pragma unroll
    for (int i = 0; i < 4; ++i) a[i]  = sA[(ty*4+i)*68 + d];
    #pragma unroll
    for (int j = 0; j < 4; ++j) bb[j] = sB[(tx+16*j)*68 + d];
    #pragma unroll
    for (int i = 0; i < 4; ++i)
      #pragma unroll
      for (int j = 0; j < 4; ++j) acc[i][j] += a[i] * bb[j];
  }
  float* Cb = C + (size_t)b * 65536 + (size_t)(qt*64) * 256 + ct*64;
  #pragma unroll
  for (int i = 0; i < 4; ++i)
    #pragma unroll
    for (int j = 0; j < 4; ++j)
      Cb[(ty*4+i)*256 + tx + 16*j] = acc[i][j] * scale;
}

// ---------------------------------------------------------------------------
// MFMA plan GEMM (the ONLY change vs the 4181us round-12 state; correctness
// already proven in round 15 at absmax 512): Y = op(P[b]) @ V, V gathered
// from e rows (zero-padded past VLEN). bf16 staged, f32 accum, f32 out.
// ---------------------------------------------------------------------------
template<int TRANSA>
__global__ __launch_bounds__(256)
void gemm_plan_mfma(const float* __restrict__ P, const float* __restrict__ E,
                    float* __restrict__ Y, int RPB, int YOFF, int VOFF,
                    int VLEN, int maskRows)
{
  __shared__ u16 sP[64 * 40];    // A chunk [row 64][k 32], stride 40
  __shared__ u16 sVT[128 * 40];  // B chunk [d 128][k 32]
  const int b = blockIdx.y, rt = blockIdx.x;
  const int t = threadIdx.x;
  const int wid = t >> 6, lane = t & 63;
  const int l15 = lane & 15, lg = lane >> 4;
  const float* Pb = P + (size_t)b * 65536;

  floatx4 acc[8];
  #pragma unroll
  for (int n = 0; n < 8; ++n) acc[n] = floatx4{0.f,0.f,0.f,0.f};

  for (int kb = 0; kb < 256; kb += 32) {
    if constexpr (TRANSA == 0) {
      for (int l = t; l < 64 * 32; l += 256) {
        const int r = l >> 5, k = l & 31;
        sP[r * 40 + k] = f2bf(Pb[(size_t)(rt * 64 + r) * 256 + kb + k]);
      }
    } else {
      for (int l = t; l < 64 * 32; l += 256) {
        const int q = l >> 6, c = l & 63;
        sP[c * 40 + q] = f2bf(Pb[(size_t)(kb + q) * 256 + rt * 64 + c]);
      }
    }
    for (int l = t; l < 32 * 128; l += 256) {
      const int k = l >> 7, d = l & 127;
      const int vr = kb + k;
      float v = 0.f;
      if (vr < VLEN) v = E[((size_t)b * EPG + VOFF + vr) * 128 + d];
      sVT[d * 40 + k] = f2bf(v);
    }
    __syncthreads();
    const short8 af = *(const short8*)&sP[(wid * 16 + l15) * 40 + lg * 8];
    #pragma unroll
    for (int n = 0; n < 8; ++n) {
      const short8 bw = *(const short8*)&sVT[(n * 16 + l15) * 40 + lg * 8];
      acc[n] = __builtin_amdgcn_mfma_f32_16x16x32_bf16(af, bw, acc[n], 0, 0, 0);
    }
    __syncthreads();
  }
  #pragma unroll
  for (int n = 0; n < 8; ++n) {
    const int col = n * 16 + l15;
    #pragma unroll
    for (int r = 0; r < 4; ++r) {
      const int row = rt * 64 + wid * 16 + lg * 4 + r;
      if (row < maskRows)
        Y[((size_t)b * RPB + YOFF + row) * 128 + col] = acc[n][r];
    }
  }
}

// ---------------------------------------------------------------------------
// Single-pass fused sinkhorn with exp-free butterflies (round-11 proven).
// ---------------------------------------------------------------------------
__global__ __launch_bounds__(1024)
void sinkhorn_fused(float* __restrict__ S)
{
  const int b = blockIdx.x, t = threadIdx.x;
  float* Sb = S + (size_t)b * 65536;
  const int w = t >> 6, lane = t & 63;
  const int cbase = lane * 4;
  __shared__ float pm[16 * 256], ps[16 * 256];
  __shared__ float su[256], sv[256];
  if (t < 256) sv[t] = 0.f;
  __syncthreads();

  for (int it = 0; it < 10; ++it) {
    const float4 v4 = *(const float4*)&sv[cbase];
    float4 cm = {-1e30f, -1e30f, -1e30f, -1e30f};
    float4 cs = {0.f, 0.f, 0.f, 0.f};
    #pragma unroll 2
    for (int i = 0; i < 16; ++i) {
      const int r = w * 16 + i;
      const float4 s4 = *(const float4*)&Sb[(size_t)r * 256 + cbase];
      const float ax = s4.x + v4.x, ay = s4.y + v4.y;
      const float az = s4.z + v4.z, aw = s4.w + v4.w;
      float m = fmaxf(fmaxf(ax, ay), fmaxf(az, aw));
      #pragma unroll
      for (int off = 32; off; off >>= 1) m = fmaxf(m, __shfl_xor(m, off));
      float s = __expf(ax - m) + __expf(ay - m) + __expf(az - m) + __expf(aw - m);
      #pragma unroll
      for (int off = 32; off; off >>= 1) s += __shfl_xor(s, off);
      const float u = -(m + __logf(s));
      if (lane == 0) su[r] = u;
      lse_online(cm.x, cs.x, s4.x + u);
      lse_online(cm.y, cs.y, s4.y + u);
      lse_online(cm.z, cs.z, s4.z + u);
      lse_online(cm.w, cs.w, s4.w + u);
    }
    *(float4*)&pm[w * 256 + cbase] = cm;
    *(float4*)&ps[w * 256 + cbase] = cs;
    __syncthreads();
    if (t < 256) {
      float m = pm[t];
      #pragma unroll
      for (int k = 1; k < 16; ++k) m = fmaxf(m, pm[k * 256 + t]);
      float s = 0.f;
      #pragma unroll
      for (int k = 0; k < 16; ++k) s += ps[k * 256 + t] * __expf(pm[k * 256 + t] - m);
      sv[t] = -(m + __logf(s));
    }
    __syncthreads();
  }
  for (int i = t; i < 16384; i += 1024) {
    const int row = i >> 6, c4 = (i & 63) * 4;
    float4 s4 = *(float4*)&Sb[(size_t)row * 256 + c4];
    const float uu = su[row];
    const float4 v4 = *(const float4*)&sv[c4];
    s4.x = __expf(s4.x + uu + v4.x);
    s4.y = __expf(s4.y + uu + v4.y);
    s4.z = __expf(s4.z + uu + v4.z);
    s4.w = __expf(s4.w + uu + v4.w);
    *(float4*)&Sb[(size_t)row * 256 + c4] = s4;
  }
}

// ---------------------------------------------------------------------------
// score[b] = -sum_{m<256,d} | (m<EQ ? e_q[m,d] : 0) - pc[m,d] |
// ---------------------------------------------------------------------------
__global__ __launch_bounds__(256)
void escore_kernel(const float* __restrict__ e, const float* __restrict__ pc,
                   float* __restrict__ out)
{
  const int b = blockIdx.x, t = threadIdx.x;
  float acc = 0.f;
  for (int i4 = t; i4 < 8192; i4 += 256) {
    const int flat = i4 * 4;
    const int m = flat >> 7, d = flat & 127;
    float4 p = *(const float4*)&pc[((size_t)b * 256 + m) * 128 + d];
    float4 q = {0.f, 0.f, 0.f, 0.f};
    if (m < EQ_) q = *(const float4*)&e[((size_t)b * EPG + m) * 128 + d];
    acc += fabsf(q.x - p.x) + fabsf(q.y - p.y) + fabsf(q.z - p.z) + fabsf(q.w - p.w);
  }
  __shared__ float red[256];
  red[t] = acc; __syncthreads();
  for (int s2 = 128; s2 > 0; s2 >>= 1) { if (t < s2) red[t] += red[t + s2]; __syncthreads(); }
  if (t == 0) out[b] = -red[0];
}

// ---------------------------------------------------------------------------
extern "C" void kernel_launch(void* const* d_in, const int* in_sizes, int n_in,
                              void* d_out, int out_size, void* d_ws, size_t ws_size,
                              hipStream_t stream)
{
  const float* node_features = (const float*)d_in[0];
  const float* edge_features = (const float*)d_in[1];
  const int*   from_idx      = (const int*)d_in[2];
  const int*   to_idx        = (const int*)d_in[3];
  const float* enc_node_W = (const float*)d_in[4];
  const float* enc_node_b = (const float*)d_in[5];
  const float* enc_edge_W = (const float*)d_in[6];
  const float* enc_edge_b = (const float*)d_in[7];
  const float* msg_W1 = (const float*)d_in[8];
  const float* msg_b1 = (const float*)d_in[9];
  const float* msg_W2 = (const float*)d_in[10];
  const float* msg_b2 = (const float*)d_in[11];
  const float* upd_W1 = (const float*)d_in[12];
  const float* upd_b1 = (const float*)d_in[13];
  const float* upd_W2 = (const float*)d_in[14];
  const float* upd_b2 = (const float*)d_in[15];
  const float* int_W1 = (const float*)d_in[16];
  const float* int_b1 = (const float*)d_in[17];
  const float* int_W2 = (const float*)d_in[18];
  const float* int_b2 = (const float*)d_in[19];
  const float* sink_W1 = (const float*)d_in[20];
  const float* sink_b1 = (const float*)d_in[21];
  const float* sink_W2 = (const float*)d_in[22];
  const float* sink_b2 = (const float*)d_in[23];
  float* out = (float*)d_out;

  // ~224 MB layout (proven). h bf16; aggF/aggB bf16; mf/mb alias e's dead window.
  float* wsf = (float*)d_ws;
  float* hreg = wsf;                              // region: NN*64 f32-sized
  float* e   = hreg + (size_t)NN * 64;            // NE*128 f32
  float* shr = e + (size_t)NE * 128;              // NE*128 f32 (inter | agg bf16 | fq+fc | pc)
  float* S   = shr + (size_t)NE * 128;            // BATCH*65536 f32
  u16* comb  = (u16*)(S + (size_t)BATCH * 65536); // NE*128 bf16
  u16* wi1 = comb + (size_t)NE * 128;             // 256x256
  u16* wi2 = wi1 + 65536;                         // 128x256
  u16* wm1 = wi2 + 32768;                         // 256x256
  u16* wm2 = wm1 + 65536;                         // 128x256
  u16* wu1 = wm2 + 32768;                         // 128x320
  u16* wu2 = wu1 + 40960;                         // 64x128

  u16* hb  = (u16*)hreg;                          // NN*64 bf16 node states
  u16* mfb = (u16*)e;                             // aliases e (dead window)
  u16* mbb = mfb + (size_t)NE * 128;

  u16* aggFb = (u16*)shr;                         // NN*128 bf16
  u16* aggBb = aggFb + (size_t)NN * 128;
  float* inter = shr;                             // EPG-row layout (f32)
  float* fq    = shr;
  float* fc    = shr + (size_t)BATCH * 16384;

  // weights -> bf16, transposed [N][K]
  wconv<<<256, 256, 0, stream>>>(int_W1, wi1, 256, 256);
  wconv<<<128, 256, 0, stream>>>(int_W2, wi2, 256, 128);
  wconv<<<256, 256, 0, stream>>>(msg_W1, wm1, 256, 256);
  wconv<<<128, 256, 0, stream>>>(msg_W2, wm2, 256, 128);
  wconv<<<160, 256, 0, stream>>>(upd_W1, wu1, 320, 128);
  wconv<<< 32, 256, 0, stream>>>(upd_W2, wu2, 128, 64);

  for (int ts = 0; ts < 2; ++ts) {
    // encoders (reset hb, e)
    fused_mlp<32,64,64,0,1,1><<<NN/32, 256, 0, stream>>>(
        node_features, nullptr, enc_node_W, enc_node_b, nullptr, nullptr,
        nullptr, hb, -1);
    fused_mlp<32,128,128,0,1,0><<<NE/32, 256, 0, stream>>>(
        edge_features, nullptr, enc_edge_W, enc_edge_b, nullptr, nullptr,
        e, nullptr, -1);

    for (int p = 0; p < 3; ++p) {
      // comb = intMLP([e, inter]) -> bf16   (inter==0 for ts0 and ts1/p0)
      const float* interArg = (ts == 1 && p > 0) ? inter : nullptr;
      mlp_mfma<256,256,128,4,0,1,8><<<NE/32, 512, 0, stream>>>(
          e, interArg, nullptr, nullptr, nullptr, nullptr,
          wi1, int_b1, wi2, int_b2, nullptr, comb, nullptr);
      // messages on old h -> mf, mb (bf16, in e's dead storage), both dirs
      mlp_mfma<256,256,128,1,1,2,8><<<NE/32, 512, 0, stream>>>(
          hb, nullptr, nullptr, comb, from_idx, to_idx,
          wm1, msg_b1, wm2, msg_b2, nullptr, mfb, mbb);
      // pair-local segment sums (LDS), both dirs as blocks -> bf16 agg
      scatter_agg<<<BATCH*2, 512, 0, stream>>>(mfb, mbb, from_idx, to_idx, aggFb, aggBb);
      // node update (in place, bf16)
      mlp_mfma<320,128,64,3,0,1,4><<<NN/32, 256, 0, stream>>>(
          hb, aggFb, aggBb, nullptr, nullptr, nullptr,
          wu1, upd_b1, wu2, upd_b2, nullptr, hb, nullptr);
      // e = mf2 + mb2 with updated h (dual-direction sum; overwrites mf/mb)
      mlp_mfma<256,256,128,1,1,0,8><<<NE/32, 512, 0, stream>>>(
          hb, nullptr, nullptr, comb, from_idx, to_idx,
          wm1, msg_b1, wm2, msg_b2, e, nullptr, nullptr);
      // interaction features from last time step's transport plan (MFMA)
      if (ts == 1 && p < 2) {
        gemm_plan_mfma<0><<<dim3(4, BATCH), 256, 0, stream>>>(
            S, e, inter, EPG, 0,   EQ_, EC_, EQ_);
        gemm_plan_mfma<1><<<dim3(4, BATCH), 256, 0, stream>>>(
            S, e, inter, EPG, EQ_, 0,   EQ_, EC_);
      }
    }
    // sinkhorn features + plan
    fused_mlp<128,64,64,5,0,0><<<BATCH*8, 256, 0, stream>>>(
        nullptr, e, sink_W1, sink_b1, sink_W2, sink_b2, fq, nullptr, EQ_);
    fused_mlp<128,64,64,6,0,0><<<BATCH*8, 256, 0, stream>>>(
        nullptr, e, sink_W1, sink_b1, sink_W2, sink_b2, fc, nullptr, EC_);
    gemm_nt_scale<<<dim3(4,4,BATCH), 256, 0, stream>>>(fq, fc, S, 10.0f);
    sinkhorn_fused<<<BATCH, 1024, 0, stream>>>(S);   // S := plan
  }

  // final score
  gemm_plan_mfma<0><<<dim3(4, BATCH), 256, 0, stream>>>(S, e, shr, 256, 0, EQ_, EC_, 256);
  escore_kernel<<<BATCH, 256, 0, stream>>>(e, shr, out);
}

// Round 18
// 4000.399 us; speedup vs baseline: 1.5333x; 1.0089x over previous
//
#include <hip/hip_runtime.h>
#include <math.h>

constexpr int BATCH = 256;
constexpr int EQ_   = 192;
constexpr int EC_   = 240;
constexpr int EPG   = 432;   // edges per pair
constexpr int NPG   = 216;   // nodes per pair
constexpr int NN    = BATCH * NPG;   // 55296
constexpr int NE    = BATCH * EPG;   // 110592

typedef __attribute__((ext_vector_type(8))) short short8;
typedef __attribute__((ext_vector_type(4))) float floatx4;
typedef unsigned short u16;

__device__ __forceinline__ u16 f2bf(float x) {
  union { float f; unsigned u; } c; c.f = x;
  const unsigned r = (c.u + 0x7FFFu + ((c.u >> 16) & 1u)) >> 16;
  return (u16)r;
}
__device__ __forceinline__ float bf2f(u16 x) {
  union { unsigned u; float f; } c; c.u = ((unsigned)x) << 16;
  return c.f;
}
__device__ __forceinline__ unsigned pack2(float a, float b) {
  return (unsigned)f2bf(a) | ((unsigned)f2bf(b) << 16);
}
__device__ __forceinline__ short8 cvt8(const float* __restrict__ p) {
  const float4 a = *(const float4*)p;
  const float4 b = *(const float4*)(p + 4);
  short8 o;
  o[0]=(short)f2bf(a.x); o[1]=(short)f2bf(a.y); o[2]=(short)f2bf(a.z); o[3]=(short)f2bf(a.w);
  o[4]=(short)f2bf(b.x); o[5]=(short)f2bf(b.y); o[6]=(short)f2bf(b.z); o[7]=(short)f2bf(b.w);
  return o;
}

__device__ __forceinline__ void lse_online(float& m, float& s, float tt) {
  if (tt > m) { s = s * __expf(m - tt) + 1.f; m = tt; }
  else        { s += __expf(tt - m); }
}

// ---------------------------------------------------------------------------
// weight transpose + f32->bf16:  out[n*K+k] = bf16(W[k*N+n])
// ---------------------------------------------------------------------------
__global__ __launch_bounds__(256)
void wconv(const float* __restrict__ W, u16* __restrict__ out, int K, int N)
{
  const int i = blockIdx.x * 256 + threadIdx.x;
  if (i < K * N) {
    const int n = i / K, k = i - n * K;
    out[i] = f2bf(W[(size_t)k * N + n]);
  }
}

// ---------------------------------------------------------------------------
// MFMA fused 2-layer MLP — EXACT round-12 m-loop variant (measured 4181us).
// DO NOT restructure (rounds 14/15 regressed 15-47% at identical FLOPs).
// IN_MODE: 1 [hb[IA],hb[IB],comb]  3 [hb,aggFb,aggBb]  4 [e(f32), inter(f32|0)]
// OUT_MODE: 0 f32 write (sum)  1 bf16 write (sum)  2 bf16 per-dir -> Yb0/Yb1
// ---------------------------------------------------------------------------
template<int K1, int HID, int NOUT, int IN_MODE, int DUAL, int OUT_MODE, int WAVES>
__global__ __launch_bounds__(WAVES * 64, 4)
void mlp_mfma(const void* __restrict__ X, const void* __restrict__ P2,
              const void* __restrict__ P3, const u16* __restrict__ CB,
              const int* __restrict__ IA, const int* __restrict__ IB,
              const u16* __restrict__ W1t, const float* __restrict__ B1,
              const u16* __restrict__ W2t, const float* __restrict__ B2,
              float* __restrict__ Yf, u16* __restrict__ Yb0, u16* __restrict__ Yb1)
{
  constexpr int RT  = 32;
  constexpr int THREADS = WAVES * 64;
  constexpr int KCH = K1 / 8;
  constexpr int NT1 = HID / (WAVES * 16);
  constexpr int NT2 = (NOUT / (WAVES * 16) > 0) ? NOUT / (WAVES * 16) : 1;
  constexpr int SAB = RT * K1 * 2;
  constexpr int SHB = RT * (HID + 8) * 2;
  __shared__ __align__(16) char smem[(SAB > SHB ? SAB : SHB)];
  u16* sA = (u16*)smem;
  u16* sH = (u16*)smem;

  const int tid = threadIdx.x;
  const int rowBase = blockIdx.x * RT;

  for (int ch = tid; ch < RT * KCH; ch += THREADS) {
    const int r = ch / KCH, kc = ch - r * KCH;
    const int gr = rowBase + r, k0 = kc * 8;
    short8 pk;
    if constexpr (IN_MODE == 4) {
      const float* Xf  = (const float*)X;
      const float* P2f = (const float*)P2;
      if (k0 < 128)      pk = cvt8(&Xf[(size_t)gr * 128 + k0]);
      else if (P2f)      pk = cvt8(&P2f[(size_t)gr * 128 + (k0 - 128)]);
      else { pk = short8{0,0,0,0,0,0,0,0}; }
    } else if constexpr (IN_MODE == 1) {
      const u16* Hb = (const u16*)X;
      if (k0 < 64)       pk = *(const short8*)&Hb[(size_t)IA[gr] * 64 + k0];
      else if (k0 < 128) pk = *(const short8*)&Hb[(size_t)IB[gr] * 64 + (k0 - 64)];
      else               pk = *(const short8*)&CB[(size_t)gr * 128 + (k0 - 128)];
    } else { // 3
      const u16* Hb = (const u16*)X;
      const u16* A0 = (const u16*)P2;
      const u16* A1 = (const u16*)P3;
      if (k0 < 64)       pk = *(const short8*)&Hb[(size_t)gr * 64 + k0];
      else if (k0 < 192) pk = *(const short8*)&A0[(size_t)gr * 128 + (k0 - 64)];
      else               pk = *(const short8*)&A1[(size_t)gr * 128 + (k0 - 192)];
    }
    const int byte = ((r * K1 + k0) * 2) ^ ((r & 7) << 4);
    *(short8*)((char*)sA + byte) = pk;
  }
  __syncthreads();

  const int wid = tid >> 6, lane = tid & 63;
  const int l15 = lane & 15, lg = lane >> 4;

  floatx4 acc1[1 + DUAL][2][NT1];
  #pragma unroll
  for (int d = 0; d <= DUAL; ++d)
    #pragma unroll
    for (int m = 0; m < 2; ++m)
      #pragma unroll
      for (int n = 0; n < NT1; ++n) acc1[d][m][n] = floatx4{0.f,0.f,0.f,0.f};

  #pragma unroll 2
  for (int kk = 0; kk < K1 / 32; ++kk) {
    short8 bw[NT1];
    #pragma unroll
    for (int n = 0; n < NT1; ++n) {
      const int col = wid * (HID / WAVES) + n * 16 + l15;
      bw[n] = *(const short8*)&W1t[(size_t)col * K1 + kk * 32 + lg * 8];
    }
    #pragma unroll
    for (int d = 0; d <= DUAL; ++d) {
      int k0 = kk * 32 + lg * 8;
      if (DUAL && d && k0 < 128) k0 ^= 64;
      #pragma unroll
      for (int m = 0; m < 2; ++m) {
        const int r = m * 16 + l15;
        const int byte = ((r * K1 + k0) * 2) ^ ((r & 7) << 4);
        const short8 af = *(const short8*)((char*)sA + byte);
        #pragma unroll
        for (int n = 0; n < NT1; ++n)
          acc1[d][m][n] = __builtin_amdgcn_mfma_f32_16x16x32_bf16(af, bw[n], acc1[d][m][n], 0, 0, 0);
      }
    }
  }
  __syncthreads();   // sA dead from here; smem becomes sH

  floatx4 accO[2][NT2];
  #pragma unroll
  for (int m = 0; m < 2; ++m)
    #pragma unroll
    for (int n = 0; n < NT2; ++n) accO[m][n] = floatx4{0.f,0.f,0.f,0.f};

  #pragma unroll
  for (int d = 0; d <= DUAL; ++d) {
    #pragma unroll
    for (int n = 0; n < NT1; ++n) {
      const int col = wid * (HID / WAVES) + n * 16 + l15;
      const float b1 = B1[col];
      #pragma unroll
      for (int m = 0; m < 2; ++m)
        #pragma unroll
        for (int r = 0; r < 4; ++r) {
          const int row = m * 16 + lg * 4 + r;
          const float y = acc1[d][m][n][r] + b1;
          sH[row * (HID + 8) + col] = f2bf(y > 0.f ? y : 0.f);
        }
    }
    __syncthreads();
    if (OUT_MODE == 2 && d == 1) {
      #pragma unroll
      for (int m = 0; m < 2; ++m)
        #pragma unroll
        for (int n = 0; n < NT2; ++n) accO[m][n] = floatx4{0.f,0.f,0.f,0.f};
    }
    #pragma unroll 2
    for (int kk = 0; kk < HID / 32; ++kk) {
      short8 bw2[NT2];
      #pragma unroll
      for (int n = 0; n < NT2; ++n) {
        const int col = wid * (NOUT / WAVES) + n * 16 + l15;
        bw2[n] = *(const short8*)&W2t[(size_t)col * HID + kk * 32 + lg * 8];
      }
      #pragma unroll
      for (int m = 0; m < 2; ++m) {
        const short8 af = *(const short8*)&sH[(m * 16 + l15) * (HID + 8) + kk * 32 + lg * 8];
        #pragma unroll
        for (int n = 0; n < NT2; ++n)
          accO[m][n] = __builtin_amdgcn_mfma_f32_16x16x32_bf16(af, bw2[n], accO[m][n], 0, 0, 0);
      }
    }
    if constexpr (OUT_MODE == 2) {
      u16* Y = d ? Yb1 : Yb0;
      #pragma unroll
      for (int n = 0; n < NT2; ++n) {
        const int col = wid * (NOUT / WAVES) + n * 16 + l15;
        const float b2 = B2[col];
        #pragma unroll
        for (int m = 0; m < 2; ++m)
          #pragma unroll
          for (int r = 0; r < 4; ++r) {
            const int gr = rowBase + m * 16 + lg * 4 + r;
            Y[(size_t)gr * NOUT + col] = f2bf(accO[m][n][r] + b2);
          }
      }
    }
    if (DUAL && d == 0) __syncthreads();
  }

  if constexpr (OUT_MODE != 2) {
    #pragma unroll
    for (int n = 0; n < NT2; ++n) {
      const int col = wid * (NOUT / WAVES) + n * 16 + l15;
      const float b2 = B2[col] * (float)(1 + DUAL);
      #pragma unroll
      for (int m = 0; m < 2; ++m)
        #pragma unroll
        for (int r = 0; r < 4; ++r) {
          const int gr = rowBase + m * 16 + lg * 4 + r;
          const float y = accO[m][n][r] + b2;
          if constexpr (OUT_MODE == 1) Yb0[(size_t)gr * NOUT + col] = f2bf(y);
          else                         Yf[(size_t)gr * NOUT + col] = y;
        }
    }
  }
}

// ---------------------------------------------------------------------------
// FUSED comb-MLP + msg-MLP. Race-fixed vs round 17: mf/mb are stored
// INTERLEAVED PER EDGE ROW inside e's storage (e row gr (512B) = mf[gr]
// (256B) | mb[gr] (256B)), so each block writes ONLY the storage of rows it
// alone staged -- no cross-block aliasing hazard (round-17's block-A-writes-
// rows-block-B-reads race is gone).
// Phases = round-12 bodies chained with LDS aliasing; numerics identical.
// ---------------------------------------------------------------------------
__global__ __launch_bounds__(512, 4)
void comb_msg_fused(const float* __restrict__ E, const float* __restrict__ INTER,
                    const u16* __restrict__ Hb,
                    const int* __restrict__ IA, const int* __restrict__ IB,
                    const u16* __restrict__ Wi1, const float* __restrict__ Bi1,
                    const u16* __restrict__ Wi2, const float* __restrict__ Bi2,
                    const u16* __restrict__ Wm1, const float* __restrict__ Bm1,
                    const u16* __restrict__ Wm2, const float* __restrict__ Bm2,
                    u16* __restrict__ COMB, u16* __restrict__ MI /* = (u16*)E */)
{
  constexpr int RT = 32;
  __shared__ __align__(16) char smem[RT * (256 + 8) * 2];   // 16896 B
  u16* sA = (u16*)smem;
  u16* sH = (u16*)smem;

  const int tid = threadIdx.x;
  const int rowBase = blockIdx.x * RT;
  const int wid = tid >> 6, lane = tid & 63;
  const int l15 = lane & 15, lg = lane >> 4;

  // ---- stage [e, inter] (reads THIS block's e rows only) ----
  for (int ch = tid; ch < RT * 32; ch += 512) {
    const int r = ch >> 5, kc = ch & 31;
    const int gr = rowBase + r, k0 = kc * 8;
    short8 pk;
    if (k0 < 128)   pk = cvt8(&E[(size_t)gr * 128 + k0]);
    else if (INTER) pk = cvt8(&INTER[(size_t)gr * 128 + (k0 - 128)]);
    else            pk = short8{0,0,0,0,0,0,0,0};
    const int byte = ((r * 256 + k0) * 2) ^ ((r & 7) << 4);
    *(short8*)((char*)sA + byte) = pk;
  }
  __syncthreads();

  // ---- comb L1 ----
  floatx4 c1[2][2];
  #pragma unroll
  for (int m = 0; m < 2; ++m) { c1[m][0] = floatx4{0,0,0,0}; c1[m][1] = floatx4{0,0,0,0}; }
  #pragma unroll 2
  for (int kk = 0; kk < 8; ++kk) {
    short8 bw[2];
    #pragma unroll
    for (int n = 0; n < 2; ++n) {
      const int col = wid * 32 + n * 16 + l15;
      bw[n] = *(const short8*)&Wi1[(size_t)col * 256 + kk * 32 + lg * 8];
    }
    #pragma unroll
    for (int m = 0; m < 2; ++m) {
      const int r = m * 16 + l15;
      const int byte = ((r * 256 + kk * 32 + lg * 8) * 2) ^ ((r & 7) << 4);
      const short8 af = *(const short8*)((char*)sA + byte);
      c1[m][0] = __builtin_amdgcn_mfma_f32_16x16x32_bf16(af, bw[0], c1[m][0], 0, 0, 0);
      c1[m][1] = __builtin_amdgcn_mfma_f32_16x16x32_bf16(af, bw[1], c1[m][1], 0, 0, 0);
    }
  }
  __syncthreads();   // sA dead; smem -> sH
  #pragma unroll
  for (int n = 0; n < 2; ++n) {
    const int col = wid * 32 + n * 16 + l15;
    const float b1 = Bi1[col];
    #pragma unroll
    for (int m = 0; m < 2; ++m)
      #pragma unroll
      for (int r = 0; r < 4; ++r) {
        const int row = m * 16 + lg * 4 + r;
        const float y = c1[m][n][r] + b1;
        sH[row * 264 + col] = f2bf(y > 0.f ? y : 0.f);
      }
  }
  __syncthreads();
  // ---- comb L2 ----
  floatx4 cO[2];
  cO[0] = floatx4{0,0,0,0}; cO[1] = floatx4{0,0,0,0};
  #pragma unroll 2
  for (int kk = 0; kk < 8; ++kk) {
    const int col = wid * 16 + l15;
    const short8 bw2 = *(const short8*)&Wi2[(size_t)col * 256 + kk * 32 + lg * 8];
    #pragma unroll
    for (int m = 0; m < 2; ++m) {
      const short8 af = *(const short8*)&sH[(m * 16 + l15) * 264 + kk * 32 + lg * 8];
      cO[m] = __builtin_amdgcn_mfma_f32_16x16x32_bf16(af, bw2, cO[m], 0, 0, 0);
    }
  }
  __syncthreads();   // sH dead; smem -> sA (msg input)

  // ---- write comb (global + swizzled LDS k0>=128), gather h (k0<128) ----
  {
    const int col = wid * 16 + l15;
    const float b2 = Bi2[col];
    #pragma unroll
    for (int m = 0; m < 2; ++m)
      #pragma unroll
      for (int r = 0; r < 4; ++r) {
        const int row = m * 16 + lg * 4 + r;
        const int gr = rowBase + row;
        const u16 v = f2bf(cO[m][r] + b2);
        COMB[(size_t)gr * 128 + col] = v;
        const int k0 = 128 + col;
        const int byte = ((row * 256 + k0) * 2) ^ ((row & 7) << 4);
        *(u16*)((char*)sA + byte) = v;
      }
  }
  for (int ch = tid; ch < RT * 16; ch += 512) {
    const int r = ch >> 4, kc = ch & 15;
    const int gr = rowBase + r, k0 = kc * 8;
    short8 pk;
    if (k0 < 64) pk = *(const short8*)&Hb[(size_t)IA[gr] * 64 + k0];
    else         pk = *(const short8*)&Hb[(size_t)IB[gr] * 64 + (k0 - 64)];
    const int byte = ((r * 256 + k0) * 2) ^ ((r & 7) << 4);
    *(short8*)((char*)sA + byte) = pk;
  }
  __syncthreads();

  // ---- msg L1 (DUAL) ----
  floatx4 m1[2][2][2];
  #pragma unroll
  for (int d = 0; d < 2; ++d)
    #pragma unroll
    for (int m = 0; m < 2; ++m) { m1[d][m][0] = floatx4{0,0,0,0}; m1[d][m][1] = floatx4{0,0,0,0}; }
  #pragma unroll 2
  for (int kk = 0; kk < 8; ++kk) {
    short8 bw[2];
    #pragma unroll
    for (int n = 0; n < 2; ++n) {
      const int col = wid * 32 + n * 16 + l15;
      bw[n] = *(const short8*)&Wm1[(size_t)col * 256 + kk * 32 + lg * 8];
    }
    #pragma unroll
    for (int d = 0; d < 2; ++d) {
      int k0 = kk * 32 + lg * 8;
      if (d && k0 < 128) k0 ^= 64;
      #pragma unroll
      for (int m = 0; m < 2; ++m) {
        const int r = m * 16 + l15;
        const int byte = ((r * 256 + k0) * 2) ^ ((r & 7) << 4);
        const short8 af = *(const short8*)((char*)sA + byte);
        m1[d][m][0] = __builtin_amdgcn_mfma_f32_16x16x32_bf16(af, bw[0], m1[d][m][0], 0, 0, 0);
        m1[d][m][1] = __builtin_amdgcn_mfma_f32_16x16x32_bf16(af, bw[1], m1[d][m][1], 0, 0, 0);
      }
    }
  }
  __syncthreads();   // sA dead; smem -> sH

  // ---- per-dir: hidden -> L2 -> store (interleaved mf/mb in e storage) ----
  floatx4 mO[2];
  #pragma unroll
  for (int d = 0; d < 2; ++d) {
    #pragma unroll
    for (int n = 0; n < 2; ++n) {
      const int col = wid * 32 + n * 16 + l15;
      const float b1 = Bm1[col];
      #pragma unroll
      for (int m = 0; m < 2; ++m)
        #pragma unroll
        for (int r = 0; r < 4; ++r) {
          const int row = m * 16 + lg * 4 + r;
          const float y = m1[d][m][n][r] + b1;
          sH[row * 264 + col] = f2bf(y > 0.f ? y : 0.f);
        }
    }
    __syncthreads();
    mO[0] = floatx4{0,0,0,0}; mO[1] = floatx4{0,0,0,0};
    #pragma unroll 2
    for (int kk = 0; kk < 8; ++kk) {
      const int col = wid * 16 + l15;
      const short8 bw2 = *(const short8*)&Wm2[(size_t)col * 256 + kk * 32 + lg * 8];
      #pragma unroll
      for (int m = 0; m < 2; ++m) {
        const short8 af = *(const short8*)&sH[(m * 16 + l15) * 264 + kk * 32 + lg * 8];
        mO[m] = __builtin_amdgcn_mfma_f32_16x16x32_bf16(af, bw2, mO[m], 0, 0, 0);
      }
    }
    {
      const int col = wid * 16 + l15;
      const float b2 = Bm2[col];
      #pragma unroll
      for (int m = 0; m < 2; ++m)
        #pragma unroll
        for (int r = 0; r < 4; ++r) {
          const int gr = rowBase + m * 16 + lg * 4 + r;
          MI[(size_t)gr * 256 + d * 128 + col] = f2bf(mO[m][r] + b2);
        }
    }
    if (d == 0) __syncthreads();
  }
}

// ---------------------------------------------------------------------------
// Pair-local segment-sum scatter, interleaved mf/mb input (stride 256/row).
// ---------------------------------------------------------------------------
__global__ __launch_bounds__(512)
void scatter_agg(const u16* __restrict__ MI,
                 const int* __restrict__ FI, const int* __restrict__ TI,
                 u16* __restrict__ AggF, u16* __restrict__ AggB)
{
  const int pair = blockIdx.x >> 1, dir = blockIdx.x & 1;
  const int* SI = dir ? FI : TI;
  u16* Agg      = dir ? AggB : AggF;
  const int tid = threadIdx.x;
  __shared__ float sAgg[NPG * 128];

  for (int i = tid; i < NPG * 128; i += 512) sAgg[i] = 0.f;
  __syncthreads();

  for (int i = tid; i < EPG * 32; i += 512) {
    const int edge = i >> 5, cb = i & 31;
    const int er = pair * EPG + edge;
    const int node = SI[er] - pair * NPG;
    const size_t base = (size_t)er * 256 + dir * 128 + cb;
    #pragma unroll
    for (int k = 0; k < 4; ++k)
      atomicAdd(&sAgg[node * 128 + cb + 32 * k], bf2f(MI[base + 32 * k]));
  }
  __syncthreads();
  unsigned* dst = (unsigned*)(Agg + (size_t)pair * NPG * 128);
  for (int i = tid; i < NPG * 64; i += 512)
    dst[i] = pack2(sAgg[2 * i], sAgg[2 * i + 1]);
}

// ---------------------------------------------------------------------------
// f32 fused MLP (encoders + sinkhorn feature MLPs)
// ---------------------------------------------------------------------------
template<int K1, int HID, int NOUT, int IN_MODE, int SINGLE, int OUTBF>
__global__ __launch_bounds__(256)
void fused_mlp(const float* __restrict__ X, const float* __restrict__ P1,
               const float* __restrict__ W1, const float* __restrict__ B1,
               const float* __restrict__ W2, const float* __restrict__ B2,
               float* __restrict__ Y, u16* __restrict__ Yb, int maskLen)
{
  constexpr int RT = 32, BK = 32;
  constexpr int J1 = HID / 32;
  constexpr int J2 = NOUT / 32;
  constexpr int BMAX = (HID > NOUT ? HID : NOUT);
  __shared__ float sA[RT * 33];
  __shared__ float sB[BK * BMAX];
  __shared__ float sH[SINGLE ? 1 : RT * (HID + 1)];

  const int t  = threadIdx.x;
  const int tx = t & 31, ty = t >> 5;
  const int rowBase = blockIdx.x * RT;

  float acc[4][J1];
  #pragma unroll
  for (int i = 0; i < 4; ++i)
    #pragma unroll
    for (int j = 0; j < J1; ++j) acc[i][j] = 0.f;

  for (int kb = 0; kb < K1; kb += BK) {
    for (int l = t; l < RT * BK; l += 256) {
      const int r = l >> 5, k = l & 31;
      const int gr = rowBase + r, gk = kb + k;
      float v;
      if constexpr (IN_MODE == 0) {
        v = X[(size_t)gr * K1 + gk];
      } else {
        const int bb = gr >> 8, m = gr & 255;
        constexpr int off = (IN_MODE == 5) ? 0 : EQ_;
        constexpr int len = (IN_MODE == 5) ? EQ_ : EC_;
        v = (m < len) ? P1[((size_t)bb * EPG + off + m) * 128 + gk] : 0.f;
      }
      sA[r * 33 + k] = v;
    }
    for (int l = t * 4; l < BK * HID; l += 1024) {
      *(float4*)&sB[l] = *(const float4*)&W1[(size_t)(kb + l / HID) * HID + (l % HID)];
    }
    __syncthreads();
    #pragma unroll
    for (int k = 0; k < BK; ++k) {
      const float a0 = sA[(ty*4+0)*33+k], a1 = sA[(ty*4+1)*33+k],
                  a2 = sA[(ty*4+2)*33+k], a3 = sA[(ty*4+3)*33+k];
      #pragma unroll
      for (int j = 0; j < J1; ++j) {
        const float bb = sB[k * HID + tx + 32*j];
        acc[0][j] += a0 * bb; acc[1][j] += a1 * bb;
        acc[2][j] += a2 * bb; acc[3][j] += a3 * bb;
      }
    }
    __syncthreads();
  }

  if constexpr (SINGLE) {
    #pragma unroll
    for (int j = 0; j < J1; ++j) {
      const int col = tx + 32*j;
      const float bias = B1[col];
      #pragma unroll
      for (int i = 0; i < 4; ++i) {
        const int gr = rowBase + ty*4 + i;
        if constexpr (OUTBF) Yb[(size_t)gr * HID + col] = f2bf(acc[i][j] + bias);
        else                 Y[(size_t)gr * HID + col] = acc[i][j] + bias;
      }
    }
  } else {
    #pragma unroll
    for (int j = 0; j < J1; ++j) {
      const int col = tx + 32*j;
      const float bias = B1[col];
      #pragma unroll
      for (int i = 0; i < 4; ++i) {
        float y = acc[i][j] + bias;
        sH[(ty*4+i) * (HID+1) + col] = y > 0.f ? y : 0.f;
      }
    }
    __syncthreads();

    float acc2[4][J2];
    #pragma unroll
    for (int i = 0; i < 4; ++i)
      #pragma unroll
      for (int j = 0; j < J2; ++j) acc2[i][j] = 0.f;

    for (int kb = 0; kb < HID; kb += BK) {
      for (int l = t * 4; l < BK * NOUT; l += 1024) {
        *(float4*)&sB[l] = *(const float4*)&W2[(size_t)(kb + l / NOUT) * NOUT + (l % NOUT)];
      }
      __syncthreads();
      #pragma unroll
      for (int k = 0; k < BK; ++k) {
        const float a0 = sH[(ty*4+0)*(HID+1) + kb + k],
                    a1 = sH[(ty*4+1)*(HID+1) + kb + k],
                    a2 = sH[(ty*4+2)*(HID+1) + kb + k],
                    a3 = sH[(ty*4+3)*(HID+1) + kb + k];
        #pragma unroll
        for (int j = 0; j < J2; ++j) {
          const float bb = sB[k * NOUT + tx + 32*j];
          acc2[0][j] += a0 * bb; acc2[1][j] += a1 * bb;
          acc2[2][j] += a2 * bb; acc2[3][j] += a3 * bb;
        }
      }
      __syncthreads();
    }
    #pragma unroll
    for (int j = 0; j < J2; ++j) {
      const int col = tx + 32*j;
      const float bias = B2[col];
      #pragma unroll
      for (int i = 0; i < 4; ++i) {
        const int gr = rowBase + ty*4 + i;
        float y = acc2[i][j] + bias;
        if (maskLen >= 0 && (gr & 255) >= maskLen) y = 0.f;
        Y[(size_t)gr * NOUT + col] = y;
      }
    }
  }
}

// ---------------------------------------------------------------------------
// S[b] = scale * fq[b] @ fc[b]^T  (kept f32: S feeds exp(10*S))
// ---------------------------------------------------------------------------
__global__ __launch_bounds__(256)
void gemm_nt_scale(const float* __restrict__ A, const float* __restrict__ Bm,
                   float* __restrict__ C, float scale)
{
  const int b = blockIdx.z, qt = blockIdx.x, ct = blockIdx.y;
  __shared__ float sA[64 * 68];
  __shared__ float sB[64 * 68];
  const int t = threadIdx.x;
  const int tx = t & 15, ty = t >> 4;
  const float* Ab = A  + (size_t)b * 16384 + (size_t)qt * 4096;
  const float* Bb = Bm + (size_t)b * 16384 + (size_t)ct * 4096;
  for (int l = t * 4; l < 64 * 64; l += 1024) {
    const int r = l >> 6, d = l & 63;
    *(float4*)&sA[r*68 + d] = *(const float4*)&Ab[r*64 + d];
    *(float4*)&sB[r*68 + d] = *(const float4*)&Bb[r*64 + d];
  }
  __syncthreads();
  float acc[4][4] = {};
  #pragma unroll
  for (int d = 0; d < 64; ++d) {
    float a[4], bb[4];
    #pragma unroll
    for (int i = 0; i < 4; ++i) a[i]  = sA[(ty*4+i)*68 + d];
    #pragma unroll
    for (int j = 0; j < 4; ++j) bb[j] = sB[(tx+16*j)*68 + d];
    #pragma unroll
    for (int i = 0; i < 4; ++i)
      #pragma unroll
      for (int j = 0; j < 4; ++j) acc[i][j] += a[i] * bb[j];
  }
  float* Cb = C + (size_t)b * 65536 + (size_t)(qt*64) * 256 + ct*64;
  #pragma unroll
  for (int i = 0; i < 4; ++i)
    #pragma unroll
    for (int j = 0; j < 4; ++j)
      Cb[(ty*4+i)*256 + tx + 16*j] = acc[i][j] * scale;
}

// ---------------------------------------------------------------------------
// MFMA plan GEMM (round-16 proven): Y = op(P[b]) @ V, V gathered from e rows.
// ---------------------------------------------------------------------------
template<int TRANSA>
__global__ __launch_bounds__(256)
void gemm_plan_mfma(const float* __restrict__ P, const float* __restrict__ E,
                    float* __restrict__ Y, int RPB, int YOFF, int VOFF,
                    int VLEN, int maskRows)
{
  __shared__ u16 sP[64 * 40];
  __shared__ u16 sVT[128 * 40];
  const int b = blockIdx.y, rt = blockIdx.x;
  const int t = threadIdx.x;
  const int wid = t >> 6, lane = t & 63;
  const int l15 = lane & 15, lg = lane >> 4;
  const float* Pb = P + (size_t)b * 65536;

  floatx4 acc[8];
  #pragma unroll
  for (int n = 0; n < 8; ++n) acc[n] = floatx4{0.f,0.f,0.f,0.f};

  for (int kb = 0; kb < 256; kb += 32) {
    if constexpr (TRANSA == 0) {
      for (int l = t; l < 64 * 32; l += 256) {
        const int r = l >> 5, k = l & 31;
        sP[r * 40 + k] = f2bf(Pb[(size_t)(rt * 64 + r) * 256 + kb + k]);
      }
    } else {
      for (int l = t; l < 64 * 32; l += 256) {
        const int q = l >> 6, c = l & 63;
        sP[c * 40 + q] = f2bf(Pb[(size_t)(kb + q) * 256 + rt * 64 + c]);
      }
    }
    for (int l = t; l < 32 * 128; l += 256) {
      const int k = l >> 7, d = l & 127;
      const int vr = kb + k;
      float v = 0.f;
      if (vr < VLEN) v = E[((size_t)b * EPG + VOFF + vr) * 128 + d];
      sVT[d * 40 + k] = f2bf(v);
    }
    __syncthreads();
    const short8 af = *(const short8*)&sP[(wid * 16 + l15) * 40 + lg * 8];
    #pragma unroll
    for (int n = 0; n < 8; ++n) {
      const short8 bw = *(const short8*)&sVT[(n * 16 + l15) * 40 + lg * 8];
      acc[n] = __builtin_amdgcn_mfma_f32_16x16x32_bf16(af, bw, acc[n], 0, 0, 0);
    }
    __syncthreads();
  }
  #pragma unroll
  for (int n = 0; n < 8; ++n) {
    const int col = n * 16 + l15;
    #pragma unroll
    for (int r = 0; r < 4; ++r) {
      const int row = rt * 64 + wid * 16 + lg * 4 + r;
      if (row < maskRows)
        Y[((size_t)b * RPB + YOFF + row) * 128 + col] = acc[n][r];
    }
  }
}

// ---------------------------------------------------------------------------
// Single-pass fused sinkhorn with exp-free butterflies (round-11 proven).
// ---------------------------------------------------------------------------
__global__ __launch_bounds__(1024)
void sinkhorn_fused(float* __restrict__ S)
{
  const int b = blockIdx.x, t = threadIdx.x;
  float* Sb = S + (size_t)b * 65536;
  const int w = t >> 6, lane = t & 63;
  const int cbase = lane * 4;
  __shared__ float pm[16 * 256], ps[16 * 256];
  __shared__ float su[256], sv[256];
  if (t < 256) sv[t] = 0.f;
  __syncthreads();

  for (int it = 0; it < 10; ++it) {
    const float4 v4 = *(const float4*)&sv[cbase];
    float4 cm = {-1e30f, -1e30f, -1e30f, -1e30f};
    float4 cs = {0.f, 0.f, 0.f, 0.f};
    #pragma unroll 2
    for (int i = 0; i < 16; ++i) {
      const int r = w * 16 + i;
      const float4 s4 = *(const float4*)&Sb[(size_t)r * 256 + cbase];
      const float ax = s4.x + v4.x, ay = s4.y + v4.y;
      const float az = s4.z + v4.z, aw = s4.w + v4.w;
      float m = fmaxf(fmaxf(ax, ay), fmaxf(az, aw));
      #pragma unroll
      for (int off = 32; off; off >>= 1) m = fmaxf(m, __shfl_xor(m, off));
      float s = __expf(ax - m) + __expf(ay - m) + __expf(az - m) + __expf(aw - m);
      #pragma unroll
      for (int off = 32; off; off >>= 1) s += __shfl_xor(s, off);
      const float u = -(m + __logf(s));
      if (lane == 0) su[r] = u;
      lse_online(cm.x, cs.x, s4.x + u);
      lse_online(cm.y, cs.y, s4.y + u);
      lse_online(cm.z, cs.z, s4.z + u);
      lse_online(cm.w, cs.w, s4.w + u);
    }
    *(float4*)&pm[w * 256 + cbase] = cm;
    *(float4*)&ps[w * 256 + cbase] = cs;
    __syncthreads();
    if (t < 256) {
      float m = pm[t];
      #pragma unroll
      for (int k = 1; k < 16; ++k) m = fmaxf(m, pm[k * 256 + t]);
      float s = 0.f;
      #pragma unroll
      for (int k = 0; k < 16; ++k) s += ps[k * 256 + t] * __expf(pm[k * 256 + t] - m);
      sv[t] = -(m + __logf(s));
    }
    __syncthreads();
  }
  for (int i = t; i < 16384; i += 1024) {
    const int row = i >> 6, c4 = (i & 63) * 4;
    float4 s4 = *(float4*)&Sb[(size_t)row * 256 + c4];
    const float uu = su[row];
    const float4 v4 = *(const float4*)&sv[c4];
    s4.x = __expf(s4.x + uu + v4.x);
    s4.y = __expf(s4.y + uu + v4.y);
    s4.z = __expf(s4.z + uu + v4.z);
    s4.w = __expf(s4.w + uu + v4.w);
    *(float4*)&Sb[(size_t)row * 256 + c4] = s4;
  }
}

// ---------------------------------------------------------------------------
// score[b] = -sum_{m<256,d} | (m<EQ ? e_q[m,d] : 0) - pc[m,d] |
// ---------------------------------------------------------------------------
__global__ __launch_bounds__(256)
void escore_kernel(const float* __restrict__ e, const float* __restrict__ pc,
                   float* __restrict__ out)
{
  const int b = blockIdx.x, t = threadIdx.x;
  float acc = 0.f;
  for (int i4 = t; i4 < 8192; i4 += 256) {
    const int flat = i4 * 4;
    const int m = flat >> 7, d = flat & 127;
    float4 p = *(const float4*)&pc[((size_t)b * 256 + m) * 128 + d];
    float4 q = {0.f, 0.f, 0.f, 0.f};
    if (m < EQ_) q = *(const float4*)&e[((size_t)b * EPG + m) * 128 + d];
    acc += fabsf(q.x - p.x) + fabsf(q.y - p.y) + fabsf(q.z - p.z) + fabsf(q.w - p.w);
  }
  __shared__ float red[256];
  red[t] = acc; __syncthreads();
  for (int s2 = 128; s2 > 0; s2 >>= 1) { if (t < s2) red[t] += red[t + s2]; __syncthreads(); }
  if (t == 0) out[b] = -red[0];
}

// ---------------------------------------------------------------------------
extern "C" void kernel_launch(void* const* d_in, const int* in_sizes, int n_in,
                              void* d_out, int out_size, void* d_ws, size_t ws_size,
                              hipStream_t stream)
{
  const float* node_features = (const float*)d_in[0];
  const float* edge_features = (const float*)d_in[1];
  const int*   from_idx      = (const int*)d_in[2];
  const int*   to_idx        = (const int*)d_in[3];
  const float* enc_node_W = (const float*)d_in[4];
  const float* enc_node_b = (const float*)d_in[5];
  const float* enc_edge_W = (const float*)d_in[6];
  const float* enc_edge_b = (const float*)d_in[7];
  const float* msg_W1 = (const float*)d_in[8];
  const float* msg_b1 = (const float*)d_in[9];
  const float* msg_W2 = (const float*)d_in[10];
  const float* msg_b2 = (const float*)d_in[11];
  const float* upd_W1 = (const float*)d_in[12];
  const float* upd_b1 = (const float*)d_in[13];
  const float* upd_W2 = (const float*)d_in[14];
  const float* upd_b2 = (const float*)d_in[15];
  const float* int_W1 = (const float*)d_in[16];
  const float* int_b1 = (const float*)d_in[17];
  const float* int_W2 = (const float*)d_in[18];
  const float* int_b2 = (const float*)d_in[19];
  const float* sink_W1 = (const float*)d_in[20];
  const float* sink_b1 = (const float*)d_in[21];
  const float* sink_W2 = (const float*)d_in[22];
  const float* sink_b2 = (const float*)d_in[23];
  float* out = (float*)d_out;

  // ~224 MB layout (proven). h bf16; agg bf16; mf/mb interleaved in e rows.
  float* wsf = (float*)d_ws;
  float* hreg = wsf;                              // region: NN*64 f32-sized
  float* e   = hreg + (size_t)NN * 64;            // NE*128 f32
  float* shr = e + (size_t)NE * 128;              // NE*128 f32 (inter | agg bf16 | fq+fc | pc)
  float* S   = shr + (size_t)NE * 128;            // BATCH*65536 f32
  u16* comb  = (u16*)(S + (size_t)BATCH * 65536); // NE*128 bf16
  u16* wi1 = comb + (size_t)NE * 128;             // 256x256
  u16* wi2 = wi1 + 65536;                         // 128x256
  u16* wm1 = wi2 + 32768;                         // 256x256
  u16* wm2 = wm1 + 65536;                         // 128x256
  u16* wu1 = wm2 + 32768;                         // 128x320
  u16* wu2 = wu1 + 40960;                         // 64x128

  u16* hb = (u16*)hreg;                           // NN*64 bf16 node states
  u16* mI = (u16*)e;                              // mf/mb interleaved: row gr = [mf(128)|mb(128)]

  u16* aggFb = (u16*)shr;                         // NN*128 bf16
  u16* aggBb = aggFb + (size_t)NN * 128;
  float* inter = shr;                             // EPG-row layout (f32)
  float* fq    = shr;
  float* fc    = shr + (size_t)BATCH * 16384;

  // weights -> bf16, transposed [N][K]
  wconv<<<256, 256, 0, stream>>>(int_W1, wi1, 256, 256);
  wconv<<<128, 256, 0, stream>>>(int_W2, wi2, 256, 128);
  wconv<<<256, 256, 0, stream>>>(msg_W1, wm1, 256, 256);
  wconv<<<128, 256, 0, stream>>>(msg_W2, wm2, 256, 128);
  wconv<<<160, 256, 0, stream>>>(upd_W1, wu1, 320, 128);
  wconv<<< 32, 256, 0, stream>>>(upd_W2, wu2, 128, 64);

  for (int ts = 0; ts < 2; ++ts) {
    // encoders (reset hb, e)
    fused_mlp<32,64,64,0,1,1><<<NN/32, 256, 0, stream>>>(
        node_features, nullptr, enc_node_W, enc_node_b, nullptr, nullptr,
        nullptr, hb, -1);
    fused_mlp<32,128,128,0,1,0><<<NE/32, 256, 0, stream>>>(
        edge_features, nullptr, enc_edge_W, enc_edge_b, nullptr, nullptr,
        e, nullptr, -1);

    for (int p = 0; p < 3; ++p) {
      // FUSED: comb = intMLP([e,inter]); msg MLP on old h -> mf/mb (block-local alias)
      const float* interArg = (ts == 1 && p > 0) ? inter : nullptr;
      comb_msg_fused<<<NE/32, 512, 0, stream>>>(
          e, interArg, hb, from_idx, to_idx,
          wi1, int_b1, wi2, int_b2, wm1, msg_b1, wm2, msg_b2,
          comb, mI);
      // pair-local segment sums (LDS) -> bf16 agg
      scatter_agg<<<BATCH*2, 512, 0, stream>>>(mI, from_idx, to_idx, aggFb, aggBb);
      // node update (in place, bf16)
      mlp_mfma<320,128,64,3,0,1,4><<<NN/32, 256, 0, stream>>>(
          hb, aggFb, aggBb, nullptr, nullptr, nullptr,
          wu1, upd_b1, wu2, upd_b2, nullptr, hb, nullptr);
      // e = mf2 + mb2 with updated h (overwrites mf/mb storage)
      mlp_mfma<256,256,128,1,1,0,8><<<NE/32, 512, 0, stream>>>(
          hb, nullptr, nullptr, comb, from_idx, to_idx,
          wm1, msg_b1, wm2, msg_b2, e, nullptr, nullptr);
      // interaction features from last time step's transport plan (MFMA)
      if (ts == 1 && p < 2) {
        gemm_plan_mfma<0><<<dim3(4, BATCH), 256, 0, stream>>>(
            S, e, inter, EPG, 0,   EQ_, EC_, EQ_);
        gemm_plan_mfma<1><<<dim3(4, BATCH), 256, 0, stream>>>(
            S, e, inter, EPG, EQ_, 0,   EQ_, EC_);
      }
    }
    // sinkhorn features + plan
    fused_mlp<128,64,64,5,0,0><<<BATCH*8, 256, 0, stream>>>(
        nullptr, e, sink_W1, sink_b1, sink_W2, sink_b2, fq, nullptr, EQ_);
    fused_mlp<128,64,64,6,0,0><<<BATCH*8, 256, 0, stream>>>(
        nullptr, e, sink_W1, sink_b1, sink_W2, sink_b2, fc, nullptr, EC_);
    gemm_nt_scale<<<dim3(4,4,BATCH), 256, 0, stream>>>(fq, fc, S, 10.0f);
    sinkhorn_fused<<<BATCH, 1024, 0, stream>>>(S);   // S := plan
  }

  // final score
  gemm_plan_mfma<0><<<dim3(4, BATCH), 256, 0, stream>>>(S, e, shr, 256, 0, EQ_, EC_, 256);
  escore_kernel<<<BATCH, 256, 0, stream>>>(e, shr, out);
}

// Round 19
// 3491.799 us; speedup vs baseline: 1.7567x; 1.1457x over previous
//
#include <hip/hip_runtime.h>
#include <math.h>

constexpr int BATCH = 256;
constexpr int EQ_   = 192;
constexpr int EC_   = 240;
constexpr int EPG   = 432;   // edges per pair
constexpr int NPG   = 216;   // nodes per pair
constexpr int NN    = BATCH * NPG;   // 55296
constexpr int NE    = BATCH * EPG;   // 110592

typedef __attribute__((ext_vector_type(8))) short short8;
typedef __attribute__((ext_vector_type(4))) float floatx4;
typedef unsigned short u16;

__device__ __forceinline__ u16 f2bf(float x) {
  union { float f; unsigned u; } c; c.f = x;
  const unsigned r = (c.u + 0x7FFFu + ((c.u >> 16) & 1u)) >> 16;
  return (u16)r;
}
__device__ __forceinline__ float bf2f(u16 x) {
  union { unsigned u; float f; } c; c.u = ((unsigned)x) << 16;
  return c.f;
}
__device__ __forceinline__ unsigned pack2(float a, float b) {
  return (unsigned)f2bf(a) | ((unsigned)f2bf(b) << 16);
}
__device__ __forceinline__ short8 cvt8(const float* __restrict__ p) {
  const float4 a = *(const float4*)p;
  const float4 b = *(const float4*)(p + 4);
  short8 o;
  o[0]=(short)f2bf(a.x); o[1]=(short)f2bf(a.y); o[2]=(short)f2bf(a.z); o[3]=(short)f2bf(a.w);
  o[4]=(short)f2bf(b.x); o[5]=(short)f2bf(b.y); o[6]=(short)f2bf(b.z); o[7]=(short)f2bf(b.w);
  return o;
}

__device__ __forceinline__ void lse_online(float& m, float& s, float tt) {
  if (tt > m) { s = s * __expf(m - tt) + 1.f; m = tt; }
  else        { s += __expf(tt - m); }
}

// ---------------------------------------------------------------------------
// weight transpose + f32->bf16:  out[n*K+k] = bf16(W[k*N+n])
// ---------------------------------------------------------------------------
__global__ __launch_bounds__(256)
void wconv(const float* __restrict__ W, u16* __restrict__ out, int K, int N)
{
  const int i = blockIdx.x * 256 + threadIdx.x;
  if (i < K * N) {
    const int n = i / K, k = i - n * K;
    out[i] = f2bf(W[(size_t)k * N + n]);
  }
}

// ---------------------------------------------------------------------------
// MFMA fused 2-layer MLP — round-12 m-loop variant (frozen).
// IN_MODE: 1 [hb[IA],hb[IB],comb]  3 [hb,aggFb,aggBb]  4 [e(f32), inter(f32|0)]
// OUT_MODE: 0 f32 write  1 bf16 write  2 bf16 per-dir  3 f32 Yf + bf16 Yb0
// ---------------------------------------------------------------------------
template<int K1, int HID, int NOUT, int IN_MODE, int DUAL, int OUT_MODE, int WAVES>
__global__ __launch_bounds__(WAVES * 64, 4)
void mlp_mfma(const void* __restrict__ X, const void* __restrict__ P2,
              const void* __restrict__ P3, const u16* __restrict__ CB,
              const int* __restrict__ IA, const int* __restrict__ IB,
              const u16* __restrict__ W1t, const float* __restrict__ B1,
              const u16* __restrict__ W2t, const float* __restrict__ B2,
              float* __restrict__ Yf, u16* __restrict__ Yb0, u16* __restrict__ Yb1)
{
  constexpr int RT  = 32;
  constexpr int THREADS = WAVES * 64;
  constexpr int KCH = K1 / 8;
  constexpr int NT1 = HID / (WAVES * 16);
  constexpr int NT2 = (NOUT / (WAVES * 16) > 0) ? NOUT / (WAVES * 16) : 1;
  constexpr int SAB = RT * K1 * 2;
  constexpr int SHB = RT * (HID + 8) * 2;
  __shared__ __align__(16) char smem[(SAB > SHB ? SAB : SHB)];
  u16* sA = (u16*)smem;
  u16* sH = (u16*)smem;

  const int tid = threadIdx.x;
  const int rowBase = blockIdx.x * RT;

  for (int ch = tid; ch < RT * KCH; ch += THREADS) {
    const int r = ch / KCH, kc = ch - r * KCH;
    const int gr = rowBase + r, k0 = kc * 8;
    short8 pk;
    if constexpr (IN_MODE == 4) {
      const float* Xf  = (const float*)X;
      const float* P2f = (const float*)P2;
      if (k0 < 128)      pk = cvt8(&Xf[(size_t)gr * 128 + k0]);
      else if (P2f)      pk = cvt8(&P2f[(size_t)gr * 128 + (k0 - 128)]);
      else { pk = short8{0,0,0,0,0,0,0,0}; }
    } else if constexpr (IN_MODE == 1) {
      const u16* Hb = (const u16*)X;
      if (k0 < 64)       pk = *(const short8*)&Hb[(size_t)IA[gr] * 64 + k0];
      else if (k0 < 128) pk = *(const short8*)&Hb[(size_t)IB[gr] * 64 + (k0 - 64)];
      else               pk = *(const short8*)&CB[(size_t)gr * 128 + (k0 - 128)];
    } else { // 3
      const u16* Hb = (const u16*)X;
      const u16* A0 = (const u16*)P2;
      const u16* A1 = (const u16*)P3;
      if (k0 < 64)       pk = *(const short8*)&Hb[(size_t)gr * 64 + k0];
      else if (k0 < 192) pk = *(const short8*)&A0[(size_t)gr * 128 + (k0 - 64)];
      else               pk = *(const short8*)&A1[(size_t)gr * 128 + (k0 - 192)];
    }
    const int byte = ((r * K1 + k0) * 2) ^ ((r & 7) << 4);
    *(short8*)((char*)sA + byte) = pk;
  }
  __syncthreads();

  const int wid = tid >> 6, lane = tid & 63;
  const int l15 = lane & 15, lg = lane >> 4;

  floatx4 acc1[1 + DUAL][2][NT1];
  #pragma unroll
  for (int d = 0; d <= DUAL; ++d)
    #pragma unroll
    for (int m = 0; m < 2; ++m)
      #pragma unroll
      for (int n = 0; n < NT1; ++n) acc1[d][m][n] = floatx4{0.f,0.f,0.f,0.f};

  #pragma unroll 2
  for (int kk = 0; kk < K1 / 32; ++kk) {
    short8 bw[NT1];
    #pragma unroll
    for (int n = 0; n < NT1; ++n) {
      const int col = wid * (HID / WAVES) + n * 16 + l15;
      bw[n] = *(const short8*)&W1t[(size_t)col * K1 + kk * 32 + lg * 8];
    }
    #pragma unroll
    for (int d = 0; d <= DUAL; ++d) {
      int k0 = kk * 32 + lg * 8;
      if (DUAL && d && k0 < 128) k0 ^= 64;
      #pragma unroll
      for (int m = 0; m < 2; ++m) {
        const int r = m * 16 + l15;
        const int byte = ((r * K1 + k0) * 2) ^ ((r & 7) << 4);
        const short8 af = *(const short8*)((char*)sA + byte);
        #pragma unroll
        for (int n = 0; n < NT1; ++n)
          acc1[d][m][n] = __builtin_amdgcn_mfma_f32_16x16x32_bf16(af, bw[n], acc1[d][m][n], 0, 0, 0);
      }
    }
  }
  __syncthreads();   // sA dead from here; smem becomes sH

  floatx4 accO[2][NT2];
  #pragma unroll
  for (int m = 0; m < 2; ++m)
    #pragma unroll
    for (int n = 0; n < NT2; ++n) accO[m][n] = floatx4{0.f,0.f,0.f,0.f};

  #pragma unroll
  for (int d = 0; d <= DUAL; ++d) {
    #pragma unroll
    for (int n = 0; n < NT1; ++n) {
      const int col = wid * (HID / WAVES) + n * 16 + l15;
      const float b1 = B1[col];
      #pragma unroll
      for (int m = 0; m < 2; ++m)
        #pragma unroll
        for (int r = 0; r < 4; ++r) {
          const int row = m * 16 + lg * 4 + r;
          const float y = acc1[d][m][n][r] + b1;
          sH[row * (HID + 8) + col] = f2bf(y > 0.f ? y : 0.f);
        }
    }
    __syncthreads();
    if (OUT_MODE == 2 && d == 1) {
      #pragma unroll
      for (int m = 0; m < 2; ++m)
        #pragma unroll
        for (int n = 0; n < NT2; ++n) accO[m][n] = floatx4{0.f,0.f,0.f,0.f};
    }
    #pragma unroll 2
    for (int kk = 0; kk < HID / 32; ++kk) {
      short8 bw2[NT2];
      #pragma unroll
      for (int n = 0; n < NT2; ++n) {
        const int col = wid * (NOUT / WAVES) + n * 16 + l15;
        bw2[n] = *(const short8*)&W2t[(size_t)col * HID + kk * 32 + lg * 8];
      }
      #pragma unroll
      for (int m = 0; m < 2; ++m) {
        const short8 af = *(const short8*)&sH[(m * 16 + l15) * (HID + 8) + kk * 32 + lg * 8];
        #pragma unroll
        for (int n = 0; n < NT2; ++n)
          accO[m][n] = __builtin_amdgcn_mfma_f32_16x16x32_bf16(af, bw2[n], accO[m][n], 0, 0, 0);
      }
    }
    if constexpr (OUT_MODE == 2) {
      u16* Y = d ? Yb1 : Yb0;
      #pragma unroll
      for (int n = 0; n < NT2; ++n) {
        const int col = wid * (NOUT / WAVES) + n * 16 + l15;
        const float b2 = B2[col];
        #pragma unroll
        for (int m = 0; m < 2; ++m)
          #pragma unroll
          for (int r = 0; r < 4; ++r) {
            const int gr = rowBase + m * 16 + lg * 4 + r;
            Y[(size_t)gr * NOUT + col] = f2bf(accO[m][n][r] + b2);
          }
      }
    }
    if (DUAL && d == 0) __syncthreads();
  }

  if constexpr (OUT_MODE != 2) {
    #pragma unroll
    for (int n = 0; n < NT2; ++n) {
      const int col = wid * (NOUT / WAVES) + n * 16 + l15;
      const float b2 = B2[col] * (float)(1 + DUAL);
      #pragma unroll
      for (int m = 0; m < 2; ++m)
        #pragma unroll
        for (int r = 0; r < 4; ++r) {
          const int gr = rowBase + m * 16 + lg * 4 + r;
          const float y = accO[m][n][r] + b2;
          if constexpr (OUT_MODE == 1) {
            Yb0[(size_t)gr * NOUT + col] = f2bf(y);
          } else {
            Yf[(size_t)gr * NOUT + col] = y;
            if constexpr (OUT_MODE == 3)
              Yb0[(size_t)gr * NOUT + col] = f2bf(y);
          }
        }
    }
  }
}

// ---------------------------------------------------------------------------
// FUSED comb-MLP + msg-MLP (round-18 proven, block-local mf/mb alias).
// EBF16: E input is bf16 (ts1-p1 checkpoint path). INTER is bf16 (or null).
// ---------------------------------------------------------------------------
template<int EBF16>
__global__ __launch_bounds__(512, 4)
void comb_msg_fused(const void* __restrict__ E, const u16* __restrict__ INTER,
                    const u16* __restrict__ Hb,
                    const int* __restrict__ IA, const int* __restrict__ IB,
                    const u16* __restrict__ Wi1, const float* __restrict__ Bi1,
                    const u16* __restrict__ Wi2, const float* __restrict__ Bi2,
                    const u16* __restrict__ Wm1, const float* __restrict__ Bm1,
                    const u16* __restrict__ Wm2, const float* __restrict__ Bm2,
                    u16* __restrict__ COMB, u16* __restrict__ MI)
{
  constexpr int RT = 32;
  __shared__ __align__(16) char smem[RT * (256 + 8) * 2];   // 16896 B
  u16* sA = (u16*)smem;
  u16* sH = (u16*)smem;

  const int tid = threadIdx.x;
  const int rowBase = blockIdx.x * RT;
  const int wid = tid >> 6, lane = tid & 63;
  const int l15 = lane & 15, lg = lane >> 4;

  // ---- stage [e, inter] ----
  for (int ch = tid; ch < RT * 32; ch += 512) {
    const int r = ch >> 5, kc = ch & 31;
    const int gr = rowBase + r, k0 = kc * 8;
    short8 pk;
    if (k0 < 128) {
      if constexpr (EBF16) pk = *(const short8*)&((const u16*)E)[(size_t)gr * 128 + k0];
      else                 pk = cvt8(&((const float*)E)[(size_t)gr * 128 + k0]);
    }
    else if (INTER) pk = *(const short8*)&INTER[(size_t)gr * 128 + (k0 - 128)];
    else            pk = short8{0,0,0,0,0,0,0,0};
    const int byte = ((r * 256 + k0) * 2) ^ ((r & 7) << 4);
    *(short8*)((char*)sA + byte) = pk;
  }
  __syncthreads();

  // ---- comb L1 ----
  floatx4 c1[2][2];
  #pragma unroll
  for (int m = 0; m < 2; ++m) { c1[m][0] = floatx4{0,0,0,0}; c1[m][1] = floatx4{0,0,0,0}; }
  #pragma unroll 2
  for (int kk = 0; kk < 8; ++kk) {
    short8 bw[2];
    #pragma unroll
    for (int n = 0; n < 2; ++n) {
      const int col = wid * 32 + n * 16 + l15;
      bw[n] = *(const short8*)&Wi1[(size_t)col * 256 + kk * 32 + lg * 8];
    }
    #pragma unroll
    for (int m = 0; m < 2; ++m) {
      const int r = m * 16 + l15;
      const int byte = ((r * 256 + kk * 32 + lg * 8) * 2) ^ ((r & 7) << 4);
      const short8 af = *(const short8*)((char*)sA + byte);
      c1[m][0] = __builtin_amdgcn_mfma_f32_16x16x32_bf16(af, bw[0], c1[m][0], 0, 0, 0);
      c1[m][1] = __builtin_amdgcn_mfma_f32_16x16x32_bf16(af, bw[1], c1[m][1], 0, 0, 0);
    }
  }
  __syncthreads();
  #pragma unroll
  for (int n = 0; n < 2; ++n) {
    const int col = wid * 32 + n * 16 + l15;
    const float b1 = Bi1[col];
    #pragma unroll
    for (int m = 0; m < 2; ++m)
      #pragma unroll
      for (int r = 0; r < 4; ++r) {
        const int row = m * 16 + lg * 4 + r;
        const float y = c1[m][n][r] + b1;
        sH[row * 264 + col] = f2bf(y > 0.f ? y : 0.f);
      }
  }
  __syncthreads();
  // ---- comb L2 ----
  floatx4 cO[2];
  cO[0] = floatx4{0,0,0,0}; cO[1] = floatx4{0,0,0,0};
  #pragma unroll 2
  for (int kk = 0; kk < 8; ++kk) {
    const int col = wid * 16 + l15;
    const short8 bw2 = *(const short8*)&Wi2[(size_t)col * 256 + kk * 32 + lg * 8];
    #pragma unroll
    for (int m = 0; m < 2; ++m) {
      const short8 af = *(const short8*)&sH[(m * 16 + l15) * 264 + kk * 32 + lg * 8];
      cO[m] = __builtin_amdgcn_mfma_f32_16x16x32_bf16(af, bw2, cO[m], 0, 0, 0);
    }
  }
  __syncthreads();

  // ---- write comb (global + swizzled LDS k0>=128), gather h (k0<128) ----
  {
    const int col = wid * 16 + l15;
    const float b2 = Bi2[col];
    #pragma unroll
    for (int m = 0; m < 2; ++m)
      #pragma unroll
      for (int r = 0; r < 4; ++r) {
        const int row = m * 16 + lg * 4 + r;
        const int gr = rowBase + row;
        const u16 v = f2bf(cO[m][r] + b2);
        COMB[(size_t)gr * 128 + col] = v;
        const int k0 = 128 + col;
        const int byte = ((row * 256 + k0) * 2) ^ ((row & 7) << 4);
        *(u16*)((char*)sA + byte) = v;
      }
  }
  for (int ch = tid; ch < RT * 16; ch += 512) {
    const int r = ch >> 4, kc = ch & 15;
    const int gr = rowBase + r, k0 = kc * 8;
    short8 pk;
    if (k0 < 64) pk = *(const short8*)&Hb[(size_t)IA[gr] * 64 + k0];
    else         pk = *(const short8*)&Hb[(size_t)IB[gr] * 64 + (k0 - 64)];
    const int byte = ((r * 256 + k0) * 2) ^ ((r & 7) << 4);
    *(short8*)((char*)sA + byte) = pk;
  }
  __syncthreads();

  // ---- msg L1 (DUAL) ----
  floatx4 m1[2][2][2];
  #pragma unroll
  for (int d = 0; d < 2; ++d)
    #pragma unroll
    for (int m = 0; m < 2; ++m) { m1[d][m][0] = floatx4{0,0,0,0}; m1[d][m][1] = floatx4{0,0,0,0}; }
  #pragma unroll 2
  for (int kk = 0; kk < 8; ++kk) {
    short8 bw[2];
    #pragma unroll
    for (int n = 0; n < 2; ++n) {
      const int col = wid * 32 + n * 16 + l15;
      bw[n] = *(const short8*)&Wm1[(size_t)col * 256 + kk * 32 + lg * 8];
    }
    #pragma unroll
    for (int d = 0; d < 2; ++d) {
      int k0 = kk * 32 + lg * 8;
      if (d && k0 < 128) k0 ^= 64;
      #pragma unroll
      for (int m = 0; m < 2; ++m) {
        const int r = m * 16 + l15;
        const int byte = ((r * 256 + k0) * 2) ^ ((r & 7) << 4);
        const short8 af = *(const short8*)((char*)sA + byte);
        m1[d][m][0] = __builtin_amdgcn_mfma_f32_16x16x32_bf16(af, bw[0], m1[d][m][0], 0, 0, 0);
        m1[d][m][1] = __builtin_amdgcn_mfma_f32_16x16x32_bf16(af, bw[1], m1[d][m][1], 0, 0, 0);
      }
    }
  }
  __syncthreads();

  // ---- per-dir: hidden -> L2 -> store (interleaved mf/mb) ----
  floatx4 mO[2];
  #pragma unroll
  for (int d = 0; d < 2; ++d) {
    #pragma unroll
    for (int n = 0; n < 2; ++n) {
      const int col = wid * 32 + n * 16 + l15;
      const float b1 = Bm1[col];
      #pragma unroll
      for (int m = 0; m < 2; ++m)
        #pragma unroll
        for (int r = 0; r < 4; ++r) {
          const int row = m * 16 + lg * 4 + r;
          const float y = m1[d][m][n][r] + b1;
          sH[row * 264 + col] = f2bf(y > 0.f ? y : 0.f);
        }
    }
    __syncthreads();
    mO[0] = floatx4{0,0,0,0}; mO[1] = floatx4{0,0,0,0};
    #pragma unroll 2
    for (int kk = 0; kk < 8; ++kk) {
      const int col = wid * 16 + l15;
      const short8 bw2 = *(const short8*)&Wm2[(size_t)col * 256 + kk * 32 + lg * 8];
      #pragma unroll
      for (int m = 0; m < 2; ++m) {
        const short8 af = *(const short8*)&sH[(m * 16 + l15) * 264 + kk * 32 + lg * 8];
        mO[m] = __builtin_amdgcn_mfma_f32_16x16x32_bf16(af, bw2, mO[m], 0, 0, 0);
      }
    }
    {
      const int col = wid * 16 + l15;
      const float b2 = Bm2[col];
      #pragma unroll
      for (int m = 0; m < 2; ++m)
        #pragma unroll
        for (int r = 0; r < 4; ++r) {
          const int gr = rowBase + m * 16 + lg * 4 + r;
          MI[(size_t)gr * 256 + d * 128 + col] = f2bf(mO[m][r] + b2);
        }
    }
    if (d == 0) __syncthreads();
  }
}

// ---------------------------------------------------------------------------
// Pair-local segment-sum scatter, interleaved mf/mb input (stride 256/row).
// ---------------------------------------------------------------------------
__global__ __launch_bounds__(512)
void scatter_agg(const u16* __restrict__ MI,
                 const int* __restrict__ FI, const int* __restrict__ TI,
                 u16* __restrict__ AggF, u16* __restrict__ AggB)
{
  const int pair = blockIdx.x >> 1, dir = blockIdx.x & 1;
  const int* SI = dir ? FI : TI;
  u16* Agg      = dir ? AggB : AggF;
  const int tid = threadIdx.x;
  __shared__ float sAgg[NPG * 128];

  for (int i = tid; i < NPG * 128; i += 512) sAgg[i] = 0.f;
  __syncthreads();

  for (int i = tid; i < EPG * 32; i += 512) {
    const int edge = i >> 5, cb = i & 31;
    const int er = pair * EPG + edge;
    const int node = SI[er] - pair * NPG;
    const size_t base = (size_t)er * 256 + dir * 128 + cb;
    #pragma unroll
    for (int k = 0; k < 4; ++k)
      atomicAdd(&sAgg[node * 128 + cb + 32 * k], bf2f(MI[base + 32 * k]));
  }
  __syncthreads();
  unsigned* dst = (unsigned*)(Agg + (size_t)pair * NPG * 128);
  for (int i = tid; i < NPG * 64; i += 512)
    dst[i] = pack2(sAgg[2 * i], sAgg[2 * i + 1]);
}

// ---------------------------------------------------------------------------
// f32 fused MLP (encoders + sinkhorn feature MLPs)
// ---------------------------------------------------------------------------
template<int K1, int HID, int NOUT, int IN_MODE, int SINGLE, int OUTBF>
__global__ __launch_bounds__(256)
void fused_mlp(const float* __restrict__ X, const float* __restrict__ P1,
               const float* __restrict__ W1, const float* __restrict__ B1,
               const float* __restrict__ W2, const float* __restrict__ B2,
               float* __restrict__ Y, u16* __restrict__ Yb, int maskLen)
{
  constexpr int RT = 32, BK = 32;
  constexpr int J1 = HID / 32;
  constexpr int J2 = NOUT / 32;
  constexpr int BMAX = (HID > NOUT ? HID : NOUT);
  __shared__ float sA[RT * 33];
  __shared__ float sB[BK * BMAX];
  __shared__ float sH[SINGLE ? 1 : RT * (HID + 1)];

  const int t  = threadIdx.x;
  const int tx = t & 31, ty = t >> 5;
  const int rowBase = blockIdx.x * RT;

  float acc[4][J1];
  #pragma unroll
  for (int i = 0; i < 4; ++i)
    #pragma unroll
    for (int j = 0; j < J1; ++j) acc[i][j] = 0.f;

  for (int kb = 0; kb < K1; kb += BK) {
    for (int l = t; l < RT * BK; l += 256) {
      const int r = l >> 5, k = l & 31;
      const int gr = rowBase + r, gk = kb + k;
      float v;
      if constexpr (IN_MODE == 0) {
        v = X[(size_t)gr * K1 + gk];
      } else {
        const int bb = gr >> 8, m = gr & 255;
        constexpr int off = (IN_MODE == 5) ? 0 : EQ_;
        constexpr int len = (IN_MODE == 5) ? EQ_ : EC_;
        v = (m < len) ? P1[((size_t)bb * EPG + off + m) * 128 + gk] : 0.f;
      }
      sA[r * 33 + k] = v;
    }
    for (int l = t * 4; l < BK * HID; l += 1024) {
      *(float4*)&sB[l] = *(const float4*)&W1[(size_t)(kb + l / HID) * HID + (l % HID)];
    }
    __syncthreads();
    #pragma unroll
    for (int k = 0; k < BK; ++k) {
      const float a0 = sA[(ty*4+0)*33+k], a1 = sA[(ty*4+1)*33+k],
                  a2 = sA[(ty*4+2)*33+k], a3 = sA[(ty*4+3)*33+k];
      #pragma unroll
      for (int j = 0; j < J1; ++j) {
        const float bb = sB[k * HID + tx + 32*j];
        acc[0][j] += a0 * bb; acc[1][j] += a1 * bb;
        acc[2][j] += a2 * bb; acc[3][j] += a3 * bb;
      }
    }
    __syncthreads();
  }

  if constexpr (SINGLE) {
    #pragma unroll
    for (int j = 0; j < J1; ++j) {
      const int col = tx + 32*j;
      const float bias = B1[col];
      #pragma unroll
      for (int i = 0; i < 4; ++i) {
        const int gr = rowBase + ty*4 + i;
        if constexpr (OUTBF) Yb[(size_t)gr * HID + col] = f2bf(acc[i][j] + bias);
        else                 Y[(size_t)gr * HID + col] = acc[i][j] + bias;
      }
    }
  } else {
    #pragma unroll
    for (int j = 0; j < J1; ++j) {
      const int col = tx + 32*j;
      const float bias = B1[col];
      #pragma unroll
      for (int i = 0; i < 4; ++i) {
        float y = acc[i][j] + bias;
        sH[(ty*4+i) * (HID+1) + col] = y > 0.f ? y : 0.f;
      }
    }
    __syncthreads();

    float acc2[4][J2];
    #pragma unroll
    for (int i = 0; i < 4; ++i)
      #pragma unroll
      for (int j = 0; j < J2; ++j) acc2[i][j] = 0.f;

    for (int kb = 0; kb < HID; kb += BK) {
      for (int l = t * 4; l < BK * NOUT; l += 1024) {
        *(float4*)&sB[l] = *(const float4*)&W2[(size_t)(kb + l / NOUT) * NOUT + (l % NOUT)];
      }
      __syncthreads();
      #pragma unroll
      for (int k = 0; k < BK; ++k) {
        const float a0 = sH[(ty*4+0)*(HID+1) + kb + k],
                    a1 = sH[(ty*4+1)*(HID+1) + kb + k],
                    a2 = sH[(ty*4+2)*(HID+1) + kb + k],
                    a3 = sH[(ty*4+3)*(HID+1) + kb + k];
        #pragma unroll
        for (int j = 0; j < J2; ++j) {
          const float bb = sB[k * NOUT + tx + 32*j];
          acc2[0][j] += a0 * bb; acc2[1][j] += a1 * bb;
          acc2[2][j] += a2 * bb; acc2[3][j] += a3 * bb;
        }
      }
      __syncthreads();
    }
    #pragma unroll
    for (int j = 0; j < J2; ++j) {
      const int col = tx + 32*j;
      const float bias = B2[col];
      #pragma unroll
      for (int i = 0; i < 4; ++i) {
        const int gr = rowBase + ty*4 + i;
        float y = acc2[i][j] + bias;
        if (maskLen >= 0 && (gr & 255) >= maskLen) y = 0.f;
        Y[(size_t)gr * NOUT + col] = y;
      }
    }
  }
}

// ---------------------------------------------------------------------------
// S[b] = scale * fq[b] @ fc[b]^T  (kept f32: S feeds exp(10*S))
// ---------------------------------------------------------------------------
__global__ __launch_bounds__(256)
void gemm_nt_scale(const float* __restrict__ A, const float* __restrict__ Bm,
                   float* __restrict__ C, float scale)
{
  const int b = blockIdx.z, qt = blockIdx.x, ct = blockIdx.y;
  __shared__ float sA[64 * 68];
  __shared__ float sB[64 * 68];
  const int t = threadIdx.x;
  const int tx = t & 15, ty = t >> 4;
  const float* Ab = A  + (size_t)b * 16384 + (size_t)qt * 4096;
  const float* Bb = Bm + (size_t)b * 16384 + (size_t)ct * 4096;
  for (int l = t * 4; l < 64 * 64; l += 1024) {
    const int r = l >> 6, d = l & 63;
    *(float4*)&sA[r*68 + d] = *(const float4*)&Ab[r*64 + d];
    *(float4*)&sB[r*68 + d] = *(const float4*)&Bb[r*64 + d];
  }
  __syncthreads();
  float acc[4][4] = {};
  #pragma unroll
  for (int d = 0; d < 64; ++d) {
    float a[4], bb[4];
    #pragma unroll
    for (int i = 0; i < 4; ++i) a[i]  = sA[(ty*4+i)*68 + d];
    #pragma unroll
    for (int j = 0; j < 4; ++j) bb[j] = sB[(tx+16*j)*68 + d];
    #pragma unroll
    for (int i = 0; i < 4; ++i)
      #pragma unroll
      for (int j = 0; j < 4; ++j) acc[i][j] += a[i] * bb[j];
  }
  float* Cb = C + (size_t)b * 65536 + (size_t)(qt*64) * 256 + ct*64;
  #pragma unroll
  for (int i = 0; i < 4; ++i)
    #pragma unroll
    for (int j = 0; j < 4; ++j)
      Cb[(ty*4+i)*256 + tx + 16*j] = acc[i][j] * scale;
}

// ---------------------------------------------------------------------------
// MFMA plan GEMM: Y = op(P[b]) @ V, V gathered from e rows (zero-padded).
// EBF16: V source already bf16. OUTBF: write bf16 (for inter — bit-identical
// to f32-write-then-cvt8 since cvt8 applies f2bf elementwise).
// ---------------------------------------------------------------------------
template<int TRANSA, int EBF16, int OUTBF>
__global__ __launch_bounds__(256)
void gemm_plan_mfma(const float* __restrict__ P, const void* __restrict__ E,
                    void* __restrict__ Y, int RPB, int YOFF, int VOFF,
                    int VLEN, int maskRows)
{
  __shared__ u16 sP[64 * 40];
  __shared__ u16 sVT[128 * 40];
  const int b = blockIdx.y, rt = blockIdx.x;
  const int t = threadIdx.x;
  const int wid = t >> 6, lane = t & 63;
  const int l15 = lane & 15, lg = lane >> 4;
  const float* Pb = P + (size_t)b * 65536;

  floatx4 acc[8];
  #pragma unroll
  for (int n = 0; n < 8; ++n) acc[n] = floatx4{0.f,0.f,0.f,0.f};

  for (int kb = 0; kb < 256; kb += 32) {
    if constexpr (TRANSA == 0) {
      for (int l = t; l < 64 * 32; l += 256) {
        const int r = l >> 5, k = l & 31;
        sP[r * 40 + k] = f2bf(Pb[(size_t)(rt * 64 + r) * 256 + kb + k]);
      }
    } else {
      for (int l = t; l < 64 * 32; l += 256) {
        const int q = l >> 6, c = l & 63;
        sP[c * 40 + q] = f2bf(Pb[(size_t)(kb + q) * 256 + rt * 64 + c]);
      }
    }
    for (int l = t; l < 32 * 128; l += 256) {
      const int k = l >> 7, d = l & 127;
      const int vr = kb + k;
      u16 v = 0;
      if (vr < VLEN) {
        if constexpr (EBF16) v = ((const u16*)E)[((size_t)b * EPG + VOFF + vr) * 128 + d];
        else                 v = f2bf(((const float*)E)[((size_t)b * EPG + VOFF + vr) * 128 + d]);
      }
      sVT[d * 40 + k] = v;
    }
    __syncthreads();
    const short8 af = *(const short8*)&sP[(wid * 16 + l15) * 40 + lg * 8];
    #pragma unroll
    for (int n = 0; n < 8; ++n) {
      const short8 bw = *(const short8*)&sVT[(n * 16 + l15) * 40 + lg * 8];
      acc[n] = __builtin_amdgcn_mfma_f32_16x16x32_bf16(af, bw, acc[n], 0, 0, 0);
    }
    __syncthreads();
  }
  #pragma unroll
  for (int n = 0; n < 8; ++n) {
    const int col = n * 16 + l15;
    #pragma unroll
    for (int r = 0; r < 4; ++r) {
      const int row = rt * 64 + wid * 16 + lg * 4 + r;
      if (row < maskRows) {
        const size_t idx = ((size_t)b * RPB + YOFF + row) * 128 + col;
        if constexpr (OUTBF) ((u16*)Y)[idx] = f2bf(acc[n][r]);
        else                 ((float*)Y)[idx] = acc[n][r];
      }
    }
  }
}

// ---------------------------------------------------------------------------
// Single-pass fused sinkhorn with exp-free butterflies (round-11 proven).
// ---------------------------------------------------------------------------
__global__ __launch_bounds__(1024)
void sinkhorn_fused(float* __restrict__ S)
{
  const int b = blockIdx.x, t = threadIdx.x;
  float* Sb = S + (size_t)b * 65536;
  const int w = t >> 6, lane = t & 63;
  const int cbase = lane * 4;
  __shared__ float pm[16 * 256], ps[16 * 256];
  __shared__ float su[256], sv[256];
  if (t < 256) sv[t] = 0.f;
  __syncthreads();

  for (int it = 0; it < 10; ++it) {
    const float4 v4 = *(const float4*)&sv[cbase];
    float4 cm = {-1e30f, -1e30f, -1e30f, -1e30f};
    float4 cs = {0.f, 0.f, 0.f, 0.f};
    #pragma unroll 2
    for (int i = 0; i < 16; ++i) {
      const int r = w * 16 + i;
      const float4 s4 = *(const float4*)&Sb[(size_t)r * 256 + cbase];
      const float ax = s4.x + v4.x, ay = s4.y + v4.y;
      const float az = s4.z + v4.z, aw = s4.w + v4.w;
      float m = fmaxf(fmaxf(ax, ay), fmaxf(az, aw));
      #pragma unroll
      for (int off = 32; off; off >>= 1) m = fmaxf(m, __shfl_xor(m, off));
      float s = __expf(ax - m) + __expf(ay - m) + __expf(az - m) + __expf(aw - m);
      #pragma unroll
      for (int off = 32; off; off >>= 1) s += __shfl_xor(s, off);
      const float u = -(m + __logf(s));
      if (lane == 0) su[r] = u;
      lse_online(cm.x, cs.x, s4.x + u);
      lse_online(cm.y, cs.y, s4.y + u);
      lse_online(cm.z, cs.z, s4.z + u);
      lse_online(cm.w, cs.w, s4.w + u);
    }
    *(float4*)&pm[w * 256 + cbase] = cm;
    *(float4*)&ps[w * 256 + cbase] = cs;
    __syncthreads();
    if (t < 256) {
      float m = pm[t];
      #pragma unroll
      for (int k = 1; k < 16; ++k) m = fmaxf(m, pm[k * 256 + t]);
      float s = 0.f;
      #pragma unroll
      for (int k = 0; k < 16; ++k) s += ps[k * 256 + t] * __expf(pm[k * 256 + t] - m);
      sv[t] = -(m + __logf(s));
    }
    __syncthreads();
  }
  for (int i = t; i < 16384; i += 1024) {
    const int row = i >> 6, c4 = (i & 63) * 4;
    float4 s4 = *(float4*)&Sb[(size_t)row * 256 + c4];
    const float uu = su[row];
    const float4 v4 = *(const float4*)&sv[c4];
    s4.x = __expf(s4.x + uu + v4.x);
    s4.y = __expf(s4.y + uu + v4.y);
    s4.z = __expf(s4.z + uu + v4.z);
    s4.w = __expf(s4.w + uu + v4.w);
    *(float4*)&Sb[(size_t)row * 256 + c4] = s4;
  }
}

// ---------------------------------------------------------------------------
// score[b] = -sum_{m<256,d} | (m<EQ ? e_q[m,d] : 0) - pc[m,d] |
// ---------------------------------------------------------------------------
__global__ __launch_bounds__(256)
void escore_kernel(const float* __restrict__ e, const float* __restrict__ pc,
                   float* __restrict__ out)
{
  const int b = blockIdx.x, t = threadIdx.x;
  float acc = 0.f;
  for (int i4 = t; i4 < 8192; i4 += 256) {
    const int flat = i4 * 4;
    const int m = flat >> 7, d = flat & 127;
    float4 p = *(const float4*)&pc[((size_t)b * 256 + m) * 128 + d];
    float4 q = {0.f, 0.f, 0.f, 0.f};
    if (m < EQ_) q = *(const float4*)&e[((size_t)b * EPG + m) * 128 + d];
    acc += fabsf(q.x - p.x) + fabsf(q.y - p.y) + fabsf(q.z - p.z) + fabsf(q.w - p.w);
  }
  __shared__ float red[256];
  red[t] = acc; __syncthreads();
  for (int s2 = 128; s2 > 0; s2 >>= 1) { if (t < s2) red[t] += red[t + s2]; __syncthreads(); }
  if (t == 0) out[b] = -red[0];
}

// ---------------------------------------------------------------------------
extern "C" void kernel_launch(void* const* d_in, const int* in_sizes, int n_in,
                              void* d_out, int out_size, void* d_ws, size_t ws_size,
                              hipStream_t stream)
{
  const float* node_features = (const float*)d_in[0];
  const float* edge_features = (const float*)d_in[1];
  const int*   from_idx      = (const int*)d_in[2];
  const int*   to_idx        = (const int*)d_in[3];
  const float* enc_node_W = (const float*)d_in[4];
  const float* enc_node_b = (const float*)d_in[5];
  const float* enc_edge_W = (const float*)d_in[6];
  const float* enc_edge_b = (const float*)d_in[7];
  const float* msg_W1 = (const float*)d_in[8];
  const float* msg_b1 = (const float*)d_in[9];
  const float* msg_W2 = (const float*)d_in[10];
  const float* msg_b2 = (const float*)d_in[11];
  const float* upd_W1 = (const float*)d_in[12];
  const float* upd_b1 = (const float*)d_in[13];
  const float* upd_W2 = (const float*)d_in[14];
  const float* upd_b2 = (const float*)d_in[15];
  const float* int_W1 = (const float*)d_in[16];
  const float* int_b1 = (const float*)d_in[17];
  const float* int_W2 = (const float*)d_in[18];
  const float* int_b2 = (const float*)d_in[19];
  const float* sink_W1 = (const float*)d_in[20];
  const float* sink_b1 = (const float*)d_in[21];
  const float* sink_W2 = (const float*)d_in[22];
  const float* sink_b2 = (const float*)d_in[23];
  float* out = (float*)d_out;

  // ~228.6 MB layout (< 240.6 MB proven in round 2).
  // inter now bf16 (bit-identical: its only reader cvt8-rounds anyway),
  // time-sharing shr with agg/fq/fc/pc. Checkpoints: e1b (bf16 e after
  // ts0-p0), h1b (bf16 h after ts0-p0) -> ts1 skips its p0 entirely
  // (reference: both time steps restart from h0,e0 with inter=0, so
  // ts1-p0 is bit-identical to ts0-p0).
  u16* wsu = (u16*)d_ws;
  u16*   hb  = wsu;                                    // NN*64 bf16
  float* e   = (float*)(wsu + (size_t)NN * 64);        // NE*128 f32
  float* shr = e + (size_t)NE * 128;                   // BATCH*32768 f32
  float* S   = shr + (size_t)BATCH * 32768;            // BATCH*65536 f32
  u16* comb  = (u16*)(S + (size_t)BATCH * 65536);      // NE*128 bf16
  u16* e1b   = comb + (size_t)NE * 128;                // NE*128 bf16 checkpoint
  u16* h1b   = e1b + (size_t)NE * 128;                 // NN*64 bf16 checkpoint
  u16* wi1 = h1b + (size_t)NN * 64;                    // 256x256
  u16* wi2 = wi1 + 65536;                              // 128x256
  u16* wm1 = wi2 + 32768;                              // 256x256
  u16* wm2 = wm1 + 65536;                              // 128x256
  u16* wu1 = wm2 + 32768;                              // 128x320
  u16* wu2 = wu1 + 40960;                              // 64x128

  u16* mI = (u16*)e;                                   // mf/mb interleaved in e rows
  u16* interb = (u16*)shr;                             // NE*128 bf16 (time-shared)
  u16* aggFb  = (u16*)shr;                             // NN*128 bf16
  u16* aggBb  = aggFb + (size_t)NN * 128;
  float* fq   = shr;
  float* fc   = shr + (size_t)BATCH * 16384;
  float* pc   = shr;

  // weights -> bf16, transposed [N][K]
  wconv<<<256, 256, 0, stream>>>(int_W1, wi1, 256, 256);
  wconv<<<128, 256, 0, stream>>>(int_W2, wi2, 256, 128);
  wconv<<<256, 256, 0, stream>>>(msg_W1, wm1, 256, 256);
  wconv<<<128, 256, 0, stream>>>(msg_W2, wm2, 256, 128);
  wconv<<<160, 256, 0, stream>>>(upd_W1, wu1, 320, 128);
  wconv<<< 32, 256, 0, stream>>>(upd_W2, wu2, 128, 64);

  // ================= ts0 =================
  fused_mlp<32,64,64,0,1,1><<<NN/32, 256, 0, stream>>>(
      node_features, nullptr, enc_node_W, enc_node_b, nullptr, nullptr,
      nullptr, hb, -1);
  fused_mlp<32,128,128,0,1,0><<<NE/32, 256, 0, stream>>>(
      edge_features, nullptr, enc_edge_W, enc_edge_b, nullptr, nullptr,
      e, nullptr, -1);

  for (int p = 0; p < 3; ++p) {
    comb_msg_fused<0><<<NE/32, 512, 0, stream>>>(
        e, nullptr, hb, from_idx, to_idx,
        wi1, int_b1, wi2, int_b2, wm1, msg_b1, wm2, msg_b2, comb, mI);
    scatter_agg<<<BATCH*2, 512, 0, stream>>>(mI, from_idx, to_idx, aggFb, aggBb);
    mlp_mfma<320,128,64,3,0,1,4><<<NN/32, 256, 0, stream>>>(
        hb, aggFb, aggBb, nullptr, nullptr, nullptr,
        wu1, upd_b1, wu2, upd_b2, nullptr, hb, nullptr);
    if (p == 0) {
      // checkpoint h1 (after node update), then e-update dual-writes e + e1b
      hipMemcpyAsync(h1b, hb, (size_t)NN * 64 * 2, hipMemcpyDeviceToDevice, stream);
      mlp_mfma<256,256,128,1,1,3,8><<<NE/32, 512, 0, stream>>>(
          hb, nullptr, nullptr, comb, from_idx, to_idx,
          wm1, msg_b1, wm2, msg_b2, e, e1b, nullptr);
    } else {
      mlp_mfma<256,256,128,1,1,0,8><<<NE/32, 512, 0, stream>>>(
          hb, nullptr, nullptr, comb, from_idx, to_idx,
          wm1, msg_b1, wm2, msg_b2, e, nullptr, nullptr);
    }
  }
  fused_mlp<128,64,64,5,0,0><<<BATCH*8, 256, 0, stream>>>(
      nullptr, e, sink_W1, sink_b1, sink_W2, sink_b2, fq, nullptr, EQ_);
  fused_mlp<128,64,64,6,0,0><<<BATCH*8, 256, 0, stream>>>(
      nullptr, e, sink_W1, sink_b1, sink_W2, sink_b2, fc, nullptr, EC_);
  gemm_nt_scale<<<dim3(4,4,BATCH), 256, 0, stream>>>(fq, fc, S, 10.0f);
  sinkhorn_fused<<<BATCH, 1024, 0, stream>>>(S);   // S := plan1

  // ================= ts1 (p0 skipped: restore checkpoint) =================
  hipMemcpyAsync(hb, h1b, (size_t)NN * 64 * 2, hipMemcpyDeviceToDevice, stream);
  // inter1 from checkpointed e1 (bf16 source, bf16 output — bit-identical)
  gemm_plan_mfma<0,1,1><<<dim3(4, BATCH), 256, 0, stream>>>(
      S, e1b, interb, EPG, 0,   EQ_, EC_, EQ_);
  gemm_plan_mfma<1,1,1><<<dim3(4, BATCH), 256, 0, stream>>>(
      S, e1b, interb, EPG, EQ_, 0,   EQ_, EC_);

  // p1 (E = bf16 checkpoint; MI targets main e storage — no alias with E)
  comb_msg_fused<1><<<NE/32, 512, 0, stream>>>(
      e1b, interb, hb, from_idx, to_idx,
      wi1, int_b1, wi2, int_b2, wm1, msg_b1, wm2, msg_b2, comb, mI);
  scatter_agg<<<BATCH*2, 512, 0, stream>>>(mI, from_idx, to_idx, aggFb, aggBb);
  mlp_mfma<320,128,64,3,0,1,4><<<NN/32, 256, 0, stream>>>(
      hb, aggFb, aggBb, nullptr, nullptr, nullptr,
      wu1, upd_b1, wu2, upd_b2, nullptr, hb, nullptr);
  mlp_mfma<256,256,128,1,1,0,8><<<NE/32, 512, 0, stream>>>(
      hb, nullptr, nullptr, comb, from_idx, to_idx,
      wm1, msg_b1, wm2, msg_b2, e, nullptr, nullptr);
  gemm_plan_mfma<0,0,1><<<dim3(4, BATCH), 256, 0, stream>>>(
      S, e, interb, EPG, 0,   EQ_, EC_, EQ_);
  gemm_plan_mfma<1,0,1><<<dim3(4, BATCH), 256, 0, stream>>>(
      S, e, interb, EPG, EQ_, 0,   EQ_, EC_);

  // p2
  comb_msg_fused<0><<<NE/32, 512, 0, stream>>>(
      e, interb, hb, from_idx, to_idx,
      wi1, int_b1, wi2, int_b2, wm1, msg_b1, wm2, msg_b2, comb, mI);
  scatter_agg<<<BATCH*2, 512, 0, stream>>>(mI, from_idx, to_idx, aggFb, aggBb);
  mlp_mfma<320,128,64,3,0,1,4><<<NN/32, 256, 0, stream>>>(
      hb, aggFb, aggBb, nullptr, nullptr, nullptr,
      wu1, upd_b1, wu2, upd_b2, nullptr, hb, nullptr);
  mlp_mfma<256,256,128,1,1,0,8><<<NE/32, 512, 0, stream>>>(
      hb, nullptr, nullptr, comb, from_idx, to_idx,
      wm1, msg_b1, wm2, msg_b2, e, nullptr, nullptr);

  fused_mlp<128,64,64,5,0,0><<<BATCH*8, 256, 0, stream>>>(
      nullptr, e, sink_W1, sink_b1, sink_W2, sink_b2, fq, nullptr, EQ_);
  fused_mlp<128,64,64,6,0,0><<<BATCH*8, 256, 0, stream>>>(
      nullptr, e, sink_W1, sink_b1, sink_W2, sink_b2, fc, nullptr, EC_);
  gemm_nt_scale<<<dim3(4,4,BATCH), 256, 0, stream>>>(fq, fc, S, 10.0f);
  sinkhorn_fused<<<BATCH, 1024, 0, stream>>>(S);   // S := plan2

  // final score
  gemm_plan_mfma<0,0,0><<<dim3(4, BATCH), 256, 0, stream>>>(
      S, e, pc, 256, 0, EQ_, EC_, 256);
  escore_kernel<<<BATCH, 256, 0, stream>>>(e, pc, out);
}

// Round 20
// 3271.399 us; speedup vs baseline: 1.8750x; 1.0674x over previous
//
#include <hip/hip_runtime.h>
#include <math.h>

constexpr int BATCH = 256;
constexpr int EQ_   = 192;
constexpr int EC_   = 240;
constexpr int EPG   = 432;   // edges per pair
constexpr int NPG   = 216;   // nodes per pair
constexpr int NN    = BATCH * NPG;   // 55296
constexpr int NE    = BATCH * EPG;   // 110592

typedef __attribute__((ext_vector_type(8))) short short8;
typedef __attribute__((ext_vector_type(4))) float floatx4;
typedef unsigned short u16;

__device__ __forceinline__ u16 f2bf(float x) {
  union { float f; unsigned u; } c; c.f = x;
  const unsigned r = (c.u + 0x7FFFu + ((c.u >> 16) & 1u)) >> 16;
  return (u16)r;
}
__device__ __forceinline__ float bf2f(u16 x) {
  union { unsigned u; float f; } c; c.u = ((unsigned)x) << 16;
  return c.f;
}
__device__ __forceinline__ unsigned pack2(float a, float b) {
  return (unsigned)f2bf(a) | ((unsigned)f2bf(b) << 16);
}
__device__ __forceinline__ short8 cvt8(const float* __restrict__ p) {
  const float4 a = *(const float4*)p;
  const float4 b = *(const float4*)(p + 4);
  short8 o;
  o[0]=(short)f2bf(a.x); o[1]=(short)f2bf(a.y); o[2]=(short)f2bf(a.z); o[3]=(short)f2bf(a.w);
  o[4]=(short)f2bf(b.x); o[5]=(short)f2bf(b.y); o[6]=(short)f2bf(b.z); o[7]=(short)f2bf(b.w);
  return o;
}

__device__ __forceinline__ void lse_online(float& m, float& s, float tt) {
  if (tt > m) { s = s * __expf(m - tt) + 1.f; m = tt; }
  else        { s += __expf(tt - m); }
}

// ---------------------------------------------------------------------------
// weight transpose + f32->bf16:  out[n*K+k] = bf16(W[k*N+n])
// ---------------------------------------------------------------------------
__global__ __launch_bounds__(256)
void wconv(const float* __restrict__ W, u16* __restrict__ out, int K, int N)
{
  const int i = blockIdx.x * 256 + threadIdx.x;
  if (i < K * N) {
    const int n = i / K, k = i - n * K;
    out[i] = f2bf(W[(size_t)k * N + n]);
  }
}

// split variant: hi = bf16(w), lo = bf16(w - hi)   (for split-bf16 f32 GEMM)
__global__ __launch_bounds__(256)
void wconv_split(const float* __restrict__ W, u16* __restrict__ hi,
                 u16* __restrict__ lo, int K, int N)
{
  const int i = blockIdx.x * 256 + threadIdx.x;
  if (i < K * N) {
    const int n = i / K, k = i - n * K;
    const float w = W[(size_t)k * N + n];
    const u16 h = f2bf(w);
    hi[i] = h;
    lo[i] = f2bf(w - bf2f(h));
  }
}

// ---------------------------------------------------------------------------
// MFMA fused 2-layer MLP — round-12 m-loop variant (frozen).
// ---------------------------------------------------------------------------
template<int K1, int HID, int NOUT, int IN_MODE, int DUAL, int OUT_MODE, int WAVES>
__global__ __launch_bounds__(WAVES * 64, 4)
void mlp_mfma(const void* __restrict__ X, const void* __restrict__ P2,
              const void* __restrict__ P3, const u16* __restrict__ CB,
              const int* __restrict__ IA, const int* __restrict__ IB,
              const u16* __restrict__ W1t, const float* __restrict__ B1,
              const u16* __restrict__ W2t, const float* __restrict__ B2,
              float* __restrict__ Yf, u16* __restrict__ Yb0, u16* __restrict__ Yb1)
{
  constexpr int RT  = 32;
  constexpr int THREADS = WAVES * 64;
  constexpr int KCH = K1 / 8;
  constexpr int NT1 = HID / (WAVES * 16);
  constexpr int NT2 = (NOUT / (WAVES * 16) > 0) ? NOUT / (WAVES * 16) : 1;
  constexpr int SAB = RT * K1 * 2;
  constexpr int SHB = RT * (HID + 8) * 2;
  __shared__ __align__(16) char smem[(SAB > SHB ? SAB : SHB)];
  u16* sA = (u16*)smem;
  u16* sH = (u16*)smem;

  const int tid = threadIdx.x;
  const int rowBase = blockIdx.x * RT;

  for (int ch = tid; ch < RT * KCH; ch += THREADS) {
    const int r = ch / KCH, kc = ch - r * KCH;
    const int gr = rowBase + r, k0 = kc * 8;
    short8 pk;
    if constexpr (IN_MODE == 4) {
      const float* Xf  = (const float*)X;
      const float* P2f = (const float*)P2;
      if (k0 < 128)      pk = cvt8(&Xf[(size_t)gr * 128 + k0]);
      else if (P2f)      pk = cvt8(&P2f[(size_t)gr * 128 + (k0 - 128)]);
      else { pk = short8{0,0,0,0,0,0,0,0}; }
    } else if constexpr (IN_MODE == 1) {
      const u16* Hb = (const u16*)X;
      if (k0 < 64)       pk = *(const short8*)&Hb[(size_t)IA[gr] * 64 + k0];
      else if (k0 < 128) pk = *(const short8*)&Hb[(size_t)IB[gr] * 64 + (k0 - 64)];
      else               pk = *(const short8*)&CB[(size_t)gr * 128 + (k0 - 128)];
    } else { // 3
      const u16* Hb = (const u16*)X;
      const u16* A0 = (const u16*)P2;
      const u16* A1 = (const u16*)P3;
      if (k0 < 64)       pk = *(const short8*)&Hb[(size_t)gr * 64 + k0];
      else if (k0 < 192) pk = *(const short8*)&A0[(size_t)gr * 128 + (k0 - 64)];
      else               pk = *(const short8*)&A1[(size_t)gr * 128 + (k0 - 192)];
    }
    const int byte = ((r * K1 + k0) * 2) ^ ((r & 7) << 4);
    *(short8*)((char*)sA + byte) = pk;
  }
  __syncthreads();

  const int wid = tid >> 6, lane = tid & 63;
  const int l15 = lane & 15, lg = lane >> 4;

  floatx4 acc1[1 + DUAL][2][NT1];
  #pragma unroll
  for (int d = 0; d <= DUAL; ++d)
    #pragma unroll
    for (int m = 0; m < 2; ++m)
      #pragma unroll
      for (int n = 0; n < NT1; ++n) acc1[d][m][n] = floatx4{0.f,0.f,0.f,0.f};

  #pragma unroll 2
  for (int kk = 0; kk < K1 / 32; ++kk) {
    short8 bw[NT1];
    #pragma unroll
    for (int n = 0; n < NT1; ++n) {
      const int col = wid * (HID / WAVES) + n * 16 + l15;
      bw[n] = *(const short8*)&W1t[(size_t)col * K1 + kk * 32 + lg * 8];
    }
    #pragma unroll
    for (int d = 0; d <= DUAL; ++d) {
      int k0 = kk * 32 + lg * 8;
      if (DUAL && d && k0 < 128) k0 ^= 64;
      #pragma unroll
      for (int m = 0; m < 2; ++m) {
        const int r = m * 16 + l15;
        const int byte = ((r * K1 + k0) * 2) ^ ((r & 7) << 4);
        const short8 af = *(const short8*)((char*)sA + byte);
        #pragma unroll
        for (int n = 0; n < NT1; ++n)
          acc1[d][m][n] = __builtin_amdgcn_mfma_f32_16x16x32_bf16(af, bw[n], acc1[d][m][n], 0, 0, 0);
      }
    }
  }
  __syncthreads();   // sA dead from here; smem becomes sH

  floatx4 accO[2][NT2];
  #pragma unroll
  for (int m = 0; m < 2; ++m)
    #pragma unroll
    for (int n = 0; n < NT2; ++n) accO[m][n] = floatx4{0.f,0.f,0.f,0.f};

  #pragma unroll
  for (int d = 0; d <= DUAL; ++d) {
    #pragma unroll
    for (int n = 0; n < NT1; ++n) {
      const int col = wid * (HID / WAVES) + n * 16 + l15;
      const float b1 = B1[col];
      #pragma unroll
      for (int m = 0; m < 2; ++m)
        #pragma unroll
        for (int r = 0; r < 4; ++r) {
          const int row = m * 16 + lg * 4 + r;
          const float y = acc1[d][m][n][r] + b1;
          sH[row * (HID + 8) + col] = f2bf(y > 0.f ? y : 0.f);
        }
    }
    __syncthreads();
    if (OUT_MODE == 2 && d == 1) {
      #pragma unroll
      for (int m = 0; m < 2; ++m)
        #pragma unroll
        for (int n = 0; n < NT2; ++n) accO[m][n] = floatx4{0.f,0.f,0.f,0.f};
    }
    #pragma unroll 2
    for (int kk = 0; kk < HID / 32; ++kk) {
      short8 bw2[NT2];
      #pragma unroll
      for (int n = 0; n < NT2; ++n) {
        const int col = wid * (NOUT / WAVES) + n * 16 + l15;
        bw2[n] = *(const short8*)&W2t[(size_t)col * HID + kk * 32 + lg * 8];
      }
      #pragma unroll
      for (int m = 0; m < 2; ++m) {
        const short8 af = *(const short8*)&sH[(m * 16 + l15) * (HID + 8) + kk * 32 + lg * 8];
        #pragma unroll
        for (int n = 0; n < NT2; ++n)
          accO[m][n] = __builtin_amdgcn_mfma_f32_16x16x32_bf16(af, bw2[n], accO[m][n], 0, 0, 0);
      }
    }
    if constexpr (OUT_MODE == 2) {
      u16* Y = d ? Yb1 : Yb0;
      #pragma unroll
      for (int n = 0; n < NT2; ++n) {
        const int col = wid * (NOUT / WAVES) + n * 16 + l15;
        const float b2 = B2[col];
        #pragma unroll
        for (int m = 0; m < 2; ++m)
          #pragma unroll
          for (int r = 0; r < 4; ++r) {
            const int gr = rowBase + m * 16 + lg * 4 + r;
            Y[(size_t)gr * NOUT + col] = f2bf(accO[m][n][r] + b2);
          }
      }
    }
    if (DUAL && d == 0) __syncthreads();
  }

  if constexpr (OUT_MODE != 2) {
    #pragma unroll
    for (int n = 0; n < NT2; ++n) {
      const int col = wid * (NOUT / WAVES) + n * 16 + l15;
      const float b2 = B2[col] * (float)(1 + DUAL);
      #pragma unroll
      for (int m = 0; m < 2; ++m)
        #pragma unroll
        for (int r = 0; r < 4; ++r) {
          const int gr = rowBase + m * 16 + lg * 4 + r;
          const float y = accO[m][n][r] + b2;
          if constexpr (OUT_MODE == 1) {
            Yb0[(size_t)gr * NOUT + col] = f2bf(y);
          } else {
            Yf[(size_t)gr * NOUT + col] = y;
            if constexpr (OUT_MODE == 3)
              Yb0[(size_t)gr * NOUT + col] = f2bf(y);
          }
        }
    }
  }
}

// ---------------------------------------------------------------------------
// FUSED comb-MLP + msg-MLP (round-18/19 proven, block-local mf/mb alias).
// ---------------------------------------------------------------------------
template<int EBF16>
__global__ __launch_bounds__(512, 4)
void comb_msg_fused(const void* __restrict__ E, const u16* __restrict__ INTER,
                    const u16* __restrict__ Hb,
                    const int* __restrict__ IA, const int* __restrict__ IB,
                    const u16* __restrict__ Wi1, const float* __restrict__ Bi1,
                    const u16* __restrict__ Wi2, const float* __restrict__ Bi2,
                    const u16* __restrict__ Wm1, const float* __restrict__ Bm1,
                    const u16* __restrict__ Wm2, const float* __restrict__ Bm2,
                    u16* __restrict__ COMB, u16* __restrict__ MI)
{
  constexpr int RT = 32;
  __shared__ __align__(16) char smem[RT * (256 + 8) * 2];   // 16896 B
  u16* sA = (u16*)smem;
  u16* sH = (u16*)smem;

  const int tid = threadIdx.x;
  const int rowBase = blockIdx.x * RT;
  const int wid = tid >> 6, lane = tid & 63;
  const int l15 = lane & 15, lg = lane >> 4;

  // ---- stage [e, inter] ----
  for (int ch = tid; ch < RT * 32; ch += 512) {
    const int r = ch >> 5, kc = ch & 31;
    const int gr = rowBase + r, k0 = kc * 8;
    short8 pk;
    if (k0 < 128) {
      if constexpr (EBF16) pk = *(const short8*)&((const u16*)E)[(size_t)gr * 128 + k0];
      else                 pk = cvt8(&((const float*)E)[(size_t)gr * 128 + k0]);
    }
    else if (INTER) pk = *(const short8*)&INTER[(size_t)gr * 128 + (k0 - 128)];
    else            pk = short8{0,0,0,0,0,0,0,0};
    const int byte = ((r * 256 + k0) * 2) ^ ((r & 7) << 4);
    *(short8*)((char*)sA + byte) = pk;
  }
  __syncthreads();

  // ---- comb L1 ----
  floatx4 c1[2][2];
  #pragma unroll
  for (int m = 0; m < 2; ++m) { c1[m][0] = floatx4{0,0,0,0}; c1[m][1] = floatx4{0,0,0,0}; }
  #pragma unroll 2
  for (int kk = 0; kk < 8; ++kk) {
    short8 bw[2];
    #pragma unroll
    for (int n = 0; n < 2; ++n) {
      const int col = wid * 32 + n * 16 + l15;
      bw[n] = *(const short8*)&Wi1[(size_t)col * 256 + kk * 32 + lg * 8];
    }
    #pragma unroll
    for (int m = 0; m < 2; ++m) {
      const int r = m * 16 + l15;
      const int byte = ((r * 256 + kk * 32 + lg * 8) * 2) ^ ((r & 7) << 4);
      const short8 af = *(const short8*)((char*)sA + byte);
      c1[m][0] = __builtin_amdgcn_mfma_f32_16x16x32_bf16(af, bw[0], c1[m][0], 0, 0, 0);
      c1[m][1] = __builtin_amdgcn_mfma_f32_16x16x32_bf16(af, bw[1], c1[m][1], 0, 0, 0);
    }
  }
  __syncthreads();
  #pragma unroll
  for (int n = 0; n < 2; ++n) {
    const int col = wid * 32 + n * 16 + l15;
    const float b1 = Bi1[col];
    #pragma unroll
    for (int m = 0; m < 2; ++m)
      #pragma unroll
      for (int r = 0; r < 4; ++r) {
        const int row = m * 16 + lg * 4 + r;
        const float y = c1[m][n][r] + b1;
        sH[row * 264 + col] = f2bf(y > 0.f ? y : 0.f);
      }
  }
  __syncthreads();
  // ---- comb L2 ----
  floatx4 cO[2];
  cO[0] = floatx4{0,0,0,0}; cO[1] = floatx4{0,0,0,0};
  #pragma unroll 2
  for (int kk = 0; kk < 8; ++kk) {
    const int col = wid * 16 + l15;
    const short8 bw2 = *(const short8*)&Wi2[(size_t)col * 256 + kk * 32 + lg * 8];
    #pragma unroll
    for (int m = 0; m < 2; ++m) {
      const short8 af = *(const short8*)&sH[(m * 16 + l15) * 264 + kk * 32 + lg * 8];
      cO[m] = __builtin_amdgcn_mfma_f32_16x16x32_bf16(af, bw2, cO[m], 0, 0, 0);
    }
  }
  __syncthreads();

  // ---- write comb (global + swizzled LDS k0>=128), gather h (k0<128) ----
  {
    const int col = wid * 16 + l15;
    const float b2 = Bi2[col];
    #pragma unroll
    for (int m = 0; m < 2; ++m)
      #pragma unroll
      for (int r = 0; r < 4; ++r) {
        const int row = m * 16 + lg * 4 + r;
        const int gr = rowBase + row;
        const u16 v = f2bf(cO[m][r] + b2);
        COMB[(size_t)gr * 128 + col] = v;
        const int k0 = 128 + col;
        const int byte = ((row * 256 + k0) * 2) ^ ((row & 7) << 4);
        *(u16*)((char*)sA + byte) = v;
      }
  }
  for (int ch = tid; ch < RT * 16; ch += 512) {
    const int r = ch >> 4, kc = ch & 15;
    const int gr = rowBase + r, k0 = kc * 8;
    short8 pk;
    if (k0 < 64) pk = *(const short8*)&Hb[(size_t)IA[gr] * 64 + k0];
    else         pk = *(const short8*)&Hb[(size_t)IB[gr] * 64 + (k0 - 64)];
    const int byte = ((r * 256 + k0) * 2) ^ ((r & 7) << 4);
    *(short8*)((char*)sA + byte) = pk;
  }
  __syncthreads();

  // ---- msg L1 (DUAL) ----
  floatx4 m1[2][2][2];
  #pragma unroll
  for (int d = 0; d < 2; ++d)
    #pragma unroll
    for (int m = 0; m < 2; ++m) { m1[d][m][0] = floatx4{0,0,0,0}; m1[d][m][1] = floatx4{0,0,0,0}; }
  #pragma unroll 2
  for (int kk = 0; kk < 8; ++kk) {
    short8 bw[2];
    #pragma unroll
    for (int n = 0; n < 2; ++n) {
      const int col = wid * 32 + n * 16 + l15;
      bw[n] = *(const short8*)&Wm1[(size_t)col * 256 + kk * 32 + lg * 8];
    }
    #pragma unroll
    for (int d = 0; d < 2; ++d) {
      int k0 = kk * 32 + lg * 8;
      if (d && k0 < 128) k0 ^= 64;
      #pragma unroll
      for (int m = 0; m < 2; ++m) {
        const int r = m * 16 + l15;
        const int byte = ((r * 256 + k0) * 2) ^ ((r & 7) << 4);
        const short8 af = *(const short8*)((char*)sA + byte);
        m1[d][m][0] = __builtin_amdgcn_mfma_f32_16x16x32_bf16(af, bw[0], m1[d][m][0], 0, 0, 0);
        m1[d][m][1] = __builtin_amdgcn_mfma_f32_16x16x32_bf16(af, bw[1], m1[d][m][1], 0, 0, 0);
      }
    }
  }
  __syncthreads();

  // ---- per-dir: hidden -> L2 -> store (interleaved mf/mb) ----
  floatx4 mO[2];
  #pragma unroll
  for (int d = 0; d < 2; ++d) {
    #pragma unroll
    for (int n = 0; n < 2; ++n) {
      const int col = wid * 32 + n * 16 + l15;
      const float b1 = Bm1[col];
      #pragma unroll
      for (int m = 0; m < 2; ++m)
        #pragma unroll
        for (int r = 0; r < 4; ++r) {
          const int row = m * 16 + lg * 4 + r;
          const float y = m1[d][m][n][r] + b1;
          sH[row * 264 + col] = f2bf(y > 0.f ? y : 0.f);
        }
    }
    __syncthreads();
    mO[0] = floatx4{0,0,0,0}; mO[1] = floatx4{0,0,0,0};
    #pragma unroll 2
    for (int kk = 0; kk < 8; ++kk) {
      const int col = wid * 16 + l15;
      const short8 bw2 = *(const short8*)&Wm2[(size_t)col * 256 + kk * 32 + lg * 8];
      #pragma unroll
      for (int m = 0; m < 2; ++m) {
        const short8 af = *(const short8*)&sH[(m * 16 + l15) * 264 + kk * 32 + lg * 8];
        mO[m] = __builtin_amdgcn_mfma_f32_16x16x32_bf16(af, bw2, mO[m], 0, 0, 0);
      }
    }
    {
      const int col = wid * 16 + l15;
      const float b2 = Bm2[col];
      #pragma unroll
      for (int m = 0; m < 2; ++m)
        #pragma unroll
        for (int r = 0; r < 4; ++r) {
          const int gr = rowBase + m * 16 + lg * 4 + r;
          MI[(size_t)gr * 256 + d * 128 + col] = f2bf(mO[m][r] + b2);
        }
    }
    if (d == 0) __syncthreads();
  }
}

// ---------------------------------------------------------------------------
// Pair-local segment-sum scatter, interleaved mf/mb input (stride 256/row).
// ---------------------------------------------------------------------------
__global__ __launch_bounds__(512)
void scatter_agg(const u16* __restrict__ MI,
                 const int* __restrict__ FI, const int* __restrict__ TI,
                 u16* __restrict__ AggF, u16* __restrict__ AggB)
{
  const int pair = blockIdx.x >> 1, dir = blockIdx.x & 1;
  const int* SI = dir ? FI : TI;
  u16* Agg      = dir ? AggB : AggF;
  const int tid = threadIdx.x;
  __shared__ float sAgg[NPG * 128];

  for (int i = tid; i < NPG * 128; i += 512) sAgg[i] = 0.f;
  __syncthreads();

  for (int i = tid; i < EPG * 32; i += 512) {
    const int edge = i >> 5, cb = i & 31;
    const int er = pair * EPG + edge;
    const int node = SI[er] - pair * NPG;
    const size_t base = (size_t)er * 256 + dir * 128 + cb;
    #pragma unroll
    for (int k = 0; k < 4; ++k)
      atomicAdd(&sAgg[node * 128 + cb + 32 * k], bf2f(MI[base + 32 * k]));
  }
  __syncthreads();
  unsigned* dst = (unsigned*)(Agg + (size_t)pair * NPG * 128);
  for (int i = tid; i < NPG * 64; i += 512)
    dst[i] = pack2(sAgg[2 * i], sAgg[2 * i + 1]);
}

// ---------------------------------------------------------------------------
// f32 fused MLP (encoders only now)
// ---------------------------------------------------------------------------
template<int K1, int HID, int NOUT, int IN_MODE, int SINGLE, int OUTBF>
__global__ __launch_bounds__(256)
void fused_mlp(const float* __restrict__ X, const float* __restrict__ P1,
               const float* __restrict__ W1, const float* __restrict__ B1,
               const float* __restrict__ W2, const float* __restrict__ B2,
               float* __restrict__ Y, u16* __restrict__ Yb, int maskLen)
{
  constexpr int RT = 32, BK = 32;
  constexpr int J1 = HID / 32;
  constexpr int J2 = NOUT / 32;
  constexpr int BMAX = (HID > NOUT ? HID : NOUT);
  __shared__ float sA[RT * 33];
  __shared__ float sB[BK * BMAX];
  __shared__ float sH[SINGLE ? 1 : RT * (HID + 1)];

  const int t  = threadIdx.x;
  const int tx = t & 31, ty = t >> 5;
  const int rowBase = blockIdx.x * RT;

  float acc[4][J1];
  #pragma unroll
  for (int i = 0; i < 4; ++i)
    #pragma unroll
    for (int j = 0; j < J1; ++j) acc[i][j] = 0.f;

  for (int kb = 0; kb < K1; kb += BK) {
    for (int l = t; l < RT * BK; l += 256) {
      const int r = l >> 5, k = l & 31;
      const int gr = rowBase + r, gk = kb + k;
      float v;
      if constexpr (IN_MODE == 0) {
        v = X[(size_t)gr * K1 + gk];
      } else {
        const int bb = gr >> 8, m = gr & 255;
        constexpr int off = (IN_MODE == 5) ? 0 : EQ_;
        constexpr int len = (IN_MODE == 5) ? EQ_ : EC_;
        v = (m < len) ? P1[((size_t)bb * EPG + off + m) * 128 + gk] : 0.f;
      }
      sA[r * 33 + k] = v;
    }
    for (int l = t * 4; l < BK * HID; l += 1024) {
      *(float4*)&sB[l] = *(const float4*)&W1[(size_t)(kb + l / HID) * HID + (l % HID)];
    }
    __syncthreads();
    #pragma unroll
    for (int k = 0; k < BK; ++k) {
      const float a0 = sA[(ty*4+0)*33+k], a1 = sA[(ty*4+1)*33+k],
                  a2 = sA[(ty*4+2)*33+k], a3 = sA[(ty*4+3)*33+k];
      #pragma unroll
      for (int j = 0; j < J1; ++j) {
        const float bb = sB[k * HID + tx + 32*j];
        acc[0][j] += a0 * bb; acc[1][j] += a1 * bb;
        acc[2][j] += a2 * bb; acc[3][j] += a3 * bb;
      }
    }
    __syncthreads();
  }

  if constexpr (SINGLE) {
    #pragma unroll
    for (int j = 0; j < J1; ++j) {
      const int col = tx + 32*j;
      const float bias = B1[col];
      #pragma unroll
      for (int i = 0; i < 4; ++i) {
        const int gr = rowBase + ty*4 + i;
        if constexpr (OUTBF) Yb[(size_t)gr * HID + col] = f2bf(acc[i][j] + bias);
        else                 Y[(size_t)gr * HID + col] = acc[i][j] + bias;
      }
    }
  }
}

// ---------------------------------------------------------------------------
// Split-bf16 MFMA sinkhorn-feature MLP (f32-accurate via hi/lo decomposition:
// x*w ~ hi*hi + hi*lo + lo*hi, error ~1e-6 relative — safe for exp(10*S)).
// 32 rows/block, 256 thr, 4 waves; K=128 -> HID 64 (relu) -> 64 out (masked).
// Fragment layout copied from the verified frozen mlp_mfma.
// ---------------------------------------------------------------------------
template<int OFFSET, int LEN>
__global__ __launch_bounds__(256)
void sink_mlp_split(const float* __restrict__ E,
                    const u16* __restrict__ W1hi, const u16* __restrict__ W1lo,
                    const float* __restrict__ B1,
                    const u16* __restrict__ W2hi, const u16* __restrict__ W2lo,
                    const float* __restrict__ B2,
                    float* __restrict__ Y)
{
  __shared__ u16 sAhi[32 * 136], sAlo[32 * 136];
  __shared__ u16 sHhi[32 * 72],  sHlo[32 * 72];
  const int tid = threadIdx.x;
  const int rowBase = blockIdx.x * 32;

  for (int ch = tid; ch < 32 * 16; ch += 256) {
    const int r = ch >> 4, kc = ch & 15;
    const int gr = rowBase + r, k0 = kc * 8;
    const int b = gr >> 8, m = gr & 255;
    short8 hi, lo;
    if (m < LEN) {
      const float* src = &E[((size_t)b * EPG + OFFSET + m) * 128 + k0];
      #pragma unroll
      for (int j = 0; j < 8; ++j) {
        const float v = src[j];
        const u16 h = f2bf(v);
        hi[j] = (short)h;
        lo[j] = (short)f2bf(v - bf2f(h));
      }
    } else {
      hi = short8{0,0,0,0,0,0,0,0};
      lo = short8{0,0,0,0,0,0,0,0};
    }
    *(short8*)&sAhi[r * 136 + k0] = hi;
    *(short8*)&sAlo[r * 136 + k0] = lo;
  }
  __syncthreads();

  const int wid = tid >> 6, lane = tid & 63;
  const int l15 = lane & 15, lg = lane >> 4;
  const int col = wid * 16 + l15;

  floatx4 acc[2];
  acc[0] = floatx4{0,0,0,0}; acc[1] = floatx4{0,0,0,0};
  #pragma unroll
  for (int kk = 0; kk < 4; ++kk) {
    const short8 bh = *(const short8*)&W1hi[(size_t)col * 128 + kk * 32 + lg * 8];
    const short8 bl = *(const short8*)&W1lo[(size_t)col * 128 + kk * 32 + lg * 8];
    #pragma unroll
    for (int m = 0; m < 2; ++m) {
      const int r = m * 16 + l15;
      const short8 ahi = *(const short8*)&sAhi[r * 136 + kk * 32 + lg * 8];
      const short8 alo = *(const short8*)&sAlo[r * 136 + kk * 32 + lg * 8];
      acc[m] = __builtin_amdgcn_mfma_f32_16x16x32_bf16(ahi, bh, acc[m], 0, 0, 0);
      acc[m] = __builtin_amdgcn_mfma_f32_16x16x32_bf16(ahi, bl, acc[m], 0, 0, 0);
      acc[m] = __builtin_amdgcn_mfma_f32_16x16x32_bf16(alo, bh, acc[m], 0, 0, 0);
    }
  }
  // hidden: bias + relu, split to hi/lo
  {
    const float b1 = B1[col];
    #pragma unroll
    for (int m = 0; m < 2; ++m)
      #pragma unroll
      for (int r4 = 0; r4 < 4; ++r4) {
        const int row = m * 16 + lg * 4 + r4;
        float y = acc[m][r4] + b1;
        y = y > 0.f ? y : 0.f;
        const u16 h = f2bf(y);
        sHhi[row * 72 + col] = h;
        sHlo[row * 72 + col] = f2bf(y - bf2f(h));
      }
  }
  __syncthreads();
  floatx4 acc2[2];
  acc2[0] = floatx4{0,0,0,0}; acc2[1] = floatx4{0,0,0,0};
  #pragma unroll
  for (int kk = 0; kk < 2; ++kk) {
    const short8 bh = *(const short8*)&W2hi[(size_t)col * 64 + kk * 32 + lg * 8];
    const short8 bl = *(const short8*)&W2lo[(size_t)col * 64 + kk * 32 + lg * 8];
    #pragma unroll
    for (int m = 0; m < 2; ++m) {
      const int r = m * 16 + l15;
      const short8 ahi = *(const short8*)&sHhi[r * 72 + kk * 32 + lg * 8];
      const short8 alo = *(const short8*)&sHlo[r * 72 + kk * 32 + lg * 8];
      acc2[m] = __builtin_amdgcn_mfma_f32_16x16x32_bf16(ahi, bh, acc2[m], 0, 0, 0);
      acc2[m] = __builtin_amdgcn_mfma_f32_16x16x32_bf16(ahi, bl, acc2[m], 0, 0, 0);
      acc2[m] = __builtin_amdgcn_mfma_f32_16x16x32_bf16(alo, bh, acc2[m], 0, 0, 0);
    }
  }
  {
    const float b2 = B2[col];
    #pragma unroll
    for (int m = 0; m < 2; ++m)
      #pragma unroll
      for (int r4 = 0; r4 < 4; ++r4) {
        const int gr = rowBase + m * 16 + lg * 4 + r4;
        float y = acc2[m][r4] + b2;
        if ((gr & 255) >= LEN) y = 0.f;
        Y[(size_t)gr * 64 + col] = y;
      }
  }
}

// ---------------------------------------------------------------------------
// S[b] = scale * fq[b] @ fc[b]^T  (kept f32: S feeds exp(10*S))
// ---------------------------------------------------------------------------
__global__ __launch_bounds__(256)
void gemm_nt_scale(const float* __restrict__ A, const float* __restrict__ Bm,
                   float* __restrict__ C, float scale)
{
  const int b = blockIdx.z, qt = blockIdx.x, ct = blockIdx.y;
  __shared__ float sA[64 * 68];
  __shared__ float sB[64 * 68];
  const int t = threadIdx.x;
  const int tx = t & 15, ty = t >> 4;
  const float* Ab = A  + (size_t)b * 16384 + (size_t)qt * 4096;
  const float* Bb = Bm + (size_t)b * 16384 + (size_t)ct * 4096;
  for (int l = t * 4; l < 64 * 64; l += 1024) {
    const int r = l >> 6, d = l & 63;
    *(float4*)&sA[r*68 + d] = *(const float4*)&Ab[r*64 + d];
    *(float4*)&sB[r*68 + d] = *(const float4*)&Bb[r*64 + d];
  }
  __syncthreads();
  float acc[4][4] = {};
  #pragma unroll
  for (int d = 0; d < 64; ++d) {
    float a[4], bb[4];
    #pragma unroll
    for (int i = 0; i < 4; ++i) a[i]  = sA[(ty*4+i)*68 + d];
    #pragma unroll
    for (int j = 0; j < 4; ++j) bb[j] = sB[(tx+16*j)*68 + d];
    #pragma unroll
    for (int i = 0; i < 4; ++i)
      #pragma unroll
      for (int j = 0; j < 4; ++j) acc[i][j] += a[i] * bb[j];
  }
  float* Cb = C + (size_t)b * 65536 + (size_t)(qt*64) * 256 + ct*64;
  #pragma unroll
  for (int i = 0; i < 4; ++i)
    #pragma unroll
    for (int j = 0; j < 4; ++j)
      Cb[(ty*4+i)*256 + tx + 16*j] = acc[i][j] * scale;
}

// ---------------------------------------------------------------------------
// MFMA plan GEMM: Y = op(P[b]) @ V (round-16/19 proven).
// ---------------------------------------------------------------------------
template<int TRANSA, int EBF16, int OUTBF>
__global__ __launch_bounds__(256)
void gemm_plan_mfma(const float* __restrict__ P, const void* __restrict__ E,
                    void* __restrict__ Y, int RPB, int YOFF, int VOFF,
                    int VLEN, int maskRows)
{
  __shared__ u16 sP[64 * 40];
  __shared__ u16 sVT[128 * 40];
  const int b = blockIdx.y, rt = blockIdx.x;
  const int t = threadIdx.x;
  const int wid = t >> 6, lane = t & 63;
  const int l15 = lane & 15, lg = lane >> 4;
  const float* Pb = P + (size_t)b * 65536;

  floatx4 acc[8];
  #pragma unroll
  for (int n = 0; n < 8; ++n) acc[n] = floatx4{0.f,0.f,0.f,0.f};

  for (int kb = 0; kb < 256; kb += 32) {
    if constexpr (TRANSA == 0) {
      for (int l = t; l < 64 * 32; l += 256) {
        const int r = l >> 5, k = l & 31;
        sP[r * 40 + k] = f2bf(Pb[(size_t)(rt * 64 + r) * 256 + kb + k]);
      }
    } else {
      for (int l = t; l < 64 * 32; l += 256) {
        const int q = l >> 6, c = l & 63;
        sP[c * 40 + q] = f2bf(Pb[(size_t)(kb + q) * 256 + rt * 64 + c]);
      }
    }
    for (int l = t; l < 32 * 128; l += 256) {
      const int k = l >> 7, d = l & 127;
      const int vr = kb + k;
      u16 v = 0;
      if (vr < VLEN) {
        if constexpr (EBF16) v = ((const u16*)E)[((size_t)b * EPG + VOFF + vr) * 128 + d];
        else                 v = f2bf(((const float*)E)[((size_t)b * EPG + VOFF + vr) * 128 + d]);
      }
      sVT[d * 40 + k] = v;
    }
    __syncthreads();
    const short8 af = *(const short8*)&sP[(wid * 16 + l15) * 40 + lg * 8];
    #pragma unroll
    for (int n = 0; n < 8; ++n) {
      const short8 bw = *(const short8*)&sVT[(n * 16 + l15) * 40 + lg * 8];
      acc[n] = __builtin_amdgcn_mfma_f32_16x16x32_bf16(af, bw, acc[n], 0, 0, 0);
    }
    __syncthreads();
  }
  #pragma unroll
  for (int n = 0; n < 8; ++n) {
    const int col = n * 16 + l15;
    #pragma unroll
    for (int r = 0; r < 4; ++r) {
      const int row = rt * 64 + wid * 16 + lg * 4 + r;
      if (row < maskRows) {
        const size_t idx = ((size_t)b * RPB + YOFF + row) * 128 + col;
        if constexpr (OUTBF) ((u16*)Y)[idx] = f2bf(acc[n][r]);
        else                 ((float*)Y)[idx] = acc[n][r];
      }
    }
  }
}

// ---------------------------------------------------------------------------
// Single-pass fused sinkhorn. Row pass keeps max-sub (raw logits can be
// large). Col pass SIMPLIFIED: after the row step, exp(S+u) = p * e^{-v}
// with p row-stochastic and v drift-bounded (>= -log256 per iter), so the
// column accumulator is a plain exp-sum — no max tracking, no branches,
// cross-wave merge is 15 adds + 1 guarded log. (Round-11 VALU evidence.)
// ---------------------------------------------------------------------------
__global__ __launch_bounds__(1024)
void sinkhorn_fused(float* __restrict__ S)
{
  const int b = blockIdx.x, t = threadIdx.x;
  float* Sb = S + (size_t)b * 65536;
  const int w = t >> 6, lane = t & 63;
  const int cbase = lane * 4;
  __shared__ float ps[16 * 256];
  __shared__ float su[256], sv[256];
  if (t < 256) sv[t] = 0.f;
  __syncthreads();

  for (int it = 0; it < 10; ++it) {
    const float4 v4 = *(const float4*)&sv[cbase];
    float4 cs = {0.f, 0.f, 0.f, 0.f};
    #pragma unroll 2
    for (int i = 0; i < 16; ++i) {
      const int r = w * 16 + i;
      const float4 s4 = *(const float4*)&Sb[(size_t)r * 256 + cbase];
      const float ax = s4.x + v4.x, ay = s4.y + v4.y;
      const float az = s4.z + v4.z, aw = s4.w + v4.w;
      float m = fmaxf(fmaxf(ax, ay), fmaxf(az, aw));
      #pragma unroll
      for (int off = 32; off; off >>= 1) m = fmaxf(m, __shfl_xor(m, off));
      float s = __expf(ax - m) + __expf(ay - m) + __expf(az - m) + __expf(aw - m);
      #pragma unroll
      for (int off = 32; off; off >>= 1) s += __shfl_xor(s, off);
      const float u = -(m + __logf(s));
      if (lane == 0) su[r] = u;
      cs.x += __expf(s4.x + u);
      cs.y += __expf(s4.y + u);
      cs.z += __expf(s4.z + u);
      cs.w += __expf(s4.w + u);
    }
    *(float4*)&ps[w * 256 + cbase] = cs;
    __syncthreads();
    if (t < 256) {
      float s = 0.f;
      #pragma unroll
      for (int k = 0; k < 16; ++k) s += ps[k * 256 + t];
      sv[t] = -__logf(fmaxf(s, 1e-38f));
    }
    __syncthreads();
  }
  for (int i = t; i < 16384; i += 1024) {
    const int row = i >> 6, c4 = (i & 63) * 4;
    float4 s4 = *(float4*)&Sb[(size_t)row * 256 + c4];
    const float uu = su[row];
    const float4 v4 = *(const float4*)&sv[c4];
    s4.x = __expf(s4.x + uu + v4.x);
    s4.y = __expf(s4.y + uu + v4.y);
    s4.z = __expf(s4.z + uu + v4.z);
    s4.w = __expf(s4.w + uu + v4.w);
    *(float4*)&Sb[(size_t)row * 256 + c4] = s4;
  }
}

// ---------------------------------------------------------------------------
// score[b] = -sum_{m<256,d} | (m<EQ ? e_q[m,d] : 0) - pc[m,d] |
// ---------------------------------------------------------------------------
__global__ __launch_bounds__(256)
void escore_kernel(const float* __restrict__ e, const float* __restrict__ pc,
                   float* __restrict__ out)
{
  const int b = blockIdx.x, t = threadIdx.x;
  float acc = 0.f;
  for (int i4 = t; i4 < 8192; i4 += 256) {
    const int flat = i4 * 4;
    const int m = flat >> 7, d = flat & 127;
    float4 p = *(const float4*)&pc[((size_t)b * 256 + m) * 128 + d];
    float4 q = {0.f, 0.f, 0.f, 0.f};
    if (m < EQ_) q = *(const float4*)&e[((size_t)b * EPG + m) * 128 + d];
    acc += fabsf(q.x - p.x) + fabsf(q.y - p.y) + fabsf(q.z - p.z) + fabsf(q.w - p.w);
  }
  __shared__ float red[256];
  red[t] = acc; __syncthreads();
  for (int s2 = 128; s2 > 0; s2 >>= 1) { if (t < s2) red[t] += red[t + s2]; __syncthreads(); }
  if (t == 0) out[b] = -red[0];
}

// ---------------------------------------------------------------------------
extern "C" void kernel_launch(void* const* d_in, const int* in_sizes, int n_in,
                              void* d_out, int out_size, void* d_ws, size_t ws_size,
                              hipStream_t stream)
{
  const float* node_features = (const float*)d_in[0];
  const float* edge_features = (const float*)d_in[1];
  const int*   from_idx      = (const int*)d_in[2];
  const int*   to_idx        = (const int*)d_in[3];
  const float* enc_node_W = (const float*)d_in[4];
  const float* enc_node_b = (const float*)d_in[5];
  const float* enc_edge_W = (const float*)d_in[6];
  const float* enc_edge_b = (const float*)d_in[7];
  const float* msg_W1 = (const float*)d_in[8];
  const float* msg_b1 = (const float*)d_in[9];
  const float* msg_W2 = (const float*)d_in[10];
  const float* msg_b2 = (const float*)d_in[11];
  const float* upd_W1 = (const float*)d_in[12];
  const float* upd_b1 = (const float*)d_in[13];
  const float* upd_W2 = (const float*)d_in[14];
  const float* upd_b2 = (const float*)d_in[15];
  const float* int_W1 = (const float*)d_in[16];
  const float* int_b1 = (const float*)d_in[17];
  const float* int_W2 = (const float*)d_in[18];
  const float* int_b2 = (const float*)d_in[19];
  const float* sink_W1 = (const float*)d_in[20];
  const float* sink_b1 = (const float*)d_in[21];
  const float* sink_W2 = (const float*)d_in[22];
  const float* sink_b2 = (const float*)d_in[23];
  float* out = (float*)d_out;

  // ~228.7 MB layout (round-19 proven + ~50KB split weights).
  u16* wsu = (u16*)d_ws;
  u16*   hb  = wsu;                                    // NN*64 bf16
  float* e   = (float*)(wsu + (size_t)NN * 64);        // NE*128 f32
  float* shr = e + (size_t)NE * 128;                   // BATCH*32768 f32
  float* S   = shr + (size_t)BATCH * 32768;            // BATCH*65536 f32
  u16* comb  = (u16*)(S + (size_t)BATCH * 65536);      // NE*128 bf16
  u16* e1b   = comb + (size_t)NE * 128;                // NE*128 bf16 checkpoint
  u16* h1b   = e1b + (size_t)NE * 128;                 // NN*64 bf16 checkpoint
  u16* wi1 = h1b + (size_t)NN * 64;                    // 256x256
  u16* wi2 = wi1 + 65536;                              // 128x256
  u16* wm1 = wi2 + 32768;                              // 256x256
  u16* wm2 = wm1 + 65536;                              // 128x256
  u16* wu1 = wm2 + 32768;                              // 128x320
  u16* wu2 = wu1 + 40960;                              // 64x128
  u16* ws1h = wu2 + 8192;                              // sink W1 hi (64x128)
  u16* ws1l = ws1h + 8192;                             // sink W1 lo
  u16* ws2h = ws1l + 8192;                             // sink W2 hi (64x64)
  u16* ws2l = ws2h + 4096;                             // sink W2 lo

  u16* mI = (u16*)e;                                   // mf/mb interleaved in e rows
  u16* interb = (u16*)shr;                             // NE*128 bf16 (time-shared)
  u16* aggFb  = (u16*)shr;                             // NN*128 bf16
  u16* aggBb  = aggFb + (size_t)NN * 128;
  float* fq   = shr;
  float* fc   = shr + (size_t)BATCH * 16384;
  float* pc   = shr;

  // weights -> bf16, transposed [N][K] (+ split pair for sink MLP)
  wconv<<<256, 256, 0, stream>>>(int_W1, wi1, 256, 256);
  wconv<<<128, 256, 0, stream>>>(int_W2, wi2, 256, 128);
  wconv<<<256, 256, 0, stream>>>(msg_W1, wm1, 256, 256);
  wconv<<<128, 256, 0, stream>>>(msg_W2, wm2, 256, 128);
  wconv<<<160, 256, 0, stream>>>(upd_W1, wu1, 320, 128);
  wconv<<< 32, 256, 0, stream>>>(upd_W2, wu2, 128, 64);
  wconv_split<<<32, 256, 0, stream>>>(sink_W1, ws1h, ws1l, 128, 64);
  wconv_split<<<16, 256, 0, stream>>>(sink_W2, ws2h, ws2l, 64, 64);

  // ================= ts0 =================
  fused_mlp<32,64,64,0,1,1><<<NN/32, 256, 0, stream>>>(
      node_features, nullptr, enc_node_W, enc_node_b, nullptr, nullptr,
      nullptr, hb, -1);
  fused_mlp<32,128,128,0,1,0><<<NE/32, 256, 0, stream>>>(
      edge_features, nullptr, enc_edge_W, enc_edge_b, nullptr, nullptr,
      e, nullptr, -1);

  for (int p = 0; p < 3; ++p) {
    comb_msg_fused<0><<<NE/32, 512, 0, stream>>>(
        e, nullptr, hb, from_idx, to_idx,
        wi1, int_b1, wi2, int_b2, wm1, msg_b1, wm2, msg_b2, comb, mI);
    scatter_agg<<<BATCH*2, 512, 0, stream>>>(mI, from_idx, to_idx, aggFb, aggBb);
    mlp_mfma<320,128,64,3,0,1,4><<<NN/32, 256, 0, stream>>>(
        hb, aggFb, aggBb, nullptr, nullptr, nullptr,
        wu1, upd_b1, wu2, upd_b2, nullptr, hb, nullptr);
    if (p == 0) {
      hipMemcpyAsync(h1b, hb, (size_t)NN * 64 * 2, hipMemcpyDeviceToDevice, stream);
      mlp_mfma<256,256,128,1,1,3,8><<<NE/32, 512, 0, stream>>>(
          hb, nullptr, nullptr, comb, from_idx, to_idx,
          wm1, msg_b1, wm2, msg_b2, e, e1b, nullptr);
    } else {
      mlp_mfma<256,256,128,1,1,0,8><<<NE/32, 512, 0, stream>>>(
          hb, nullptr, nullptr, comb, from_idx, to_idx,
          wm1, msg_b1, wm2, msg_b2, e, nullptr, nullptr);
    }
  }
  sink_mlp_split<0,   EQ_><<<BATCH*8, 256, 0, stream>>>(
      e, ws1h, ws1l, sink_b1, ws2h, ws2l, sink_b2, fq);
  sink_mlp_split<EQ_, EC_><<<BATCH*8, 256, 0, stream>>>(
      e, ws1h, ws1l, sink_b1, ws2h, ws2l, sink_b2, fc);
  gemm_nt_scale<<<dim3(4,4,BATCH), 256, 0, stream>>>(fq, fc, S, 10.0f);
  sinkhorn_fused<<<BATCH, 1024, 0, stream>>>(S);   // S := plan1

  // ================= ts1 (p0 skipped: restore checkpoint) =================
  hipMemcpyAsync(hb, h1b, (size_t)NN * 64 * 2, hipMemcpyDeviceToDevice, stream);
  gemm_plan_mfma<0,1,1><<<dim3(4, BATCH), 256, 0, stream>>>(
      S, e1b, interb, EPG, 0,   EQ_, EC_, EQ_);
  gemm_plan_mfma<1,1,1><<<dim3(4, BATCH), 256, 0, stream>>>(
      S, e1b, interb, EPG, EQ_, 0,   EQ_, EC_);

  // p1
  comb_msg_fused<1><<<NE/32, 512, 0, stream>>>(
      e1b, interb, hb, from_idx, to_idx,
      wi1, int_b1, wi2, int_b2, wm1, msg_b1, wm2, msg_b2, comb, mI);
  scatter_agg<<<BATCH*2, 512, 0, stream>>>(mI, from_idx, to_idx, aggFb, aggBb);
  mlp_mfma<320,128,64,3,0,1,4><<<NN/32, 256, 0, stream>>>(
      hb, aggFb, aggBb, nullptr, nullptr, nullptr,
      wu1, upd_b1, wu2, upd_b2, nullptr, hb, nullptr);
  mlp_mfma<256,256,128,1,1,0,8><<<NE/32, 512, 0, stream>>>(
      hb, nullptr, nullptr, comb, from_idx, to_idx,
      wm1, msg_b1, wm2, msg_b2, e, nullptr, nullptr);
  gemm_plan_mfma<0,0,1><<<dim3(4, BATCH), 256, 0, stream>>>(
      S, e, interb, EPG, 0,   EQ_, EC_, EQ_);
  gemm_plan_mfma<1,0,1><<<dim3(4, BATCH), 256, 0, stream>>>(
      S, e, interb, EPG, EQ_, 0,   EQ_, EC_);

  // p2
  comb_msg_fused<0><<<NE/32, 512, 0, stream>>>(
      e, interb, hb, from_idx, to_idx,
      wi1, int_b1, wi2, int_b2, wm1, msg_b1, wm2, msg_b2, comb, mI);
  scatter_agg<<<BATCH*2, 512, 0, stream>>>(mI, from_idx, to_idx, aggFb, aggBb);
  mlp_mfma<320,128,64,3,0,1,4><<<NN/32, 256, 0, stream>>>(
      hb, aggFb, aggBb, nullptr, nullptr, nullptr,
      wu1, upd_b1, wu2, upd_b2, nullptr, hb, nullptr);
  mlp_mfma<256,256,128,1,1,0,8><<<NE/32, 512, 0, stream>>>(
      hb, nullptr, nullptr, comb, from_idx, to_idx,
      wm1, msg_b1, wm2, msg_b2, e, nullptr, nullptr);

  sink_mlp_split<0,   EQ_><<<BATCH*8, 256, 0, stream>>>(
      e, ws1h, ws1l, sink_b1, ws2h, ws2l, sink_b2, fq);
  sink_mlp_split<EQ_, EC_><<<BATCH*8, 256, 0, stream>>>(
      e, ws1h, ws1l, sink_b1, ws2h, ws2l, sink_b2, fc);
  gemm_nt_scale<<<dim3(4,4,BATCH), 256, 0, stream>>>(fq, fc, S, 10.0f);
  sinkhorn_fused<<<BATCH, 1024, 0, stream>>>(S);   // S := plan2

  // final score
  gemm_plan_mfma<0,0,0><<<dim3(4, BATCH), 256, 0, stream>>>(
      S, e, pc, 256, 0, EQ_, EC_, 256);
  escore_kernel<<<BATCH, 256, 0, stream>>>(e, pc, out);
}

// Round 21
// 3264.244 us; speedup vs baseline: 1.8791x; 1.0022x over previous
//
#include <hip/hip_runtime.h>
#include <math.h>

constexpr int BATCH = 256;
constexpr int EQ_   = 192;
constexpr int EC_   = 240;
constexpr int EPG   = 432;   // edges per pair
constexpr int NPG   = 216;   // nodes per pair
constexpr int NN    = BATCH * NPG;   // 55296
constexpr int NE    = BATCH * EPG;   // 110592

typedef __attribute__((ext_vector_type(8))) short short8;
typedef __attribute__((ext_vector_type(4))) float floatx4;
typedef unsigned short u16;

__device__ __forceinline__ u16 f2bf(float x) {
  union { float f; unsigned u; } c; c.f = x;
  const unsigned r = (c.u + 0x7FFFu + ((c.u >> 16) & 1u)) >> 16;
  return (u16)r;
}
__device__ __forceinline__ float bf2f(u16 x) {
  union { unsigned u; float f; } c; c.u = ((unsigned)x) << 16;
  return c.f;
}
__device__ __forceinline__ unsigned pack2(float a, float b) {
  return (unsigned)f2bf(a) | ((unsigned)f2bf(b) << 16);
}
__device__ __forceinline__ short8 cvt8(const float* __restrict__ p) {
  const float4 a = *(const float4*)p;
  const float4 b = *(const float4*)(p + 4);
  short8 o;
  o[0]=(short)f2bf(a.x); o[1]=(short)f2bf(a.y); o[2]=(short)f2bf(a.z); o[3]=(short)f2bf(a.w);
  o[4]=(short)f2bf(b.x); o[5]=(short)f2bf(b.y); o[6]=(short)f2bf(b.z); o[7]=(short)f2bf(b.w);
  return o;
}

__device__ __forceinline__ void lse_online(float& m, float& s, float tt) {
  if (tt > m) { s = s * __expf(m - tt) + 1.f; m = tt; }
  else        { s += __expf(tt - m); }
}

// ---------------------------------------------------------------------------
// weight transpose + f32->bf16:  out[n*K+k] = bf16(W[k*N+n])
// ---------------------------------------------------------------------------
__global__ __launch_bounds__(256)
void wconv(const float* __restrict__ W, u16* __restrict__ out, int K, int N)
{
  const int i = blockIdx.x * 256 + threadIdx.x;
  if (i < K * N) {
    const int n = i / K, k = i - n * K;
    out[i] = f2bf(W[(size_t)k * N + n]);
  }
}

// split variant: hi = bf16(w), lo = bf16(w - hi)   (for split-bf16 f32 GEMM)
__global__ __launch_bounds__(256)
void wconv_split(const float* __restrict__ W, u16* __restrict__ hi,
                 u16* __restrict__ lo, int K, int N)
{
  const int i = blockIdx.x * 256 + threadIdx.x;
  if (i < K * N) {
    const int n = i / K, k = i - n * K;
    const float w = W[(size_t)k * N + n];
    const u16 h = f2bf(w);
    hi[i] = h;
    lo[i] = f2bf(w - bf2f(h));
  }
}

// ---------------------------------------------------------------------------
// MFMA fused 2-layer MLP — round-12 m-loop variant (frozen).
// ---------------------------------------------------------------------------
template<int K1, int HID, int NOUT, int IN_MODE, int DUAL, int OUT_MODE, int WAVES>
__global__ __launch_bounds__(WAVES * 64, 4)
void mlp_mfma(const void* __restrict__ X, const void* __restrict__ P2,
              const void* __restrict__ P3, const u16* __restrict__ CB,
              const int* __restrict__ IA, const int* __restrict__ IB,
              const u16* __restrict__ W1t, const float* __restrict__ B1,
              const u16* __restrict__ W2t, const float* __restrict__ B2,
              float* __restrict__ Yf, u16* __restrict__ Yb0, u16* __restrict__ Yb1)
{
  constexpr int RT  = 32;
  constexpr int THREADS = WAVES * 64;
  constexpr int KCH = K1 / 8;
  constexpr int NT1 = HID / (WAVES * 16);
  constexpr int NT2 = (NOUT / (WAVES * 16) > 0) ? NOUT / (WAVES * 16) : 1;
  constexpr int SAB = RT * K1 * 2;
  constexpr int SHB = RT * (HID + 8) * 2;
  __shared__ __align__(16) char smem[(SAB > SHB ? SAB : SHB)];
  u16* sA = (u16*)smem;
  u16* sH = (u16*)smem;

  const int tid = threadIdx.x;
  const int rowBase = blockIdx.x * RT;

  for (int ch = tid; ch < RT * KCH; ch += THREADS) {
    const int r = ch / KCH, kc = ch - r * KCH;
    const int gr = rowBase + r, k0 = kc * 8;
    short8 pk;
    if constexpr (IN_MODE == 4) {
      const float* Xf  = (const float*)X;
      const float* P2f = (const float*)P2;
      if (k0 < 128)      pk = cvt8(&Xf[(size_t)gr * 128 + k0]);
      else if (P2f)      pk = cvt8(&P2f[(size_t)gr * 128 + (k0 - 128)]);
      else { pk = short8{0,0,0,0,0,0,0,0}; }
    } else if constexpr (IN_MODE == 1) {
      const u16* Hb = (const u16*)X;
      if (k0 < 64)       pk = *(const short8*)&Hb[(size_t)IA[gr] * 64 + k0];
      else if (k0 < 128) pk = *(const short8*)&Hb[(size_t)IB[gr] * 64 + (k0 - 64)];
      else               pk = *(const short8*)&CB[(size_t)gr * 128 + (k0 - 128)];
    } else { // 3
      const u16* Hb = (const u16*)X;
      const u16* A0 = (const u16*)P2;
      const u16* A1 = (const u16*)P3;
      if (k0 < 64)       pk = *(const short8*)&Hb[(size_t)gr * 64 + k0];
      else if (k0 < 192) pk = *(const short8*)&A0[(size_t)gr * 128 + (k0 - 64)];
      else               pk = *(const short8*)&A1[(size_t)gr * 128 + (k0 - 192)];
    }
    const int byte = ((r * K1 + k0) * 2) ^ ((r & 7) << 4);
    *(short8*)((char*)sA + byte) = pk;
  }
  __syncthreads();

  const int wid = tid >> 6, lane = tid & 63;
  const int l15 = lane & 15, lg = lane >> 4;

  floatx4 acc1[1 + DUAL][2][NT1];
  #pragma unroll
  for (int d = 0; d <= DUAL; ++d)
    #pragma unroll
    for (int m = 0; m < 2; ++m)
      #pragma unroll
      for (int n = 0; n < NT1; ++n) acc1[d][m][n] = floatx4{0.f,0.f,0.f,0.f};

  #pragma unroll 2
  for (int kk = 0; kk < K1 / 32; ++kk) {
    short8 bw[NT1];
    #pragma unroll
    for (int n = 0; n < NT1; ++n) {
      const int col = wid * (HID / WAVES) + n * 16 + l15;
      bw[n] = *(const short8*)&W1t[(size_t)col * K1 + kk * 32 + lg * 8];
    }
    #pragma unroll
    for (int d = 0; d <= DUAL; ++d) {
      int k0 = kk * 32 + lg * 8;
      if (DUAL && d && k0 < 128) k0 ^= 64;
      #pragma unroll
      for (int m = 0; m < 2; ++m) {
        const int r = m * 16 + l15;
        const int byte = ((r * K1 + k0) * 2) ^ ((r & 7) << 4);
        const short8 af = *(const short8*)((char*)sA + byte);
        #pragma unroll
        for (int n = 0; n < NT1; ++n)
          acc1[d][m][n] = __builtin_amdgcn_mfma_f32_16x16x32_bf16(af, bw[n], acc1[d][m][n], 0, 0, 0);
      }
    }
  }
  __syncthreads();   // sA dead from here; smem becomes sH

  floatx4 accO[2][NT2];
  #pragma unroll
  for (int m = 0; m < 2; ++m)
    #pragma unroll
    for (int n = 0; n < NT2; ++n) accO[m][n] = floatx4{0.f,0.f,0.f,0.f};

  #pragma unroll
  for (int d = 0; d <= DUAL; ++d) {
    #pragma unroll
    for (int n = 0; n < NT1; ++n) {
      const int col = wid * (HID / WAVES) + n * 16 + l15;
      const float b1 = B1[col];
      #pragma unroll
      for (int m = 0; m < 2; ++m)
        #pragma unroll
        for (int r = 0; r < 4; ++r) {
          const int row = m * 16 + lg * 4 + r;
          const float y = acc1[d][m][n][r] + b1;
          sH[row * (HID + 8) + col] = f2bf(y > 0.f ? y : 0.f);
        }
    }
    __syncthreads();
    if (OUT_MODE == 2 && d == 1) {
      #pragma unroll
      for (int m = 0; m < 2; ++m)
        #pragma unroll
        for (int n = 0; n < NT2; ++n) accO[m][n] = floatx4{0.f,0.f,0.f,0.f};
    }
    #pragma unroll 2
    for (int kk = 0; kk < HID / 32; ++kk) {
      short8 bw2[NT2];
      #pragma unroll
      for (int n = 0; n < NT2; ++n) {
        const int col = wid * (NOUT / WAVES) + n * 16 + l15;
        bw2[n] = *(const short8*)&W2t[(size_t)col * HID + kk * 32 + lg * 8];
      }
      #pragma unroll
      for (int m = 0; m < 2; ++m) {
        const short8 af = *(const short8*)&sH[(m * 16 + l15) * (HID + 8) + kk * 32 + lg * 8];
        #pragma unroll
        for (int n = 0; n < NT2; ++n)
          accO[m][n] = __builtin_amdgcn_mfma_f32_16x16x32_bf16(af, bw2[n], accO[m][n], 0, 0, 0);
      }
    }
    if constexpr (OUT_MODE == 2) {
      u16* Y = d ? Yb1 : Yb0;
      #pragma unroll
      for (int n = 0; n < NT2; ++n) {
        const int col = wid * (NOUT / WAVES) + n * 16 + l15;
        const float b2 = B2[col];
        #pragma unroll
        for (int m = 0; m < 2; ++m)
          #pragma unroll
          for (int r = 0; r < 4; ++r) {
            const int gr = rowBase + m * 16 + lg * 4 + r;
            Y[(size_t)gr * NOUT + col] = f2bf(accO[m][n][r] + b2);
          }
      }
    }
    if (DUAL && d == 0) __syncthreads();
  }

  if constexpr (OUT_MODE != 2) {
    #pragma unroll
    for (int n = 0; n < NT2; ++n) {
      const int col = wid * (NOUT / WAVES) + n * 16 + l15;
      const float b2 = B2[col] * (float)(1 + DUAL);
      #pragma unroll
      for (int m = 0; m < 2; ++m)
        #pragma unroll
        for (int r = 0; r < 4; ++r) {
          const int gr = rowBase + m * 16 + lg * 4 + r;
          const float y = accO[m][n][r] + b2;
          if constexpr (OUT_MODE == 1) {
            Yb0[(size_t)gr * NOUT + col] = f2bf(y);
          } else {
            Yf[(size_t)gr * NOUT + col] = y;
            if constexpr (OUT_MODE == 3)
              Yb0[(size_t)gr * NOUT + col] = f2bf(y);
          }
        }
    }
  }
}

// ---------------------------------------------------------------------------
// FUSED comb-MLP + msg-MLP (round-18/19 proven, block-local mf/mb alias).
// ---------------------------------------------------------------------------
template<int EBF16>
__global__ __launch_bounds__(512, 4)
void comb_msg_fused(const void* __restrict__ E, const u16* __restrict__ INTER,
                    const u16* __restrict__ Hb,
                    const int* __restrict__ IA, const int* __restrict__ IB,
                    const u16* __restrict__ Wi1, const float* __restrict__ Bi1,
                    const u16* __restrict__ Wi2, const float* __restrict__ Bi2,
                    const u16* __restrict__ Wm1, const float* __restrict__ Bm1,
                    const u16* __restrict__ Wm2, const float* __restrict__ Bm2,
                    u16* __restrict__ COMB, u16* __restrict__ MI)
{
  constexpr int RT = 32;
  __shared__ __align__(16) char smem[RT * (256 + 8) * 2];   // 16896 B
  u16* sA = (u16*)smem;
  u16* sH = (u16*)smem;

  const int tid = threadIdx.x;
  const int rowBase = blockIdx.x * RT;
  const int wid = tid >> 6, lane = tid & 63;
  const int l15 = lane & 15, lg = lane >> 4;

  // ---- stage [e, inter] ----
  for (int ch = tid; ch < RT * 32; ch += 512) {
    const int r = ch >> 5, kc = ch & 31;
    const int gr = rowBase + r, k0 = kc * 8;
    short8 pk;
    if (k0 < 128) {
      if constexpr (EBF16) pk = *(const short8*)&((const u16*)E)[(size_t)gr * 128 + k0];
      else                 pk = cvt8(&((const float*)E)[(size_t)gr * 128 + k0]);
    }
    else if (INTER) pk = *(const short8*)&INTER[(size_t)gr * 128 + (k0 - 128)];
    else            pk = short8{0,0,0,0,0,0,0,0};
    const int byte = ((r * 256 + k0) * 2) ^ ((r & 7) << 4);
    *(short8*)((char*)sA + byte) = pk;
  }
  __syncthreads();

  // ---- comb L1 ----
  floatx4 c1[2][2];
  #pragma unroll
  for (int m = 0; m < 2; ++m) { c1[m][0] = floatx4{0,0,0,0}; c1[m][1] = floatx4{0,0,0,0}; }
  #pragma unroll 2
  for (int kk = 0; kk < 8; ++kk) {
    short8 bw[2];
    #pragma unroll
    for (int n = 0; n < 2; ++n) {
      const int col = wid * 32 + n * 16 + l15;
      bw[n] = *(const short8*)&Wi1[(size_t)col * 256 + kk * 32 + lg * 8];
    }
    #pragma unroll
    for (int m = 0; m < 2; ++m) {
      const int r = m * 16 + l15;
      const int byte = ((r * 256 + kk * 32 + lg * 8) * 2) ^ ((r & 7) << 4);
      const short8 af = *(const short8*)((char*)sA + byte);
      c1[m][0] = __builtin_amdgcn_mfma_f32_16x16x32_bf16(af, bw[0], c1[m][0], 0, 0, 0);
      c1[m][1] = __builtin_amdgcn_mfma_f32_16x16x32_bf16(af, bw[1], c1[m][1], 0, 0, 0);
    }
  }
  __syncthreads();
  #pragma unroll
  for (int n = 0; n < 2; ++n) {
    const int col = wid * 32 + n * 16 + l15;
    const float b1 = Bi1[col];
    #pragma unroll
    for (int m = 0; m < 2; ++m)
      #pragma unroll
      for (int r = 0; r < 4; ++r) {
        const int row = m * 16 + lg * 4 + r;
        const float y = c1[m][n][r] + b1;
        sH[row * 264 + col] = f2bf(y > 0.f ? y : 0.f);
      }
  }
  __syncthreads();
  // ---- comb L2 ----
  floatx4 cO[2];
  cO[0] = floatx4{0,0,0,0}; cO[1] = floatx4{0,0,0,0};
  #pragma unroll 2
  for (int kk = 0; kk < 8; ++kk) {
    const int col = wid * 16 + l15;
    const short8 bw2 = *(const short8*)&Wi2[(size_t)col * 256 + kk * 32 + lg * 8];
    #pragma unroll
    for (int m = 0; m < 2; ++m) {
      const short8 af = *(const short8*)&sH[(m * 16 + l15) * 264 + kk * 32 + lg * 8];
      cO[m] = __builtin_amdgcn_mfma_f32_16x16x32_bf16(af, bw2, cO[m], 0, 0, 0);
    }
  }
  __syncthreads();

  // ---- write comb (global + swizzled LDS k0>=128), gather h (k0<128) ----
  {
    const int col = wid * 16 + l15;
    const float b2 = Bi2[col];
    #pragma unroll
    for (int m = 0; m < 2; ++m)
      #pragma unroll
      for (int r = 0; r < 4; ++r) {
        const int row = m * 16 + lg * 4 + r;
        const int gr = rowBase + row;
        const u16 v = f2bf(cO[m][r] + b2);
        COMB[(size_t)gr * 128 + col] = v;
        const int k0 = 128 + col;
        const int byte = ((row * 256 + k0) * 2) ^ ((row & 7) << 4);
        *(u16*)((char*)sA + byte) = v;
      }
  }
  for (int ch = tid; ch < RT * 16; ch += 512) {
    const int r = ch >> 4, kc = ch & 15;
    const int gr = rowBase + r, k0 = kc * 8;
    short8 pk;
    if (k0 < 64) pk = *(const short8*)&Hb[(size_t)IA[gr] * 64 + k0];
    else         pk = *(const short8*)&Hb[(size_t)IB[gr] * 64 + (k0 - 64)];
    const int byte = ((r * 256 + k0) * 2) ^ ((r & 7) << 4);
    *(short8*)((char*)sA + byte) = pk;
  }
  __syncthreads();

  // ---- msg L1 (DUAL) ----
  floatx4 m1[2][2][2];
  #pragma unroll
  for (int d = 0; d < 2; ++d)
    #pragma unroll
    for (int m = 0; m < 2; ++m) { m1[d][m][0] = floatx4{0,0,0,0}; m1[d][m][1] = floatx4{0,0,0,0}; }
  #pragma unroll 2
  for (int kk = 0; kk < 8; ++kk) {
    short8 bw[2];
    #pragma unroll
    for (int n = 0; n < 2; ++n) {
      const int col = wid * 32 + n * 16 + l15;
      bw[n] = *(const short8*)&Wm1[(size_t)col * 256 + kk * 32 + lg * 8];
    }
    #pragma unroll
    for (int d = 0; d < 2; ++d) {
      int k0 = kk * 32 + lg * 8;
      if (d && k0 < 128) k0 ^= 64;
      #pragma unroll
      for (int m = 0; m < 2; ++m) {
        const int r = m * 16 + l15;
        const int byte = ((r * 256 + k0) * 2) ^ ((r & 7) << 4);
        const short8 af = *(const short8*)((char*)sA + byte);
        m1[d][m][0] = __builtin_amdgcn_mfma_f32_16x16x32_bf16(af, bw[0], m1[d][m][0], 0, 0, 0);
        m1[d][m][1] = __builtin_amdgcn_mfma_f32_16x16x32_bf16(af, bw[1], m1[d][m][1], 0, 0, 0);
      }
    }
  }
  __syncthreads();

  // ---- per-dir: hidden -> L2 -> store (interleaved mf/mb) ----
  floatx4 mO[2];
  #pragma unroll
  for (int d = 0; d < 2; ++d) {
    #pragma unroll
    for (int n = 0; n < 2; ++n) {
      const int col = wid * 32 + n * 16 + l15;
      const float b1 = Bm1[col];
      #pragma unroll
      for (int m = 0; m < 2; ++m)
        #pragma unroll
        for (int r = 0; r < 4; ++r) {
          const int row = m * 16 + lg * 4 + r;
          const float y = m1[d][m][n][r] + b1;
          sH[row * 264 + col] = f2bf(y > 0.f ? y : 0.f);
        }
    }
    __syncthreads();
    mO[0] = floatx4{0,0,0,0}; mO[1] = floatx4{0,0,0,0};
    #pragma unroll 2
    for (int kk = 0; kk < 8; ++kk) {
      const int col = wid * 16 + l15;
      const short8 bw2 = *(const short8*)&Wm2[(size_t)col * 256 + kk * 32 + lg * 8];
      #pragma unroll
      for (int m = 0; m < 2; ++m) {
        const short8 af = *(const short8*)&sH[(m * 16 + l15) * 264 + kk * 32 + lg * 8];
        mO[m] = __builtin_amdgcn_mfma_f32_16x16x32_bf16(af, bw2, mO[m], 0, 0, 0);
      }
    }
    {
      const int col = wid * 16 + l15;
      const float b2 = Bm2[col];
      #pragma unroll
      for (int m = 0; m < 2; ++m)
        #pragma unroll
        for (int r = 0; r < 4; ++r) {
          const int gr = rowBase + m * 16 + lg * 4 + r;
          MI[(size_t)gr * 256 + d * 128 + col] = f2bf(mO[m][r] + b2);
        }
    }
    if (d == 0) __syncthreads();
  }
}

// ---------------------------------------------------------------------------
// Pair-local segment-sum scatter, COLUMN-SPLIT: block = pair*4 + dir*2 + half.
// sAgg 216x64 f32 (stride 65 for banks) = 56.2 KB -> 2 blocks/CU (was 1 at
// 110 KB). Same per-(node,col) accumulation sets; atomic order was already
// nondeterministic-tolerant.
// ---------------------------------------------------------------------------
__global__ __launch_bounds__(512)
void scatter_agg(const u16* __restrict__ MI,
                 const int* __restrict__ FI, const int* __restrict__ TI,
                 u16* __restrict__ AggF, u16* __restrict__ AggB)
{
  const int pair = blockIdx.x >> 2, dir = (blockIdx.x >> 1) & 1, half = blockIdx.x & 1;
  const int* SI = dir ? FI : TI;
  u16* Agg      = dir ? AggB : AggF;
  const int tid = threadIdx.x;
  __shared__ float sAgg[NPG * 65];   // 56160 B

  for (int i = tid; i < NPG * 65; i += 512) sAgg[i] = 0.f;
  __syncthreads();

  for (int i = tid; i < EPG * 16; i += 512) {
    const int edge = i >> 4, c0 = i & 15;
    const int er = pair * EPG + edge;
    const int node = SI[er] - pair * NPG;
    const size_t base = (size_t)er * 256 + dir * 128 + half * 64 + c0;
    #pragma unroll
    for (int k = 0; k < 4; ++k)
      atomicAdd(&sAgg[node * 65 + c0 + 16 * k], bf2f(MI[base + 16 * k]));
  }
  __syncthreads();
  for (int i = tid; i < NPG * 32; i += 512) {
    const int node = i >> 5, cp = i & 31;
    unsigned* dst = (unsigned*)(Agg + (size_t)(pair * NPG + node) * 128 + half * 64);
    dst[cp] = pack2(sAgg[node * 65 + 2 * cp], sAgg[node * 65 + 2 * cp + 1]);
  }
}

// ---------------------------------------------------------------------------
// f32 fused MLP (encoders only)
// ---------------------------------------------------------------------------
template<int K1, int HID, int NOUT, int IN_MODE, int SINGLE, int OUTBF>
__global__ __launch_bounds__(256)
void fused_mlp(const float* __restrict__ X, const float* __restrict__ P1,
               const float* __restrict__ W1, const float* __restrict__ B1,
               const float* __restrict__ W2, const float* __restrict__ B2,
               float* __restrict__ Y, u16* __restrict__ Yb, int maskLen)
{
  constexpr int RT = 32, BK = 32;
  constexpr int J1 = HID / 32;
  constexpr int BMAX = HID;
  __shared__ float sA[RT * 33];
  __shared__ float sB[BK * BMAX];

  const int t  = threadIdx.x;
  const int tx = t & 31, ty = t >> 5;
  const int rowBase = blockIdx.x * RT;

  float acc[4][J1];
  #pragma unroll
  for (int i = 0; i < 4; ++i)
    #pragma unroll
    for (int j = 0; j < J1; ++j) acc[i][j] = 0.f;

  for (int kb = 0; kb < K1; kb += BK) {
    for (int l = t; l < RT * BK; l += 256) {
      const int r = l >> 5, k = l & 31;
      const int gr = rowBase + r, gk = kb + k;
      float v = X[(size_t)gr * K1 + gk];
      sA[r * 33 + k] = v;
    }
    for (int l = t * 4; l < BK * HID; l += 1024) {
      *(float4*)&sB[l] = *(const float4*)&W1[(size_t)(kb + l / HID) * HID + (l % HID)];
    }
    __syncthreads();
    #pragma unroll
    for (int k = 0; k < BK; ++k) {
      const float a0 = sA[(ty*4+0)*33+k], a1 = sA[(ty*4+1)*33+k],
                  a2 = sA[(ty*4+2)*33+k], a3 = sA[(ty*4+3)*33+k];
      #pragma unroll
      for (int j = 0; j < J1; ++j) {
        const float bb = sB[k * HID + tx + 32*j];
        acc[0][j] += a0 * bb; acc[1][j] += a1 * bb;
        acc[2][j] += a2 * bb; acc[3][j] += a3 * bb;
      }
    }
    __syncthreads();
  }

  #pragma unroll
  for (int j = 0; j < J1; ++j) {
    const int col = tx + 32*j;
    const float bias = B1[col];
    #pragma unroll
    for (int i = 0; i < 4; ++i) {
      const int gr = rowBase + ty*4 + i;
      if constexpr (OUTBF) Yb[(size_t)gr * HID + col] = f2bf(acc[i][j] + bias);
      else                 Y[(size_t)gr * HID + col] = acc[i][j] + bias;
    }
  }
}

// ---------------------------------------------------------------------------
// Split-bf16 MFMA sinkhorn-feature MLP (round-20 proven).
// ---------------------------------------------------------------------------
template<int OFFSET, int LEN>
__global__ __launch_bounds__(256)
void sink_mlp_split(const float* __restrict__ E,
                    const u16* __restrict__ W1hi, const u16* __restrict__ W1lo,
                    const float* __restrict__ B1,
                    const u16* __restrict__ W2hi, const u16* __restrict__ W2lo,
                    const float* __restrict__ B2,
                    float* __restrict__ Y)
{
  __shared__ u16 sAhi[32 * 136], sAlo[32 * 136];
  __shared__ u16 sHhi[32 * 72],  sHlo[32 * 72];
  const int tid = threadIdx.x;
  const int rowBase = blockIdx.x * 32;

  for (int ch = tid; ch < 32 * 16; ch += 256) {
    const int r = ch >> 4, kc = ch & 15;
    const int gr = rowBase + r, k0 = kc * 8;
    const int b = gr >> 8, m = gr & 255;
    short8 hi, lo;
    if (m < LEN) {
      const float* src = &E[((size_t)b * EPG + OFFSET + m) * 128 + k0];
      #pragma unroll
      for (int j = 0; j < 8; ++j) {
        const float v = src[j];
        const u16 h = f2bf(v);
        hi[j] = (short)h;
        lo[j] = (short)f2bf(v - bf2f(h));
      }
    } else {
      hi = short8{0,0,0,0,0,0,0,0};
      lo = short8{0,0,0,0,0,0,0,0};
    }
    *(short8*)&sAhi[r * 136 + k0] = hi;
    *(short8*)&sAlo[r * 136 + k0] = lo;
  }
  __syncthreads();

  const int wid = tid >> 6, lane = tid & 63;
  const int l15 = lane & 15, lg = lane >> 4;
  const int col = wid * 16 + l15;

  floatx4 acc[2];
  acc[0] = floatx4{0,0,0,0}; acc[1] = floatx4{0,0,0,0};
  #pragma unroll
  for (int kk = 0; kk < 4; ++kk) {
    const short8 bh = *(const short8*)&W1hi[(size_t)col * 128 + kk * 32 + lg * 8];
    const short8 bl = *(const short8*)&W1lo[(size_t)col * 128 + kk * 32 + lg * 8];
    #pragma unroll
    for (int m = 0; m < 2; ++m) {
      const int r = m * 16 + l15;
      const short8 ahi = *(const short8*)&sAhi[r * 136 + kk * 32 + lg * 8];
      const short8 alo = *(const short8*)&sAlo[r * 136 + kk * 32 + lg * 8];
      acc[m] = __builtin_amdgcn_mfma_f32_16x16x32_bf16(ahi, bh, acc[m], 0, 0, 0);
      acc[m] = __builtin_amdgcn_mfma_f32_16x16x32_bf16(ahi, bl, acc[m], 0, 0, 0);
      acc[m] = __builtin_amdgcn_mfma_f32_16x16x32_bf16(alo, bh, acc[m], 0, 0, 0);
    }
  }
  {
    const float b1 = B1[col];
    #pragma unroll
    for (int m = 0; m < 2; ++m)
      #pragma unroll
      for (int r4 = 0; r4 < 4; ++r4) {
        const int row = m * 16 + lg * 4 + r4;
        float y = acc[m][r4] + b1;
        y = y > 0.f ? y : 0.f;
        const u16 h = f2bf(y);
        sHhi[row * 72 + col] = h;
        sHlo[row * 72 + col] = f2bf(y - bf2f(h));
      }
  }
  __syncthreads();
  floatx4 acc2[2];
  acc2[0] = floatx4{0,0,0,0}; acc2[1] = floatx4{0,0,0,0};
  #pragma unroll
  for (int kk = 0; kk < 2; ++kk) {
    const short8 bh = *(const short8*)&W2hi[(size_t)col * 64 + kk * 32 + lg * 8];
    const short8 bl = *(const short8*)&W2lo[(size_t)col * 64 + kk * 32 + lg * 8];
    #pragma unroll
    for (int m = 0; m < 2; ++m) {
      const int r = m * 16 + l15;
      const short8 ahi = *(const short8*)&sHhi[r * 72 + kk * 32 + lg * 8];
      const short8 alo = *(const short8*)&sHlo[r * 72 + kk * 32 + lg * 8];
      acc2[m] = __builtin_amdgcn_mfma_f32_16x16x32_bf16(ahi, bh, acc2[m], 0, 0, 0);
      acc2[m] = __builtin_amdgcn_mfma_f32_16x16x32_bf16(ahi, bl, acc2[m], 0, 0, 0);
      acc2[m] = __builtin_amdgcn_mfma_f32_16x16x32_bf16(alo, bh, acc2[m], 0, 0, 0);
    }
  }
  {
    const float b2 = B2[col];
    #pragma unroll
    for (int m = 0; m < 2; ++m)
      #pragma unroll
      for (int r4 = 0; r4 < 4; ++r4) {
        const int gr = rowBase + m * 16 + lg * 4 + r4;
        float y = acc2[m][r4] + b2;
        if ((gr & 255) >= LEN) y = 0.f;
        Y[(size_t)gr * 64 + col] = y;
      }
  }
}

// ---------------------------------------------------------------------------
// Split-bf16 MFMA S-GEMM: S[b] = scale * fq[b] @ fc[b]^T. hi/lo decomposition
// (3 MFMAs) keeps rel error ~1.5e-5 — safe for exp(10*S). Block = (qt, ct, b),
// 64x64 output tile, 256 thr, 4 waves. Fragment mapping per frozen kernels.
// ---------------------------------------------------------------------------
__global__ __launch_bounds__(256)
void gemm_nt_split(const float* __restrict__ A, const float* __restrict__ Bm,
                   float* __restrict__ C, float scale)
{
  __shared__ u16 sQh[64 * 72], sQl[64 * 72];
  __shared__ u16 sCh[64 * 72], sCl[64 * 72];
  const int b = blockIdx.z, qt = blockIdx.x, ct = blockIdx.y;
  const int t = threadIdx.x;
  const float* Ab = A  + (size_t)b * 16384 + (size_t)qt * 4096;
  const float* Bb = Bm + (size_t)b * 16384 + (size_t)ct * 4096;

  for (int i = t; i < 64 * 64; i += 256) {
    const int r = i >> 6, d = i & 63;
    float v = Ab[r * 64 + d];
    u16 h = f2bf(v);
    sQh[r * 72 + d] = h;
    sQl[r * 72 + d] = f2bf(v - bf2f(h));
    v = Bb[r * 64 + d];
    h = f2bf(v);
    sCh[r * 72 + d] = h;
    sCl[r * 72 + d] = f2bf(v - bf2f(h));
  }
  __syncthreads();

  const int wid = t >> 6, lane = t & 63;
  const int l15 = lane & 15, lg = lane >> 4;

  floatx4 acc[4];
  #pragma unroll
  for (int n = 0; n < 4; ++n) acc[n] = floatx4{0.f,0.f,0.f,0.f};

  #pragma unroll
  for (int kk = 0; kk < 2; ++kk) {
    const short8 ahi = *(const short8*)&sQh[(wid * 16 + l15) * 72 + kk * 32 + lg * 8];
    const short8 alo = *(const short8*)&sQl[(wid * 16 + l15) * 72 + kk * 32 + lg * 8];
    #pragma unroll
    for (int n = 0; n < 4; ++n) {
      const short8 bh = *(const short8*)&sCh[(n * 16 + l15) * 72 + kk * 32 + lg * 8];
      const short8 bl = *(const short8*)&sCl[(n * 16 + l15) * 72 + kk * 32 + lg * 8];
      acc[n] = __builtin_amdgcn_mfma_f32_16x16x32_bf16(ahi, bh, acc[n], 0, 0, 0);
      acc[n] = __builtin_amdgcn_mfma_f32_16x16x32_bf16(ahi, bl, acc[n], 0, 0, 0);
      acc[n] = __builtin_amdgcn_mfma_f32_16x16x32_bf16(alo, bh, acc[n], 0, 0, 0);
    }
  }
  float* Cb = C + (size_t)b * 65536;
  #pragma unroll
  for (int n = 0; n < 4; ++n) {
    const int col = ct * 64 + n * 16 + l15;
    #pragma unroll
    for (int r4 = 0; r4 < 4; ++r4) {
      const int row = qt * 64 + wid * 16 + lg * 4 + r4;
      Cb[(size_t)row * 256 + col] = acc[n][r4] * scale;
    }
  }
}

// ---------------------------------------------------------------------------
// MFMA plan GEMM: Y = op(P[b]) @ V (round-16/19 proven).
// ---------------------------------------------------------------------------
template<int TRANSA, int EBF16, int OUTBF>
__global__ __launch_bounds__(256)
void gemm_plan_mfma(const float* __restrict__ P, const void* __restrict__ E,
                    void* __restrict__ Y, int RPB, int YOFF, int VOFF,
                    int VLEN, int maskRows)
{
  __shared__ u16 sP[64 * 40];
  __shared__ u16 sVT[128 * 40];
  const int b = blockIdx.y, rt = blockIdx.x;
  const int t = threadIdx.x;
  const int wid = t >> 6, lane = t & 63;
  const int l15 = lane & 15, lg = lane >> 4;
  const float* Pb = P + (size_t)b * 65536;

  floatx4 acc[8];
  #pragma unroll
  for (int n = 0; n < 8; ++n) acc[n] = floatx4{0.f,0.f,0.f,0.f};

  for (int kb = 0; kb < 256; kb += 32) {
    if constexpr (TRANSA == 0) {
      for (int l = t; l < 64 * 32; l += 256) {
        const int r = l >> 5, k = l & 31;
        sP[r * 40 + k] = f2bf(Pb[(size_t)(rt * 64 + r) * 256 + kb + k]);
      }
    } else {
      for (int l = t; l < 64 * 32; l += 256) {
        const int q = l >> 6, c = l & 63;
        sP[c * 40 + q] = f2bf(Pb[(size_t)(kb + q) * 256 + rt * 64 + c]);
      }
    }
    for (int l = t; l < 32 * 128; l += 256) {
      const int k = l >> 7, d = l & 127;
      const int vr = kb + k;
      u16 v = 0;
      if (vr < VLEN) {
        if constexpr (EBF16) v = ((const u16*)E)[((size_t)b * EPG + VOFF + vr) * 128 + d];
        else                 v = f2bf(((const float*)E)[((size_t)b * EPG + VOFF + vr) * 128 + d]);
      }
      sVT[d * 40 + k] = v;
    }
    __syncthreads();
    const short8 af = *(const short8*)&sP[(wid * 16 + l15) * 40 + lg * 8];
    #pragma unroll
    for (int n = 0; n < 8; ++n) {
      const short8 bw = *(const short8*)&sVT[(n * 16 + l15) * 40 + lg * 8];
      acc[n] = __builtin_amdgcn_mfma_f32_16x16x32_bf16(af, bw, acc[n], 0, 0, 0);
    }
    __syncthreads();
  }
  #pragma unroll
  for (int n = 0; n < 8; ++n) {
    const int col = n * 16 + l15;
    #pragma unroll
    for (int r = 0; r < 4; ++r) {
      const int row = rt * 64 + wid * 16 + lg * 4 + r;
      if (row < maskRows) {
        const size_t idx = ((size_t)b * RPB + YOFF + row) * 128 + col;
        if constexpr (OUTBF) ((u16*)Y)[idx] = f2bf(acc[n][r]);
        else                 ((float*)Y)[idx] = acc[n][r];
      }
    }
  }
}

// ---------------------------------------------------------------------------
// Single-pass fused sinkhorn (round-20 proven: max-sub row pass, plain
// exp-sum col pass).
// ---------------------------------------------------------------------------
__global__ __launch_bounds__(1024)
void sinkhorn_fused(float* __restrict__ S)
{
  const int b = blockIdx.x, t = threadIdx.x;
  float* Sb = S + (size_t)b * 65536;
  const int w = t >> 6, lane = t & 63;
  const int cbase = lane * 4;
  __shared__ float ps[16 * 256];
  __shared__ float su[256], sv[256];
  if (t < 256) sv[t] = 0.f;
  __syncthreads();

  for (int it = 0; it < 10; ++it) {
    const float4 v4 = *(const float4*)&sv[cbase];
    float4 cs = {0.f, 0.f, 0.f, 0.f};
    #pragma unroll 2
    for (int i = 0; i < 16; ++i) {
      const int r = w * 16 + i;
      const float4 s4 = *(const float4*)&Sb[(size_t)r * 256 + cbase];
      const float ax = s4.x + v4.x, ay = s4.y + v4.y;
      const float az = s4.z + v4.z, aw = s4.w + v4.w;
      float m = fmaxf(fmaxf(ax, ay), fmaxf(az, aw));
      #pragma unroll
      for (int off = 32; off; off >>= 1) m = fmaxf(m, __shfl_xor(m, off));
      float s = __expf(ax - m) + __expf(ay - m) + __expf(az - m) + __expf(aw - m);
      #pragma unroll
      for (int off = 32; off; off >>= 1) s += __shfl_xor(s, off);
      const float u = -(m + __logf(s));
      if (lane == 0) su[r] = u;
      cs.x += __expf(s4.x + u);
      cs.y += __expf(s4.y + u);
      cs.z += __expf(s4.z + u);
      cs.w += __expf(s4.w + u);
    }
    *(float4*)&ps[w * 256 + cbase] = cs;
    __syncthreads();
    if (t < 256) {
      float s = 0.f;
      #pragma unroll
      for (int k = 0; k < 16; ++k) s += ps[k * 256 + t];
      sv[t] = -__logf(fmaxf(s, 1e-38f));
    }
    __syncthreads();
  }
  for (int i = t; i < 16384; i += 1024) {
    const int row = i >> 6, c4 = (i & 63) * 4;
    float4 s4 = *(float4*)&Sb[(size_t)row * 256 + c4];
    const float uu = su[row];
    const float4 v4 = *(const float4*)&sv[c4];
    s4.x = __expf(s4.x + uu + v4.x);
    s4.y = __expf(s4.y + uu + v4.y);
    s4.z = __expf(s4.z + uu + v4.z);
    s4.w = __expf(s4.w + uu + v4.w);
    *(float4*)&Sb[(size_t)row * 256 + c4] = s4;
  }
}

// ---------------------------------------------------------------------------
// score[b] = -sum_{m<256,d} | (m<EQ ? e_q[m,d] : 0) - pc[m,d] |
// ---------------------------------------------------------------------------
__global__ __launch_bounds__(256)
void escore_kernel(const float* __restrict__ e, const float* __restrict__ pc,
                   float* __restrict__ out)
{
  const int b = blockIdx.x, t = threadIdx.x;
  float acc = 0.f;
  for (int i4 = t; i4 < 8192; i4 += 256) {
    const int flat = i4 * 4;
    const int m = flat >> 7, d = flat & 127;
    float4 p = *(const float4*)&pc[((size_t)b * 256 + m) * 128 + d];
    float4 q = {0.f, 0.f, 0.f, 0.f};
    if (m < EQ_) q = *(const float4*)&e[((size_t)b * EPG + m) * 128 + d];
    acc += fabsf(q.x - p.x) + fabsf(q.y - p.y) + fabsf(q.z - p.z) + fabsf(q.w - p.w);
  }
  __shared__ float red[256];
  red[t] = acc; __syncthreads();
  for (int s2 = 128; s2 > 0; s2 >>= 1) { if (t < s2) red[t] += red[t + s2]; __syncthreads(); }
  if (t == 0) out[b] = -red[0];
}

// ---------------------------------------------------------------------------
extern "C" void kernel_launch(void* const* d_in, const int* in_sizes, int n_in,
                              void* d_out, int out_size, void* d_ws, size_t ws_size,
                              hipStream_t stream)
{
  const float* node_features = (const float*)d_in[0];
  const float* edge_features = (const float*)d_in[1];
  const int*   from_idx      = (const int*)d_in[2];
  const int*   to_idx        = (const int*)d_in[3];
  const float* enc_node_W = (const float*)d_in[4];
  const float* enc_node_b = (const float*)d_in[5];
  const float* enc_edge_W = (const float*)d_in[6];
  const float* enc_edge_b = (const float*)d_in[7];
  const float* msg_W1 = (const float*)d_in[8];
  const float* msg_b1 = (const float*)d_in[9];
  const float* msg_W2 = (const float*)d_in[10];
  const float* msg_b2 = (const float*)d_in[11];
  const float* upd_W1 = (const float*)d_in[12];
  const float* upd_b1 = (const float*)d_in[13];
  const float* upd_W2 = (const float*)d_in[14];
  const float* upd_b2 = (const float*)d_in[15];
  const float* int_W1 = (const float*)d_in[16];
  const float* int_b1 = (const float*)d_in[17];
  const float* int_W2 = (const float*)d_in[18];
  const float* int_b2 = (const float*)d_in[19];
  const float* sink_W1 = (const float*)d_in[20];
  const float* sink_b1 = (const float*)d_in[21];
  const float* sink_W2 = (const float*)d_in[22];
  const float* sink_b2 = (const float*)d_in[23];
  float* out = (float*)d_out;

  // ~228.7 MB layout (round-19/20 proven).
  u16* wsu = (u16*)d_ws;
  u16*   hb  = wsu;                                    // NN*64 bf16
  float* e   = (float*)(wsu + (size_t)NN * 64);        // NE*128 f32
  float* shr = e + (size_t)NE * 128;                   // BATCH*32768 f32
  float* S   = shr + (size_t)BATCH * 32768;            // BATCH*65536 f32
  u16* comb  = (u16*)(S + (size_t)BATCH * 65536);      // NE*128 bf16
  u16* e1b   = comb + (size_t)NE * 128;                // NE*128 bf16 checkpoint (also e0b)
  u16* h1b   = e1b + (size_t)NE * 128;                 // NN*64 bf16 checkpoint
  u16* wi1 = h1b + (size_t)NN * 64;                    // 256x256
  u16* wi2 = wi1 + 65536;                              // 128x256
  u16* wm1 = wi2 + 32768;                              // 256x256
  u16* wm2 = wm1 + 65536;                              // 128x256
  u16* wu1 = wm2 + 32768;                              // 128x320
  u16* wu2 = wu1 + 40960;                              // 64x128
  u16* ws1h = wu2 + 8192;                              // sink W1 hi (64x128)
  u16* ws1l = ws1h + 8192;                             // sink W1 lo
  u16* ws2h = ws1l + 8192;                             // sink W2 hi (64x64)
  u16* ws2l = ws2h + 4096;                             // sink W2 lo

  u16* mI = (u16*)e;                                   // mf/mb interleaved in e rows
  u16* interb = (u16*)shr;                             // NE*128 bf16 (time-shared)
  u16* aggFb  = (u16*)shr;                             // NN*128 bf16
  u16* aggBb  = aggFb + (size_t)NN * 128;
  float* fq   = shr;
  float* fc   = shr + (size_t)BATCH * 16384;
  float* pc   = shr;

  // weights -> bf16, transposed [N][K] (+ split pair for sink MLP)
  wconv<<<256, 256, 0, stream>>>(int_W1, wi1, 256, 256);
  wconv<<<128, 256, 0, stream>>>(int_W2, wi2, 256, 128);
  wconv<<<256, 256, 0, stream>>>(msg_W1, wm1, 256, 256);
  wconv<<<128, 256, 0, stream>>>(msg_W2, wm2, 256, 128);
  wconv<<<160, 256, 0, stream>>>(upd_W1, wu1, 320, 128);
  wconv<<< 32, 256, 0, stream>>>(upd_W2, wu2, 128, 64);
  wconv_split<<<32, 256, 0, stream>>>(sink_W1, ws1h, ws1l, 128, 64);
  wconv_split<<<16, 256, 0, stream>>>(sink_W2, ws2h, ws2l, 64, 64);

  // ================= ts0 =================
  // node encoder -> bf16 hb; edge encoder -> bf16 e0 straight into e1b
  // (its only consumer, comb_msg p0, bf16-rounds anyway; e1b is dead until
  // the p0 e-update overwrites it with the real checkpoint AFTER p0 staging).
  fused_mlp<32,64,64,0,1,1><<<NN/32, 256, 0, stream>>>(
      node_features, nullptr, enc_node_W, enc_node_b, nullptr, nullptr,
      nullptr, hb, -1);
  fused_mlp<32,128,128,0,1,1><<<NE/32, 256, 0, stream>>>(
      edge_features, nullptr, enc_edge_W, enc_edge_b, nullptr, nullptr,
      nullptr, e1b, -1);

  for (int p = 0; p < 3; ++p) {
    if (p == 0)
      comb_msg_fused<1><<<NE/32, 512, 0, stream>>>(
          e1b, nullptr, hb, from_idx, to_idx,
          wi1, int_b1, wi2, int_b2, wm1, msg_b1, wm2, msg_b2, comb, mI);
    else
      comb_msg_fused<0><<<NE/32, 512, 0, stream>>>(
          e, nullptr, hb, from_idx, to_idx,
          wi1, int_b1, wi2, int_b2, wm1, msg_b1, wm2, msg_b2, comb, mI);
    scatter_agg<<<BATCH*4, 512, 0, stream>>>(mI, from_idx, to_idx, aggFb, aggBb);
    mlp_mfma<320,128,64,3,0,1,4><<<NN/32, 256, 0, stream>>>(
        hb, aggFb, aggBb, nullptr, nullptr, nullptr,
        wu1, upd_b1, wu2, upd_b2, nullptr, hb, nullptr);
    if (p == 0) {
      hipMemcpyAsync(h1b, hb, (size_t)NN * 64 * 2, hipMemcpyDeviceToDevice, stream);
      mlp_mfma<256,256,128,1,1,3,8><<<NE/32, 512, 0, stream>>>(
          hb, nullptr, nullptr, comb, from_idx, to_idx,
          wm1, msg_b1, wm2, msg_b2, e, e1b, nullptr);
    } else {
      mlp_mfma<256,256,128,1,1,0,8><<<NE/32, 512, 0, stream>>>(
          hb, nullptr, nullptr, comb, from_idx, to_idx,
          wm1, msg_b1, wm2, msg_b2, e, nullptr, nullptr);
    }
  }
  sink_mlp_split<0,   EQ_><<<BATCH*8, 256, 0, stream>>>(
      e, ws1h, ws1l, sink_b1, ws2h, ws2l, sink_b2, fq);
  sink_mlp_split<EQ_, EC_><<<BATCH*8, 256, 0, stream>>>(
      e, ws1h, ws1l, sink_b1, ws2h, ws2l, sink_b2, fc);
  gemm_nt_split<<<dim3(4,4,BATCH), 256, 0, stream>>>(fq, fc, S, 10.0f);
  sinkhorn_fused<<<BATCH, 1024, 0, stream>>>(S);   // S := plan1

  // ================= ts1 (p0 skipped: restore checkpoint) =================
  hipMemcpyAsync(hb, h1b, (size_t)NN * 64 * 2, hipMemcpyDeviceToDevice, stream);
  gemm_plan_mfma<0,1,1><<<dim3(4, BATCH), 256, 0, stream>>>(
      S, e1b, interb, EPG, 0,   EQ_, EC_, EQ_);
  gemm_plan_mfma<1,1,1><<<dim3(4, BATCH), 256, 0, stream>>>(
      S, e1b, interb, EPG, EQ_, 0,   EQ_, EC_);

  // p1
  comb_msg_fused<1><<<NE/32, 512, 0, stream>>>(
      e1b, interb, hb, from_idx, to_idx,
      wi1, int_b1, wi2, int_b2, wm1, msg_b1, wm2, msg_b2, comb, mI);
  scatter_agg<<<BATCH*4, 512, 0, stream>>>(mI, from_idx, to_idx, aggFb, aggBb);
  mlp_mfma<320,128,64,3,0,1,4><<<NN/32, 256, 0, stream>>>(
      hb, aggFb, aggBb, nullptr, nullptr, nullptr,
      wu1, upd_b1, wu2, upd_b2, nullptr, hb, nullptr);
  mlp_mfma<256,256,128,1,1,0,8><<<NE/32, 512, 0, stream>>>(
      hb, nullptr, nullptr, comb, from_idx, to_idx,
      wm1, msg_b1, wm2, msg_b2, e, nullptr, nullptr);
  gemm_plan_mfma<0,0,1><<<dim3(4, BATCH), 256, 0, stream>>>(
      S, e, interb, EPG, 0,   EQ_, EC_, EQ_);
  gemm_plan_mfma<1,0,1><<<dim3(4, BATCH), 256, 0, stream>>>(
      S, e, interb, EPG, EQ_, 0,   EQ_, EC_);

  // p2
  comb_msg_fused<0><<<NE/32, 512, 0, stream>>>(
      e, interb, hb, from_idx, to_idx,
      wi1, int_b1, wi2, int_b2, wm1, msg_b1, wm2, msg_b2, comb, mI);
  scatter_agg<<<BATCH*4, 512, 0, stream>>>(mI, from_idx, to_idx, aggFb, aggBb);
  mlp_mfma<320,128,64,3,0,1,4><<<NN/32, 256, 0, stream>>>(
      hb, aggFb, aggBb, nullptr, nullptr, nullptr,
      wu1, upd_b1, wu2, upd_b2, nullptr, hb, nullptr);
  mlp_mfma<256,256,128,1,1,0,8><<<NE/32, 512, 0, stream>>>(
      hb, nullptr, nullptr, comb, from_idx, to_idx,
      wm1, msg_b1, wm2, msg_b2, e, nullptr, nullptr);

  sink_mlp_split<0,   EQ_><<<BATCH*8, 256, 0, stream>>>(
      e, ws1h, ws1l, sink_b1, ws2h, ws2l, sink_b2, fq);
  sink_mlp_split<EQ_, EC_><<<BATCH*8, 256, 0, stream>>>(
      e, ws1h, ws1l, sink_b1, ws2h, ws2l, sink_b2, fc);
  gemm_nt_split<<<dim3(4,4,BATCH), 256, 0, stream>>>(fq, fc, S, 10.0f);
  sinkhorn_fused<<<BATCH, 1024, 0, stream>>>(S);   // S := plan2

  // final score
  gemm_plan_mfma<0,0,0><<<dim3(4, BATCH), 256, 0, stream>>>(
      S, e, pc, 256, 0, EQ_, EC_, 256);
  escore_kernel<<<BATCH, 256, 0, stream>>>(e, pc, out);
}